// Round 1
// baseline (19136.166 us; speedup 1.0000x reference)
//
#include <hip/hip_runtime.h>
#include <hip/hip_bf16.h>
#include <math.h>

#define B_ 2
#define S_ 1024
#define D_ 1024
#define H_ 16
#define HD_ 64
#define L_ 8
#define DFF_ 4096
#define V_ 32000
#define M_ (B_*S_)   /* 2048 rows */

// ---------------------------------------------------------------- embedding
__global__ __launch_bounds__(256) void embed_k(const int* __restrict__ x,
                                               const float* __restrict__ emb,
                                               float* __restrict__ h) {
    int row = blockIdx.x;                       // 0..M_-1
    int tok = x[row];
    const float4* src = (const float4*)(emb + (size_t)tok * D_);
    float4* dst = (float4*)(h + (size_t)row * D_);
    dst[threadIdx.x] = src[threadIdx.x];        // 256 thr x 4 f32 = 1024
}

// ---------------------------------------------------------------- layernorm
// Faithful to source: out = w*(x-m)/(var + 1e-12) + b   (NO sqrt!)
__global__ __launch_bounds__(256) void layernorm_k(const float* __restrict__ x,
                                                   const float* __restrict__ w,
                                                   const float* __restrict__ bb,
                                                   float* __restrict__ out) {
    int row = blockIdx.x;
    const float4* xr = (const float4*)(x + (size_t)row * D_);
    float4 v = xr[threadIdx.x];
    float s = v.x + v.y + v.z + v.w;
    #pragma unroll
    for (int off = 32; off; off >>= 1) s += __shfl_xor(s, off);
    __shared__ float red1[4];
    __shared__ float red2[4];
    int wave = threadIdx.x >> 6, lane = threadIdx.x & 63;
    if (lane == 0) red1[wave] = s;
    __syncthreads();
    float m = (red1[0] + red1[1] + red1[2] + red1[3]) * (1.f / 1024.f);
    float dx = v.x - m, dy = v.y - m, dz = v.z - m, dw = v.w - m;
    float ss = dx*dx + dy*dy + dz*dz + dw*dw;
    #pragma unroll
    for (int off = 32; off; off >>= 1) ss += __shfl_xor(ss, off);
    if (lane == 0) red2[wave] = ss;
    __syncthreads();
    float var = (red2[0] + red2[1] + red2[2] + red2[3]) * (1.f / 1024.f);
    float inv = 1.f / (var + 1e-12f);
    float4 wv = ((const float4*)w)[threadIdx.x];
    float4 bv = ((const float4*)bb)[threadIdx.x];
    float4 ov;
    ov.x = wv.x * dx * inv + bv.x;
    ov.y = wv.y * dy * inv + bv.y;
    ov.z = wv.z * dz * inv + bv.z;
    ov.w = wv.w * dw * inv + bv.w;
    ((float4*)(out + (size_t)row * D_))[threadIdx.x] = ov;
}

// ---------------------------------------------------------------- RoPE
// Faithful quirk: angle = head_index * inv_freq(pair)  (broadcast over seq!)
__global__ __launch_bounds__(256) void rope_k(float* __restrict__ qkv) {
    int idx = blockIdx.x * 256 + threadIdx.x;   // M_ * H_ * 32 threads
    int i  = idx & 31;            // pair index 0..31
    int hh = (idx >> 5) & 15;     // head
    int row = idx >> 9;           // b*S+s, 0..2047
    float e = (2.f * (float)i) / 64.f;
    float inv = powf(10000.f, -e);
    float ang = (float)hh * inv;
    float sn, cs;
    sincosf(ang, &sn, &cs);
    float* qb = qkv + (size_t)row * (3*D_) + hh * (3*HD_) + 2*i;
    float a = qb[0], b = qb[1];
    qb[0] = a*cs - b*sn; qb[1] = a*sn + b*cs;
    float* kb = qb + HD_;
    a = kb[0]; b = kb[1];
    kb[0] = a*cs - b*sn; kb[1] = a*sn + b*cs;
}

// ---------------------------------------------------------------- attention
// One wave (64 lanes) per (b, h, q-row); lane = head dim. Online softmax.
// Masked entries contribute exp(-65504 - m) == 0, so skipping j>q is exact.
__global__ __launch_bounds__(64) void attn_k(const float* __restrict__ qkv,
                                             float* __restrict__ o) {
    int gid  = blockIdx.x;            // (b*H + h)*S + qrow
    int qrow = gid & (S_ - 1);
    int bh   = gid >> 10;
    int hh   = bh & (H_ - 1);
    int bb   = bh >> 4;
    int lane = threadIdx.x;
    const float* qp = qkv + (size_t)(bb*S_ + qrow) * (3*D_) + hh * (3*HD_);
    float qv = qp[lane] * 0.125f;     // 1/sqrt(64)
    float m = -INFINITY, l = 0.f, acc = 0.f;
    for (int j = 0; j <= qrow; ++j) {
        const float* kb = qkv + (size_t)(bb*S_ + j) * (3*D_) + hh * (3*HD_) + HD_;
        float prod = qv * kb[lane];
        #pragma unroll
        for (int off = 32; off; off >>= 1) prod += __shfl_xor(prod, off);
        float mn = fmaxf(m, prod);
        float scale = __expf(m - mn);
        float p = __expf(prod - mn);
        l = l * scale + p;
        acc = acc * scale + p * kb[HD_ + lane];   // v row
        m = mn;
    }
    o[(size_t)(bb*S_ + qrow) * D_ + hh * HD_ + lane] = acc / l;
}

// ---------------------------------------------------------------- GEMM fp32
// C[M,N] = A[M,K] @ B[K,N] (+ Res | gelu).  64x64 tile, BK=16, 4x4 micro.
// All dims divisible: M=2048, N in {3072,1024,4096,32000}, K in {1024,4096}.
#define BM 64
#define BN 64
#define BK 16

__device__ inline float gelu_f(float x) {
    return 0.5f * x * (1.f + erff(x * 0.70710678118654752f));
}

__global__ __launch_bounds__(256) void gemm_k(const float* __restrict__ A,
                                              const float* __restrict__ Bm,
                                              float* __restrict__ C,
                                              const float* __restrict__ Res,
                                              int M, int N, int K, int epi) {
    __shared__ float As[BK][BM + 4];
    __shared__ float Bs[BK][BN];
    int bm = blockIdx.y * BM;
    int bn = blockIdx.x * BN;
    int tid = threadIdx.x;
    int tm = (tid >> 4) * 4;       // 0..60
    int tn = (tid & 15) * 4;       // 0..60
    int aRow = tid >> 2;           // 0..63
    int aCol = (tid & 3) * 4;      // 0,4,8,12
    int bRow = tid >> 4;           // 0..15
    int bCol = (tid & 15) * 4;     // 0..60

    const float* Aptr = A + (size_t)(bm + aRow) * K + aCol;
    const float* Bptr = Bm + (size_t)bRow * N + bn + bCol;

    float acc[4][4] = {};
    for (int k0 = 0; k0 < K; k0 += BK) {
        float4 av = *(const float4*)(Aptr + k0);
        float4 bv = *(const float4*)(Bptr + (size_t)k0 * N);
        __syncthreads();
        As[aCol + 0][aRow] = av.x;
        As[aCol + 1][aRow] = av.y;
        As[aCol + 2][aRow] = av.z;
        As[aCol + 3][aRow] = av.w;
        *(float4*)&Bs[bRow][bCol] = bv;
        __syncthreads();
        #pragma unroll
        for (int k = 0; k < BK; ++k) {
            float4 a4 = *(const float4*)&As[k][tm];
            float4 b4 = *(const float4*)&Bs[k][tn];
            acc[0][0] += a4.x * b4.x; acc[0][1] += a4.x * b4.y;
            acc[0][2] += a4.x * b4.z; acc[0][3] += a4.x * b4.w;
            acc[1][0] += a4.y * b4.x; acc[1][1] += a4.y * b4.y;
            acc[1][2] += a4.y * b4.z; acc[1][3] += a4.y * b4.w;
            acc[2][0] += a4.z * b4.x; acc[2][1] += a4.z * b4.y;
            acc[2][2] += a4.z * b4.z; acc[2][3] += a4.z * b4.w;
            acc[3][0] += a4.w * b4.x; acc[3][1] += a4.w * b4.y;
            acc[3][2] += a4.w * b4.z; acc[3][3] += a4.w * b4.w;
        }
    }
    #pragma unroll
    for (int i = 0; i < 4; ++i) {
        size_t off = (size_t)(bm + tm + i) * N + bn + tn;
        float4 v = make_float4(acc[i][0], acc[i][1], acc[i][2], acc[i][3]);
        if (epi == 1) {
            float4 r = *(const float4*)(Res + off);
            v.x += r.x; v.y += r.y; v.z += r.z; v.w += r.w;
        } else if (epi == 2) {
            v.x = gelu_f(v.x); v.y = gelu_f(v.y);
            v.z = gelu_f(v.z); v.w = gelu_f(v.w);
        }
        *(float4*)(C + off) = v;
    }
}

// ---------------------------------------------------------------- launch
extern "C" void kernel_launch(void* const* d_in, const int* in_sizes, int n_in,
                              void* d_out, int out_size, void* d_ws, size_t ws_size,
                              hipStream_t stream) {
    const int*   x    = (const int*)  d_in[0];
    const float* emb  = (const float*)d_in[1];
    const float* ln1w = (const float*)d_in[2];
    const float* ln1b = (const float*)d_in[3];
    const float* Wqkv = (const float*)d_in[4];
    const float* Wo   = (const float*)d_in[5];
    const float* ln2w = (const float*)d_in[6];
    const float* ln2b = (const float*)d_in[7];
    const float* W1   = (const float*)d_in[8];
    const float* W2   = (const float*)d_in[9];
    const float* lnfw = (const float*)d_in[10];
    const float* lnfb = (const float*)d_in[11];
    const float* Wdec = (const float*)d_in[12];
    float* out = (float*)d_out;

    float* ws  = (float*)d_ws;
    float* h   = ws;                              // [2048,1024]
    float* xn  = h   + (size_t)M_ * D_;           // [2048,1024]
    float* qkv = xn  + (size_t)M_ * D_;           // [2048,3072]
    float* o   = qkv + (size_t)M_ * 3 * D_;       // [2048,1024]
    float* ff  = o   + (size_t)M_ * D_;           // [2048,4096]

    embed_k<<<M_, 256, 0, stream>>>(x, emb, h);
    for (int l = 0; l < L_; ++l) {
        layernorm_k<<<M_, 256, 0, stream>>>(h, ln1w + l*D_, ln1b + l*D_, xn);
        gemm_k<<<dim3(3*D_/BN, M_/BM), 256, 0, stream>>>(
            xn, Wqkv + (size_t)l*D_*3*D_, qkv, nullptr, M_, 3*D_, D_, 0);
        rope_k<<<(M_*H_*32)/256, 256, 0, stream>>>(qkv);
        attn_k<<<B_*H_*S_, 64, 0, stream>>>(qkv, o);
        gemm_k<<<dim3(D_/BN, M_/BM), 256, 0, stream>>>(
            o, Wo + (size_t)l*D_*D_, h, h, M_, D_, D_, 1);
        layernorm_k<<<M_, 256, 0, stream>>>(h, ln2w + l*D_, ln2b + l*D_, xn);
        gemm_k<<<dim3(DFF_/BN, M_/BM), 256, 0, stream>>>(
            xn, W1 + (size_t)l*D_*DFF_, ff, nullptr, M_, DFF_, D_, 2);
        gemm_k<<<dim3(D_/BN, M_/BM), 256, 0, stream>>>(
            ff, W2 + (size_t)l*DFF_*D_, h, h, M_, D_, DFF_, 1);
    }
    layernorm_k<<<M_, 256, 0, stream>>>(h, lnfw, lnfb, xn);
    gemm_k<<<dim3(V_/BN, M_/BM), 256, 0, stream>>>(
        xn, Wdec, out, nullptr, M_, V_, D_, 0);
}

// Round 2
// 12659.193 us; speedup vs baseline: 1.5116x; 1.5116x over previous
//
#include <hip/hip_runtime.h>
#include <hip/hip_bf16.h>
#include <math.h>

#define B_ 2
#define S_ 1024
#define D_ 1024
#define H_ 16
#define HD_ 64
#define L_ 8
#define DFF_ 4096
#define V_ 32000
#define M_ (B_*S_)   /* 2048 rows */

typedef unsigned short ushort_t;
typedef __attribute__((ext_vector_type(8))) __bf16 bf16x8_t;
typedef __attribute__((ext_vector_type(4))) float f32x4_t;

__device__ __forceinline__ ushort_t f2bf(float f) {
    union { float f; unsigned u; } x; x.f = f;
    unsigned r = x.u + 0x7fffu + ((x.u >> 16) & 1u);
    return (ushort_t)(r >> 16);
}

__device__ __forceinline__ void gload_lds16(const void* g, void* l) {
    __builtin_amdgcn_global_load_lds(
        (const __attribute__((address_space(1))) void*)g,
        (__attribute__((address_space(3))) void*)l, 16, 0, 0);
}

// ---------------------------------------------------------------- embedding
__global__ __launch_bounds__(256) void embed_k(const int* __restrict__ x,
                                               const float* __restrict__ emb,
                                               float* __restrict__ h) {
    int row = blockIdx.x;
    int tok = x[row];
    const float4* src = (const float4*)(emb + (size_t)tok * D_);
    float4* dst = (float4*)(h + (size_t)row * D_);
    dst[threadIdx.x] = src[threadIdx.x];
}

// ---------------------------------------------------------------- layernorm
// Faithful: out = w*(x-m)/(var + 1e-12) + b   (NO sqrt). Writes bf16 always,
// fp32 optionally (layer-0 QKV path needs fp32).
__global__ __launch_bounds__(256) void layernorm_k(const float* __restrict__ x,
                                                   const float* __restrict__ w,
                                                   const float* __restrict__ bb,
                                                   float* __restrict__ out32,
                                                   ushort_t* __restrict__ out16) {
    int row = blockIdx.x;
    const float4* xr = (const float4*)(x + (size_t)row * D_);
    float4 v = xr[threadIdx.x];
    float s = v.x + v.y + v.z + v.w;
    #pragma unroll
    for (int off = 32; off; off >>= 1) s += __shfl_xor(s, off);
    __shared__ float red1[4];
    __shared__ float red2[4];
    int wave = threadIdx.x >> 6, lane = threadIdx.x & 63;
    if (lane == 0) red1[wave] = s;
    __syncthreads();
    float m = (red1[0] + red1[1] + red1[2] + red1[3]) * (1.f / 1024.f);
    float dx = v.x - m, dy = v.y - m, dz = v.z - m, dw = v.w - m;
    float ss = dx*dx + dy*dy + dz*dz + dw*dw;
    #pragma unroll
    for (int off = 32; off; off >>= 1) ss += __shfl_xor(ss, off);
    if (lane == 0) red2[wave] = ss;
    __syncthreads();
    float var = (red2[0] + red2[1] + red2[2] + red2[3]) * (1.f / 1024.f);
    float inv = 1.f / (var + 1e-12f);
    float4 wv = ((const float4*)w)[threadIdx.x];
    float4 bv = ((const float4*)bb)[threadIdx.x];
    float4 ov;
    ov.x = wv.x * dx * inv + bv.x;
    ov.y = wv.y * dy * inv + bv.y;
    ov.z = wv.z * dz * inv + bv.z;
    ov.w = wv.w * dw * inv + bv.w;
    if (out32) ((float4*)(out32 + (size_t)row * D_))[threadIdx.x] = ov;
    ushort4 ob;
    ob.x = f2bf(ov.x); ob.y = f2bf(ov.y); ob.z = f2bf(ov.z); ob.w = f2bf(ov.w);
    ((ushort4*)(out16 + (size_t)row * D_))[threadIdx.x] = ob;
}

// ---------------------------------------------------------------- RoPE
// Faithful quirk: angle = head_index * inv_freq(pair)  (broadcast over seq)
__global__ __launch_bounds__(256) void rope_k(float* __restrict__ qkv) {
    int idx = blockIdx.x * 256 + threadIdx.x;
    int i  = idx & 31;
    int hh = (idx >> 5) & 15;
    int row = idx >> 9;
    float e = (2.f * (float)i) / 64.f;
    float inv = powf(10000.f, -e);
    float ang = (float)hh * inv;
    float sn, cs;
    sincosf(ang, &sn, &cs);
    float* qb = qkv + (size_t)row * (3*D_) + hh * (3*HD_) + 2*i;
    float a = qb[0], b = qb[1];
    qb[0] = a*cs - b*sn; qb[1] = a*sn + b*cs;
    float* kb = qb + HD_;
    a = kb[0]; b = kb[1];
    kb[0] = a*cs - b*sn; kb[1] = a*sn + b*cs;
}

// ---------------------------------------------------------------- attention
// One wave per (b,h,q-row); lane = head dim. Online softmax, fp32 math,
// bf16 output (next GEMM's A operand).
__global__ __launch_bounds__(64) void attn_k(const float* __restrict__ qkv,
                                             ushort_t* __restrict__ o) {
    int gid  = blockIdx.x;
    int qrow = gid & (S_ - 1);
    int bh   = gid >> 10;
    int hh   = bh & (H_ - 1);
    int bb   = bh >> 4;
    int lane = threadIdx.x;
    const float* qp = qkv + (size_t)(bb*S_ + qrow) * (3*D_) + hh * (3*HD_);
    float qv = qp[lane] * 0.125f;
    float m = -INFINITY, l = 0.f, acc = 0.f;
    for (int j = 0; j <= qrow; ++j) {
        const float* kb = qkv + (size_t)(bb*S_ + j) * (3*D_) + hh * (3*HD_) + HD_;
        float prod = qv * kb[lane];
        #pragma unroll
        for (int off = 32; off; off >>= 1) prod += __shfl_xor(prod, off);
        float mn = fmaxf(m, prod);
        float scale = __expf(m - mn);
        float p = __expf(prod - mn);
        l = l * scale + p;
        acc = acc * scale + p * kb[HD_ + lane];
        m = mn;
    }
    o[(size_t)(bb*S_ + qrow) * D_ + hh * HD_ + lane] = f2bf(acc / l);
}

// ------------------------------------------------- weight transpose fp32->bf16
// W [K][N] fp32  ->  Wt [N][K] bf16. 32x32 LDS tile.
__global__ __launch_bounds__(256) void wt_k(const float* __restrict__ W,
                                            ushort_t* __restrict__ Wt,
                                            int K, int N) {
    __shared__ float t[32][33];
    int k0 = blockIdx.y << 5, n0 = blockIdx.x << 5;
    int r = threadIdx.x >> 3, c4 = (threadIdx.x & 7) << 2;
    float4 v = *(const float4*)(W + (size_t)(k0 + r) * N + n0 + c4);
    t[r][c4+0] = v.x; t[r][c4+1] = v.y; t[r][c4+2] = v.z; t[r][c4+3] = v.w;
    __syncthreads();
    ushort4 o;
    o.x = f2bf(t[c4+0][r]); o.y = f2bf(t[c4+1][r]);
    o.z = f2bf(t[c4+2][r]); o.w = f2bf(t[c4+3][r]);
    *(ushort4*)(Wt + (size_t)(n0 + r) * K + k0 + c4) = o;
}

// ---------------------------------------------------------------- GEMM fp32
// Kept for layer-0 QKV only (sharp-softmax precision). C = A @ B, B [K][N].
#define BM 64
#define BN 64
#define BK 16
__global__ __launch_bounds__(256) void gemm_k(const float* __restrict__ A,
                                              const float* __restrict__ Bm,
                                              float* __restrict__ C,
                                              int M, int N, int K) {
    __shared__ float As[BK][BM + 4];
    __shared__ float Bs[BK][BN];
    int bm = blockIdx.y * BM;
    int bn = blockIdx.x * BN;
    int tid = threadIdx.x;
    int tm = (tid >> 4) * 4;
    int tn = (tid & 15) * 4;
    int aRow = tid >> 2;
    int aCol = (tid & 3) * 4;
    int bRow = tid >> 4;
    int bCol = (tid & 15) * 4;
    const float* Aptr = A + (size_t)(bm + aRow) * K + aCol;
    const float* Bptr = Bm + (size_t)bRow * N + bn + bCol;
    float acc[4][4] = {};
    for (int k0 = 0; k0 < K; k0 += BK) {
        float4 av = *(const float4*)(Aptr + k0);
        float4 bv = *(const float4*)(Bptr + (size_t)k0 * N);
        __syncthreads();
        As[aCol + 0][aRow] = av.x;
        As[aCol + 1][aRow] = av.y;
        As[aCol + 2][aRow] = av.z;
        As[aCol + 3][aRow] = av.w;
        *(float4*)&Bs[bRow][bCol] = bv;
        __syncthreads();
        #pragma unroll
        for (int k = 0; k < BK; ++k) {
            float4 a4 = *(const float4*)&As[k][tm];
            float4 b4 = *(const float4*)&Bs[k][tn];
            acc[0][0] += a4.x * b4.x; acc[0][1] += a4.x * b4.y;
            acc[0][2] += a4.x * b4.z; acc[0][3] += a4.x * b4.w;
            acc[1][0] += a4.y * b4.x; acc[1][1] += a4.y * b4.y;
            acc[1][2] += a4.y * b4.z; acc[1][3] += a4.y * b4.w;
            acc[2][0] += a4.z * b4.x; acc[2][1] += a4.z * b4.y;
            acc[2][2] += a4.z * b4.z; acc[2][3] += a4.z * b4.w;
            acc[3][0] += a4.w * b4.x; acc[3][1] += a4.w * b4.y;
            acc[3][2] += a4.w * b4.z; acc[3][3] += a4.w * b4.w;
        }
    }
    #pragma unroll
    for (int i = 0; i < 4; ++i) {
        size_t off = (size_t)(bm + tm + i) * N + bn + tn;
        *(float4*)(C + off) = make_float4(acc[i][0], acc[i][1], acc[i][2], acc[i][3]);
    }
}

// ---------------------------------------------------------------- GEMM bf16
// C[M,N] = A[M,K] @ Bt[N,K]^T. 128x128 tile, BK=64, 4 waves (2x2), each wave
// 64x64 via 4x4 frags of mfma_f32_16x16x32_bf16. fp32 accumulate.
// epi: 0 = fp32 out, 1 = fp32 out + Res (residual, may alias C), 2 = gelu->bf16
__device__ __forceinline__ float gelu_f(float x) {
    return 0.5f * x * (1.f + erff(x * 0.70710678118654752f));
}

__global__ __launch_bounds__(256, 2) void gemm_bf16_k(
    const ushort_t* __restrict__ A,
    const ushort_t* __restrict__ Bt,
    const float* __restrict__ Res,
    float* __restrict__ Cf,
    ushort_t* __restrict__ Cb,
    int M, int N, int K, int epi)
{
    __shared__ __align__(16) ushort_t As[128 * 64];
    __shared__ __align__(16) ushort_t Bs[128 * 64];
    int tid = threadIdx.x;
    int wid = tid >> 6, lane = tid & 63;
    int wm = wid >> 1, wn = wid & 1;
    int bm = blockIdx.y * 128, bn = blockIdx.x * 128;

    f32x4_t acc[4][4];
    #pragma unroll
    for (int m = 0; m < 4; ++m)
        #pragma unroll
        for (int n = 0; n < 4; ++n)
            acc[m][n] = (f32x4_t){0.f, 0.f, 0.f, 0.f};

    int srow = (lane >> 3);        // 0..7 within 8-row chunk
    int scol = (lane & 7) * 8;     // element offset 0..56

    for (int k0 = 0; k0 < K; k0 += 64) {
        __syncthreads();   // previous iteration's LDS reads done
        #pragma unroll
        for (int i = 0; i < 4; ++i) {
            int rb = i * 32 + wid * 8;
            gload_lds16(A  + (size_t)(bm + rb + srow) * K + k0 + scol, &As[rb * 64]);
            gload_lds16(Bt + (size_t)(bn + rb + srow) * K + k0 + scol, &Bs[rb * 64]);
        }
        __syncthreads();   // staging complete (vmcnt(0) drained by barrier)
        #pragma unroll
        for (int kk = 0; kk < 64; kk += 32) {
            bf16x8_t af[4], bfr[4];
            int kof = kk + (lane >> 4) * 8;
            #pragma unroll
            for (int m = 0; m < 4; ++m) {
                int r = wm * 64 + m * 16 + (lane & 15);
                af[m] = *(const bf16x8_t*)&As[r * 64 + kof];
            }
            #pragma unroll
            for (int n = 0; n < 4; ++n) {
                int r = wn * 64 + n * 16 + (lane & 15);
                bfr[n] = *(const bf16x8_t*)&Bs[r * 64 + kof];
            }
            #pragma unroll
            for (int m = 0; m < 4; ++m)
                #pragma unroll
                for (int n = 0; n < 4; ++n)
                    acc[m][n] = __builtin_amdgcn_mfma_f32_16x16x32_bf16(
                        af[m], bfr[n], acc[m][n], 0, 0, 0);
        }
    }

    int cr = (lane >> 4) * 4, cc = lane & 15;
    #pragma unroll
    for (int m = 0; m < 4; ++m) {
        int row = bm + wm * 64 + m * 16 + cr;
        #pragma unroll
        for (int n = 0; n < 4; ++n) {
            int col = bn + wn * 64 + n * 16 + cc;
            #pragma unroll
            for (int j = 0; j < 4; ++j) {
                size_t off = (size_t)(row + j) * N + col;
                float v = acc[m][n][j];
                if (epi == 0) {
                    Cf[off] = v;
                } else if (epi == 1) {
                    Cf[off] = Res[off] + v;
                } else {
                    Cb[off] = f2bf(gelu_f(v));
                }
            }
        }
    }
}

// ---------------------------------------------------------------- launch
extern "C" void kernel_launch(void* const* d_in, const int* in_sizes, int n_in,
                              void* d_out, int out_size, void* d_ws, size_t ws_size,
                              hipStream_t stream) {
    const int*   x    = (const int*)  d_in[0];
    const float* emb  = (const float*)d_in[1];
    const float* ln1w = (const float*)d_in[2];
    const float* ln1b = (const float*)d_in[3];
    const float* Wqkv = (const float*)d_in[4];
    const float* Wo   = (const float*)d_in[5];
    const float* ln2w = (const float*)d_in[6];
    const float* ln2b = (const float*)d_in[7];
    const float* W1   = (const float*)d_in[8];
    const float* W2   = (const float*)d_in[9];
    const float* lnfw = (const float*)d_in[10];
    const float* lnfb = (const float*)d_in[11];
    const float* Wdec = (const float*)d_in[12];
    float* out = (float*)d_out;

    // ---- workspace layout (bytes), lifetime-aliased, 80 MB total ----
    char* ws = (char*)d_ws;
    float*    h     = (float*)   (ws + 0);              // 8 MB  [2048,1024] f32
    ushort_t* xnb   = (ushort_t*)(ws + (8u<<20));       // 4 MB  [2048,1024] bf16
    ushort_t* ob    = (ushort_t*)(ws + (12u<<20));      // 4 MB  [2048,1024] bf16
    float*    qkv   = (float*)   (ws + (16u<<20));      // 24 MB [2048,3072] f32
    ushort_t* ffb   = (ushort_t*)(ws + (40u<<20));      // 16 MB [2048,4096] bf16
    ushort_t* wqkvT = (ushort_t*)(ws + (56u<<20));      // 6 MB  [3072,1024] bf16
    ushort_t* woT   = (ushort_t*)(ws + (62u<<20));      // 2 MB  [1024,1024] bf16
    ushort_t* w1T   = (ushort_t*)(ws + (64u<<20));      // 8 MB  [4096,1024] bf16
    ushort_t* w2T   = (ushort_t*)(ws + (72u<<20));      // 8 MB  [1024,4096] bf16
    float*    xn    = (float*)   (ws + (64u<<20));      // 8 MB, aliases w1T (l=0 only, dead before wt(W1))
    ushort_t* wdecT = (ushort_t*)(ws + (16u<<20));      // 64 MB, aliases qkv..w2T (post-loop)

    embed_k<<<M_, 256, 0, stream>>>(x, emb, h);
    for (int l = 0; l < L_; ++l) {
        if (l == 0) {
            layernorm_k<<<M_, 256, 0, stream>>>(h, ln1w, ln1b, xn, xnb);
            gemm_k<<<dim3(3*D_/BN, M_/BM), 256, 0, stream>>>(
                xn, Wqkv, qkv, M_, 3*D_, D_);
        } else {
            layernorm_k<<<M_, 256, 0, stream>>>(h, ln1w + l*D_, ln1b + l*D_, nullptr, xnb);
            wt_k<<<dim3(3*D_/32, D_/32), 256, 0, stream>>>(
                Wqkv + (size_t)l*D_*3*D_, wqkvT, D_, 3*D_);
            gemm_bf16_k<<<dim3(3*D_/128, M_/128), 256, 0, stream>>>(
                xnb, wqkvT, nullptr, qkv, nullptr, M_, 3*D_, D_, 0);
        }
        rope_k<<<(M_*H_*32)/256, 256, 0, stream>>>(qkv);
        attn_k<<<B_*H_*S_, 64, 0, stream>>>(qkv, ob);
        wt_k<<<dim3(D_/32, D_/32), 256, 0, stream>>>(
            Wo + (size_t)l*D_*D_, woT, D_, D_);
        gemm_bf16_k<<<dim3(D_/128, M_/128), 256, 0, stream>>>(
            ob, woT, h, h, nullptr, M_, D_, D_, 1);
        layernorm_k<<<M_, 256, 0, stream>>>(h, ln2w + l*D_, ln2b + l*D_, nullptr, xnb);
        wt_k<<<dim3(DFF_/32, D_/32), 256, 0, stream>>>(
            W1 + (size_t)l*D_*DFF_, w1T, D_, DFF_);
        gemm_bf16_k<<<dim3(DFF_/128, M_/128), 256, 0, stream>>>(
            xnb, w1T, nullptr, nullptr, ffb, M_, DFF_, D_, 2);
        wt_k<<<dim3(D_/32, DFF_/32), 256, 0, stream>>>(
            W2 + (size_t)l*DFF_*D_, w2T, DFF_, D_);
        gemm_bf16_k<<<dim3(D_/128, M_/128), 256, 0, stream>>>(
            ffb, w2T, h, h, nullptr, M_, D_, DFF_, 1);
    }
    layernorm_k<<<M_, 256, 0, stream>>>(h, lnfw, lnfb, nullptr, xnb);
    wt_k<<<dim3(V_/32, D_/32), 256, 0, stream>>>(Wdec, wdecT, D_, V_);
    gemm_bf16_k<<<dim3(V_/128, M_/128), 256, 0, stream>>>(
        xnb, wdecT, nullptr, out, nullptr, M_, V_, D_, 0);
}

// Round 3
// 5201.649 us; speedup vs baseline: 3.6789x; 2.4337x over previous
//
#include <hip/hip_runtime.h>
#include <hip/hip_bf16.h>
#include <math.h>

#define B_ 2
#define S_ 1024
#define D_ 1024
#define H_ 16
#define HD_ 64
#define L_ 8
#define DFF_ 4096
#define V_ 32000
#define M_ (B_*S_)   /* 2048 rows */

typedef unsigned short ushort_t;
typedef __attribute__((ext_vector_type(8))) __bf16 bf16x8_t;
typedef __attribute__((ext_vector_type(4))) float f32x4_t;

__device__ __forceinline__ ushort_t f2bf(float f) {
    union { float f; unsigned u; } x; x.f = f;
    unsigned r = x.u + 0x7fffu + ((x.u >> 16) & 1u);
    return (ushort_t)(r >> 16);
}

__device__ __forceinline__ void gload_lds16(const void* g, void* l) {
    __builtin_amdgcn_global_load_lds(
        (const __attribute__((address_space(1))) void*)g,
        (__attribute__((address_space(3))) void*)l, 16, 0, 0);
}

// ---------------------------------------------------------------- embedding
__global__ __launch_bounds__(256) void embed_k(const int* __restrict__ x,
                                               const float* __restrict__ emb,
                                               float* __restrict__ h) {
    int row = blockIdx.x;
    int tok = x[row];
    const float4* src = (const float4*)(emb + (size_t)tok * D_);
    float4* dst = (float4*)(h + (size_t)row * D_);
    dst[threadIdx.x] = src[threadIdx.x];
}

// ---------------------------------------------------------------- layernorm
// Faithful: out = w*(x-m)/(var + 1e-12) + b   (NO sqrt). Writes bf16 always,
// fp32 optionally (layer-0 QKV path needs fp32).
__global__ __launch_bounds__(256) void layernorm_k(const float* __restrict__ x,
                                                   const float* __restrict__ w,
                                                   const float* __restrict__ bb,
                                                   float* __restrict__ out32,
                                                   ushort_t* __restrict__ out16) {
    int row = blockIdx.x;
    const float4* xr = (const float4*)(x + (size_t)row * D_);
    float4 v = xr[threadIdx.x];
    float s = v.x + v.y + v.z + v.w;
    #pragma unroll
    for (int off = 32; off; off >>= 1) s += __shfl_xor(s, off);
    __shared__ float red1[4];
    __shared__ float red2[4];
    int wave = threadIdx.x >> 6, lane = threadIdx.x & 63;
    if (lane == 0) red1[wave] = s;
    __syncthreads();
    float m = (red1[0] + red1[1] + red1[2] + red1[3]) * (1.f / 1024.f);
    float dx = v.x - m, dy = v.y - m, dz = v.z - m, dw = v.w - m;
    float ss = dx*dx + dy*dy + dz*dz + dw*dw;
    #pragma unroll
    for (int off = 32; off; off >>= 1) ss += __shfl_xor(ss, off);
    if (lane == 0) red2[wave] = ss;
    __syncthreads();
    float var = (red2[0] + red2[1] + red2[2] + red2[3]) * (1.f / 1024.f);
    float inv = 1.f / (var + 1e-12f);
    float4 wv = ((const float4*)w)[threadIdx.x];
    float4 bv = ((const float4*)bb)[threadIdx.x];
    float4 ov;
    ov.x = wv.x * dx * inv + bv.x;
    ov.y = wv.y * dy * inv + bv.y;
    ov.z = wv.z * dz * inv + bv.z;
    ov.w = wv.w * dw * inv + bv.w;
    if (out32) ((float4*)(out32 + (size_t)row * D_))[threadIdx.x] = ov;
    ushort4 ob;
    ob.x = f2bf(ov.x); ob.y = f2bf(ov.y); ob.z = f2bf(ov.z); ob.w = f2bf(ov.w);
    ((ushort4*)(out16 + (size_t)row * D_))[threadIdx.x] = ob;
}

// ---------------------------------------------------------------- RoPE
// Faithful quirk: angle = head_index * inv_freq(pair)  (broadcast over seq)
__global__ __launch_bounds__(256) void rope_k(float* __restrict__ qkv) {
    int idx = blockIdx.x * 256 + threadIdx.x;
    int i  = idx & 31;
    int hh = (idx >> 5) & 15;
    int row = idx >> 9;
    float e = (2.f * (float)i) / 64.f;
    float inv = powf(10000.f, -e);
    float ang = (float)hh * inv;
    float sn, cs;
    sincosf(ang, &sn, &cs);
    float* qb = qkv + (size_t)row * (3*D_) + hh * (3*HD_) + 2*i;
    float a = qb[0], b = qb[1];
    qb[0] = a*cs - b*sn; qb[1] = a*sn + b*cs;
    float* kb = qb + HD_;
    a = kb[0]; b = kb[1];
    kb[0] = a*cs - b*sn; kb[1] = a*sn + b*cs;
}

// ---------------------------------------------------------------- attention
// Tiled fp32 flash attention. Block = 4 waves = 16 q-rows of one (b,h).
// K tile stored transposed (Kt[d][j], pad 65) so QK reads are lane-consecutive;
// V row-major (pad 68). Online softmax per q-row, wave-reduced once per tile.
__global__ __launch_bounds__(256) void attn_tile_k(const float* __restrict__ qkv,
                                                   ushort_t* __restrict__ o) {
    __shared__ float Kt[64][65];
    __shared__ float Vs[64][68];
    __shared__ float qs[16][68];
    __shared__ float ps[16][68];
    int gid = blockIdx.x;
    int qt = 63 - (gid & 63);          // longest blocks first
    int bh = gid >> 6;
    int hh = bh & (H_ - 1);
    int bb = bh >> 4;
    int tid = threadIdx.x, wv = tid >> 6, lane = tid & 63;
    const float* base = qkv + (size_t)bb * S_ * (3*D_) + hh * (3*HD_);

    {   // stage q (pre-scaled by 1/sqrt(64))
        int r = tid >> 4, d0 = (tid & 15) * 4;
        float4 qv = *(const float4*)(base + (size_t)(qt*16 + r) * (3*D_) + d0);
        float4 qsc = make_float4(qv.x*0.125f, qv.y*0.125f, qv.z*0.125f, qv.w*0.125f);
        *(float4*)&qs[r][d0] = qsc;
    }

    int q0 = qt*16 + wv*4;
    float m[4], l[4] = {0.f,0.f,0.f,0.f}, oa[4] = {0.f,0.f,0.f,0.f};
    m[0] = m[1] = m[2] = m[3] = -INFINITY;
    int ntile = (qt*16 + 15) / 64 + 1;

    int jr = tid >> 2;              // staging row 0..63
    int c0 = (tid & 3) * 16;        // staging col chunk

    for (int t = 0; t < ntile; ++t) {
        __syncthreads();            // LDS reuse + (t==0) q staging
        const float* kp = base + (size_t)(t*64 + jr) * (3*D_) + HD_;
        float4 ka = *(const float4*)(kp + c0 + 0);
        float4 kb = *(const float4*)(kp + c0 + 4);
        float4 kc = *(const float4*)(kp + c0 + 8);
        float4 kd = *(const float4*)(kp + c0 + 12);
        Kt[c0+ 0][jr] = ka.x; Kt[c0+ 1][jr] = ka.y;
        Kt[c0+ 2][jr] = ka.z; Kt[c0+ 3][jr] = ka.w;
        Kt[c0+ 4][jr] = kb.x; Kt[c0+ 5][jr] = kb.y;
        Kt[c0+ 6][jr] = kb.z; Kt[c0+ 7][jr] = kb.w;
        Kt[c0+ 8][jr] = kc.x; Kt[c0+ 9][jr] = kc.y;
        Kt[c0+10][jr] = kc.z; Kt[c0+11][jr] = kc.w;
        Kt[c0+12][jr] = kd.x; Kt[c0+13][jr] = kd.y;
        Kt[c0+14][jr] = kd.z; Kt[c0+15][jr] = kd.w;
        const float* vp = kp + HD_;
        *(float4*)&Vs[jr][c0+ 0] = *(const float4*)(vp + c0 + 0);
        *(float4*)&Vs[jr][c0+ 4] = *(const float4*)(vp + c0 + 4);
        *(float4*)&Vs[jr][c0+ 8] = *(const float4*)(vp + c0 + 8);
        *(float4*)&Vs[jr][c0+12] = *(const float4*)(vp + c0 + 12);
        __syncthreads();

        // ---- QK: lane = key j within tile
        float s[4] = {0.f, 0.f, 0.f, 0.f};
        #pragma unroll
        for (int d0 = 0; d0 < 64; d0 += 4) {
            float k0 = Kt[d0+0][lane], k1 = Kt[d0+1][lane],
                  k2 = Kt[d0+2][lane], k3 = Kt[d0+3][lane];
            #pragma unroll
            for (int r = 0; r < 4; ++r) {
                float4 q4 = *(const float4*)&qs[wv*4+r][d0];
                s[r] += q4.x*k0 + q4.y*k1 + q4.z*k2 + q4.w*k3;
            }
        }

        // ---- online softmax (wave-uniform m/l/scale; p per lane)
        int jj = t*64 + lane;
        float scale[4];
        #pragma unroll
        for (int r = 0; r < 4; ++r) {
            float sv = (jj <= q0 + r) ? s[r] : -INFINITY;
            float mx = sv;
            #pragma unroll
            for (int off = 32; off; off >>= 1) mx = fmaxf(mx, __shfl_xor(mx, off));
            float mn = fmaxf(m[r], mx);
            float sc = __expf(m[r] - mn);
            float p  = __expf(sv - mn);
            float sm = p;
            #pragma unroll
            for (int off = 32; off; off >>= 1) sm += __shfl_xor(sm, off);
            l[r] = l[r] * sc + sm;
            m[r] = mn;
            scale[r] = sc;
            ps[wv*4+r][lane] = p;
        }

        // ---- PV: lane = output dim d  (ps write->read same wave, in-order)
        #pragma unroll
        for (int r = 0; r < 4; ++r) oa[r] *= scale[r];
        #pragma unroll
        for (int j0 = 0; j0 < 64; j0 += 4) {
            float v0 = Vs[j0+0][lane], v1 = Vs[j0+1][lane],
                  v2 = Vs[j0+2][lane], v3 = Vs[j0+3][lane];
            #pragma unroll
            for (int r = 0; r < 4; ++r) {
                float4 p4 = *(const float4*)&ps[wv*4+r][j0];
                oa[r] += p4.x*v0 + p4.y*v1 + p4.z*v2 + p4.w*v3;
            }
        }
    }
    #pragma unroll
    for (int r = 0; r < 4; ++r)
        o[(size_t)(bb*S_ + q0 + r) * D_ + hh * HD_ + lane] = f2bf(oa[r] / l[r]);
}

// ------------------------------------------------- weight transpose fp32->bf16
__global__ __launch_bounds__(256) void wt_k(const float* __restrict__ W,
                                            ushort_t* __restrict__ Wt,
                                            int K, int N) {
    __shared__ float t[32][33];
    int k0 = blockIdx.y << 5, n0 = blockIdx.x << 5;
    int r = threadIdx.x >> 3, c4 = (threadIdx.x & 7) << 2;
    float4 v = *(const float4*)(W + (size_t)(k0 + r) * N + n0 + c4);
    t[r][c4+0] = v.x; t[r][c4+1] = v.y; t[r][c4+2] = v.z; t[r][c4+3] = v.w;
    __syncthreads();
    ushort4 o;
    o.x = f2bf(t[c4+0][r]); o.y = f2bf(t[c4+1][r]);
    o.z = f2bf(t[c4+2][r]); o.w = f2bf(t[c4+3][r]);
    *(ushort4*)(Wt + (size_t)(n0 + r) * K + k0 + c4) = o;
}

// ---------------------------------------------------------------- GEMM fp32
// Kept for layer-0 QKV only (sharp-softmax precision). C = A @ B, B [K][N].
#define BM 64
#define BN 64
#define BK 16
__global__ __launch_bounds__(256) void gemm_k(const float* __restrict__ A,
                                              const float* __restrict__ Bm,
                                              float* __restrict__ C,
                                              int M, int N, int K) {
    __shared__ float As[BK][BM + 4];
    __shared__ float Bs[BK][BN];
    int bm = blockIdx.y * BM;
    int bn = blockIdx.x * BN;
    int tid = threadIdx.x;
    int tm = (tid >> 4) * 4;
    int tn = (tid & 15) * 4;
    int aRow = tid >> 2;
    int aCol = (tid & 3) * 4;
    int bRow = tid >> 4;
    int bCol = (tid & 15) * 4;
    const float* Aptr = A + (size_t)(bm + aRow) * K + aCol;
    const float* Bptr = Bm + (size_t)bRow * N + bn + bCol;
    float acc[4][4] = {};
    for (int k0 = 0; k0 < K; k0 += BK) {
        float4 av = *(const float4*)(Aptr + k0);
        float4 bv = *(const float4*)(Bptr + (size_t)k0 * N);
        __syncthreads();
        As[aCol + 0][aRow] = av.x;
        As[aCol + 1][aRow] = av.y;
        As[aCol + 2][aRow] = av.z;
        As[aCol + 3][aRow] = av.w;
        *(float4*)&Bs[bRow][bCol] = bv;
        __syncthreads();
        #pragma unroll
        for (int k = 0; k < BK; ++k) {
            float4 a4 = *(const float4*)&As[k][tm];
            float4 b4 = *(const float4*)&Bs[k][tn];
            acc[0][0] += a4.x * b4.x; acc[0][1] += a4.x * b4.y;
            acc[0][2] += a4.x * b4.z; acc[0][3] += a4.x * b4.w;
            acc[1][0] += a4.y * b4.x; acc[1][1] += a4.y * b4.y;
            acc[1][2] += a4.y * b4.z; acc[1][3] += a4.y * b4.w;
            acc[2][0] += a4.z * b4.x; acc[2][1] += a4.z * b4.y;
            acc[2][2] += a4.z * b4.z; acc[2][3] += a4.z * b4.w;
            acc[3][0] += a4.w * b4.x; acc[3][1] += a4.w * b4.y;
            acc[3][2] += a4.w * b4.z; acc[3][3] += a4.w * b4.w;
        }
    }
    #pragma unroll
    for (int i = 0; i < 4; ++i) {
        size_t off = (size_t)(bm + tm + i) * N + bn + tn;
        *(float4*)(C + off) = make_float4(acc[i][0], acc[i][1], acc[i][2], acc[i][3]);
    }
}

// ---------------------------------------------------------------- GEMM bf16
__device__ __forceinline__ float gelu_f(float x) {
    return 0.5f * x * (1.f + erff(x * 0.70710678118654752f));
}

__global__ __launch_bounds__(256, 2) void gemm_bf16_k(
    const ushort_t* __restrict__ A,
    const ushort_t* __restrict__ Bt,
    const float* __restrict__ Res,
    float* __restrict__ Cf,
    ushort_t* __restrict__ Cb,
    int M, int N, int K, int epi)
{
    __shared__ __align__(16) ushort_t As[128 * 64];
    __shared__ __align__(16) ushort_t Bs[128 * 64];
    int tid = threadIdx.x;
    int wid = tid >> 6, lane = tid & 63;
    int wm = wid >> 1, wn = wid & 1;
    int bm = blockIdx.y * 128, bn = blockIdx.x * 128;

    f32x4_t acc[4][4];
    #pragma unroll
    for (int m = 0; m < 4; ++m)
        #pragma unroll
        for (int n = 0; n < 4; ++n)
            acc[m][n] = (f32x4_t){0.f, 0.f, 0.f, 0.f};

    int srow = (lane >> 3);
    int scol = (lane & 7) * 8;

    for (int k0 = 0; k0 < K; k0 += 64) {
        __syncthreads();
        #pragma unroll
        for (int i = 0; i < 4; ++i) {
            int rb = i * 32 + wid * 8;
            gload_lds16(A  + (size_t)(bm + rb + srow) * K + k0 + scol, &As[rb * 64]);
            gload_lds16(Bt + (size_t)(bn + rb + srow) * K + k0 + scol, &Bs[rb * 64]);
        }
        __syncthreads();
        #pragma unroll
        for (int kk = 0; kk < 64; kk += 32) {
            bf16x8_t af[4], bfr[4];
            int kof = kk + (lane >> 4) * 8;
            #pragma unroll
            for (int m = 0; m < 4; ++m) {
                int r = wm * 64 + m * 16 + (lane & 15);
                af[m] = *(const bf16x8_t*)&As[r * 64 + kof];
            }
            #pragma unroll
            for (int n = 0; n < 4; ++n) {
                int r = wn * 64 + n * 16 + (lane & 15);
                bfr[n] = *(const bf16x8_t*)&Bs[r * 64 + kof];
            }
            #pragma unroll
            for (int m = 0; m < 4; ++m)
                #pragma unroll
                for (int n = 0; n < 4; ++n)
                    acc[m][n] = __builtin_amdgcn_mfma_f32_16x16x32_bf16(
                        af[m], bfr[n], acc[m][n], 0, 0, 0);
        }
    }

    int cr = (lane >> 4) * 4, cc = lane & 15;
    #pragma unroll
    for (int m = 0; m < 4; ++m) {
        int row = bm + wm * 64 + m * 16 + cr;
        #pragma unroll
        for (int n = 0; n < 4; ++n) {
            int col = bn + wn * 64 + n * 16 + cc;
            #pragma unroll
            for (int j = 0; j < 4; ++j) {
                size_t off = (size_t)(row + j) * N + col;
                float v = acc[m][n][j];
                if (epi == 0) {
                    Cf[off] = v;
                } else if (epi == 1) {
                    Cf[off] = Res[off] + v;
                } else {
                    Cb[off] = f2bf(gelu_f(v));
                }
            }
        }
    }
}

// ---------------------------------------------------------------- launch
extern "C" void kernel_launch(void* const* d_in, const int* in_sizes, int n_in,
                              void* d_out, int out_size, void* d_ws, size_t ws_size,
                              hipStream_t stream) {
    const int*   x    = (const int*)  d_in[0];
    const float* emb  = (const float*)d_in[1];
    const float* ln1w = (const float*)d_in[2];
    const float* ln1b = (const float*)d_in[3];
    const float* Wqkv = (const float*)d_in[4];
    const float* Wo   = (const float*)d_in[5];
    const float* ln2w = (const float*)d_in[6];
    const float* ln2b = (const float*)d_in[7];
    const float* W1   = (const float*)d_in[8];
    const float* W2   = (const float*)d_in[9];
    const float* lnfw = (const float*)d_in[10];
    const float* lnfb = (const float*)d_in[11];
    const float* Wdec = (const float*)d_in[12];
    float* out = (float*)d_out;

    // ---- workspace layout (bytes), lifetime-aliased, 80 MB total ----
    char* ws = (char*)d_ws;
    float*    h     = (float*)   (ws + 0);              // 8 MB  [2048,1024] f32
    ushort_t* xnb   = (ushort_t*)(ws + (8u<<20));       // 4 MB  [2048,1024] bf16
    ushort_t* ob    = (ushort_t*)(ws + (12u<<20));      // 4 MB  [2048,1024] bf16
    float*    qkv   = (float*)   (ws + (16u<<20));      // 24 MB [2048,3072] f32
    ushort_t* ffb   = (ushort_t*)(ws + (40u<<20));      // 16 MB [2048,4096] bf16
    ushort_t* wqkvT = (ushort_t*)(ws + (56u<<20));      // 6 MB  [3072,1024] bf16
    ushort_t* woT   = (ushort_t*)(ws + (62u<<20));      // 2 MB  [1024,1024] bf16
    ushort_t* w1T   = (ushort_t*)(ws + (64u<<20));      // 8 MB  [4096,1024] bf16
    ushort_t* w2T   = (ushort_t*)(ws + (72u<<20));      // 8 MB  [1024,4096] bf16
    float*    xn    = (float*)   (ws + (64u<<20));      // 8 MB, aliases w1T (l=0 only, dead before wt(W1))
    ushort_t* wdecT = (ushort_t*)(ws + (16u<<20));      // 64 MB, aliases qkv..w2T (post-loop)

    embed_k<<<M_, 256, 0, stream>>>(x, emb, h);
    for (int l = 0; l < L_; ++l) {
        if (l == 0) {
            layernorm_k<<<M_, 256, 0, stream>>>(h, ln1w, ln1b, xn, xnb);
            gemm_k<<<dim3(3*D_/BN, M_/BM), 256, 0, stream>>>(
                xn, Wqkv, qkv, M_, 3*D_, D_);
        } else {
            layernorm_k<<<M_, 256, 0, stream>>>(h, ln1w + l*D_, ln1b + l*D_, nullptr, xnb);
            wt_k<<<dim3(3*D_/32, D_/32), 256, 0, stream>>>(
                Wqkv + (size_t)l*D_*3*D_, wqkvT, D_, 3*D_);
            gemm_bf16_k<<<dim3(3*D_/128, M_/128), 256, 0, stream>>>(
                xnb, wqkvT, nullptr, qkv, nullptr, M_, 3*D_, D_, 0);
        }
        rope_k<<<(M_*H_*32)/256, 256, 0, stream>>>(qkv);
        attn_tile_k<<<B_*H_*(S_/16), 256, 0, stream>>>(qkv, ob);
        wt_k<<<dim3(D_/32, D_/32), 256, 0, stream>>>(
            Wo + (size_t)l*D_*D_, woT, D_, D_);
        gemm_bf16_k<<<dim3(D_/128, M_/128), 256, 0, stream>>>(
            ob, woT, h, h, nullptr, M_, D_, D_, 1);
        layernorm_k<<<M_, 256, 0, stream>>>(h, ln2w + l*D_, ln2b + l*D_, nullptr, xnb);
        wt_k<<<dim3(DFF_/32, D_/32), 256, 0, stream>>>(
            W1 + (size_t)l*D_*DFF_, w1T, D_, DFF_);
        gemm_bf16_k<<<dim3(DFF_/128, M_/128), 256, 0, stream>>>(
            xnb, w1T, nullptr, nullptr, ffb, M_, DFF_, D_, 2);
        wt_k<<<dim3(D_/32, DFF_/32), 256, 0, stream>>>(
            W2 + (size_t)l*DFF_*D_, w2T, DFF_, D_);
        gemm_bf16_k<<<dim3(D_/128, M_/128), 256, 0, stream>>>(
            ffb, w2T, h, h, nullptr, M_, D_, DFF_, 1);
    }
    layernorm_k<<<M_, 256, 0, stream>>>(h, lnfw, lnfb, nullptr, xnb);
    wt_k<<<dim3(V_/32, D_/32), 256, 0, stream>>>(Wdec, wdecT, D_, V_);
    gemm_bf16_k<<<dim3(V_/128, M_/128), 256, 0, stream>>>(
        xnb, wdecT, nullptr, out, nullptr, M_, V_, D_, 0);
}

// Round 5
// 2880.192 us; speedup vs baseline: 6.6441x; 1.8060x over previous
//
#include <hip/hip_runtime.h>
#include <hip/hip_bf16.h>
#include <math.h>

#define B_ 2
#define S_ 1024
#define D_ 1024
#define H_ 16
#define HD_ 64
#define L_ 8
#define DFF_ 4096
#define V_ 32000
#define M_ (B_*S_)   /* 2048 rows */

typedef unsigned short ushort_t;
typedef __attribute__((ext_vector_type(8))) __bf16 bf16x8_t;
typedef __attribute__((ext_vector_type(4))) float f32x4_t;

__device__ __forceinline__ ushort_t f2bf(float f) {
    union { float f; unsigned u; } x; x.f = f;
    unsigned r = x.u + 0x7fffu + ((x.u >> 16) & 1u);
    return (ushort_t)(r >> 16);
}

__device__ __forceinline__ void gload_lds16(const void* g, void* l) {
    __builtin_amdgcn_global_load_lds(
        (const __attribute__((address_space(1))) void*)g,
        (__attribute__((address_space(3))) void*)l, 16, 0, 0);
}

// ---------------------------------------------------------------- embedding
__global__ __launch_bounds__(256) void embed_k(const int* __restrict__ x,
                                               const float* __restrict__ emb,
                                               float* __restrict__ h) {
    int row = blockIdx.x;
    int tok = x[row];
    const float4* src = (const float4*)(emb + (size_t)tok * D_);
    float4* dst = (float4*)(h + (size_t)row * D_);
    dst[threadIdx.x] = src[threadIdx.x];
}

// ---------------------------------------------------------------- layernorm
// Faithful: out = w*(x-m)/(var + 1e-12) + b   (NO sqrt).
__global__ __launch_bounds__(256) void layernorm_k(const float* __restrict__ x,
                                                   const float* __restrict__ w,
                                                   const float* __restrict__ bb,
                                                   float* __restrict__ out32,
                                                   ushort_t* __restrict__ out16) {
    int row = blockIdx.x;
    const float4* xr = (const float4*)(x + (size_t)row * D_);
    float4 v = xr[threadIdx.x];
    float s = v.x + v.y + v.z + v.w;
    #pragma unroll
    for (int off = 32; off; off >>= 1) s += __shfl_xor(s, off);
    __shared__ float red1[4];
    __shared__ float red2[4];
    int wave = threadIdx.x >> 6, lane = threadIdx.x & 63;
    if (lane == 0) red1[wave] = s;
    __syncthreads();
    float m = (red1[0] + red1[1] + red1[2] + red1[3]) * (1.f / 1024.f);
    float dx = v.x - m, dy = v.y - m, dz = v.z - m, dw = v.w - m;
    float ss = dx*dx + dy*dy + dz*dz + dw*dw;
    #pragma unroll
    for (int off = 32; off; off >>= 1) ss += __shfl_xor(ss, off);
    if (lane == 0) red2[wave] = ss;
    __syncthreads();
    float var = (red2[0] + red2[1] + red2[2] + red2[3]) * (1.f / 1024.f);
    float inv = 1.f / (var + 1e-12f);
    float4 wv = ((const float4*)w)[threadIdx.x];
    float4 bv = ((const float4*)bb)[threadIdx.x];
    float4 ov;
    ov.x = wv.x * dx * inv + bv.x;
    ov.y = wv.y * dy * inv + bv.y;
    ov.z = wv.z * dz * inv + bv.z;
    ov.w = wv.w * dw * inv + bv.w;
    if (out32) ((float4*)(out32 + (size_t)row * D_))[threadIdx.x] = ov;
    ushort4 ob;
    ob.x = f2bf(ov.x); ob.y = f2bf(ov.y); ob.z = f2bf(ov.z); ob.w = f2bf(ov.w);
    ((ushort4*)(out16 + (size_t)row * D_))[threadIdx.x] = ob;
}

// ---------------------------------------------------------------- RoPE (fp32, layer 0 path)
// Faithful quirk: angle = head_index * inv_freq(pair)  (broadcast over seq)
__global__ __launch_bounds__(256) void rope_k(float* __restrict__ qkv) {
    int idx = blockIdx.x * 256 + threadIdx.x;
    int i  = idx & 31;
    int hh = (idx >> 5) & 15;
    int row = idx >> 9;
    float e = (2.f * (float)i) / 64.f;
    float inv = powf(10000.f, -e);
    float ang = (float)hh * inv;
    float sn, cs;
    sincosf(ang, &sn, &cs);
    float* qb = qkv + (size_t)row * (3*D_) + hh * (3*HD_) + 2*i;
    float a = qb[0], b = qb[1];
    qb[0] = a*cs - b*sn; qb[1] = a*sn + b*cs;
    float* kb = qb + HD_;
    a = kb[0]; b = kb[1];
    kb[0] = a*cs - b*sn; kb[1] = a*sn + b*cs;
}

// ---------------------------------------------------------------- fp32 flash attn (layer 0 only)
__global__ __launch_bounds__(256) void attn_tile_k(const float* __restrict__ qkv,
                                                   ushort_t* __restrict__ o) {
    __shared__ float Kt[64][65];
    __shared__ float Vs[64][68];
    __shared__ float qs[16][68];
    __shared__ float ps[16][68];
    int gid = blockIdx.x;
    int qt = 63 - (gid & 63);
    int bh = gid >> 6;
    int hh = bh & (H_ - 1);
    int bb = bh >> 4;
    int tid = threadIdx.x, wv = tid >> 6, lane = tid & 63;
    const float* base = qkv + (size_t)bb * S_ * (3*D_) + hh * (3*HD_);

    {
        int r = tid >> 4, d0 = (tid & 15) * 4;
        float4 qv = *(const float4*)(base + (size_t)(qt*16 + r) * (3*D_) + d0);
        float4 qsc = make_float4(qv.x*0.125f, qv.y*0.125f, qv.z*0.125f, qv.w*0.125f);
        *(float4*)&qs[r][d0] = qsc;
    }

    int q0 = qt*16 + wv*4;
    float m[4], l[4] = {0.f,0.f,0.f,0.f}, oa[4] = {0.f,0.f,0.f,0.f};
    m[0] = m[1] = m[2] = m[3] = -INFINITY;
    int ntile = (qt*16 + 15) / 64 + 1;

    int jr = tid >> 2;
    int c0 = (tid & 3) * 16;

    for (int t = 0; t < ntile; ++t) {
        __syncthreads();
        const float* kp = base + (size_t)(t*64 + jr) * (3*D_) + HD_;
        float4 ka = *(const float4*)(kp + c0 + 0);
        float4 kb = *(const float4*)(kp + c0 + 4);
        float4 kc = *(const float4*)(kp + c0 + 8);
        float4 kd = *(const float4*)(kp + c0 + 12);
        Kt[c0+ 0][jr] = ka.x; Kt[c0+ 1][jr] = ka.y;
        Kt[c0+ 2][jr] = ka.z; Kt[c0+ 3][jr] = ka.w;
        Kt[c0+ 4][jr] = kb.x; Kt[c0+ 5][jr] = kb.y;
        Kt[c0+ 6][jr] = kb.z; Kt[c0+ 7][jr] = kb.w;
        Kt[c0+ 8][jr] = kc.x; Kt[c0+ 9][jr] = kc.y;
        Kt[c0+10][jr] = kc.z; Kt[c0+11][jr] = kc.w;
        Kt[c0+12][jr] = kd.x; Kt[c0+13][jr] = kd.y;
        Kt[c0+14][jr] = kd.z; Kt[c0+15][jr] = kd.w;
        const float* vp = kp + HD_;
        *(float4*)&Vs[jr][c0+ 0] = *(const float4*)(vp + c0 + 0);
        *(float4*)&Vs[jr][c0+ 4] = *(const float4*)(vp + c0 + 4);
        *(float4*)&Vs[jr][c0+ 8] = *(const float4*)(vp + c0 + 8);
        *(float4*)&Vs[jr][c0+12] = *(const float4*)(vp + c0 + 12);
        __syncthreads();

        float s[4] = {0.f, 0.f, 0.f, 0.f};
        #pragma unroll
        for (int d0 = 0; d0 < 64; d0 += 4) {
            float k0 = Kt[d0+0][lane], k1 = Kt[d0+1][lane],
                  k2 = Kt[d0+2][lane], k3 = Kt[d0+3][lane];
            #pragma unroll
            for (int r = 0; r < 4; ++r) {
                float4 q4 = *(const float4*)&qs[wv*4+r][d0];
                s[r] += q4.x*k0 + q4.y*k1 + q4.z*k2 + q4.w*k3;
            }
        }

        int jj = t*64 + lane;
        float scale[4];
        #pragma unroll
        for (int r = 0; r < 4; ++r) {
            float sv = (jj <= q0 + r) ? s[r] : -INFINITY;
            float mx = sv;
            #pragma unroll
            for (int off = 32; off; off >>= 1) mx = fmaxf(mx, __shfl_xor(mx, off));
            float mn = fmaxf(m[r], mx);
            float sc = __expf(m[r] - mn);
            float p  = __expf(sv - mn);
            float sm = p;
            #pragma unroll
            for (int off = 32; off; off >>= 1) sm += __shfl_xor(sm, off);
            l[r] = l[r] * sc + sm;
            m[r] = mn;
            scale[r] = sc;
            ps[wv*4+r][lane] = p;
        }

        #pragma unroll
        for (int r = 0; r < 4; ++r) oa[r] *= scale[r];
        #pragma unroll
        for (int j0 = 0; j0 < 64; j0 += 4) {
            float v0 = Vs[j0+0][lane], v1 = Vs[j0+1][lane],
                  v2 = Vs[j0+2][lane], v3 = Vs[j0+3][lane];
            #pragma unroll
            for (int r = 0; r < 4; ++r) {
                float4 p4 = *(const float4*)&ps[wv*4+r][j0];
                oa[r] += p4.x*v0 + p4.y*v1 + p4.z*v2 + p4.w*v3;
            }
        }
    }
    #pragma unroll
    for (int r = 0; r < 4; ++r)
        o[(size_t)(bb*S_ + q0 + r) * D_ + hh * HD_ + lane] = f2bf(oa[r] / l[r]);
}

// ------------------------------------------- qkv fp32 -> rope'd bf16 q/k + vT
// q_bf/k_bf: [bh][s][64] (q pre-scaled by 0.125); vT_bf: [bh][d][s].
__global__ __launch_bounds__(256) void qkv_cvt_k(const float* __restrict__ qkv,
                                                 ushort_t* __restrict__ qb,
                                                 ushort_t* __restrict__ kb,
                                                 ushort_t* __restrict__ vtb) {
    __shared__ float t[64][68];
    int blk = blockIdx.x;
    int st = blk & 15, bh = blk >> 4;
    int hh = bh & 15, bb = bh >> 4;
    int tid = threadIdx.x;
    int sr = tid >> 2, c4 = tid & 3;
    const float* base = qkv + (size_t)(bb*S_ + st*64 + sr) * (3*D_) + hh*192;
    // ---- q,k rope + bf16
    float qv[16], kv[16];
    #pragma unroll
    for (int p = 0; p < 4; ++p) {
        float4 a = *(const float4*)(base + c4*16 + 4*p);
        float4 b = *(const float4*)(base + 64 + c4*16 + 4*p);
        qv[4*p+0]=a.x; qv[4*p+1]=a.y; qv[4*p+2]=a.z; qv[4*p+3]=a.w;
        kv[4*p+0]=b.x; kv[4*p+1]=b.y; kv[4*p+2]=b.z; kv[4*p+3]=b.w;
    }
    ushort_t qo[16], ko[16];
    #pragma unroll
    for (int p = 0; p < 8; ++p) {
        int i = c4*8 + p;
        float inv = exp2f((float)i * (-13.287712379549449f / 32.f));
        float ang = (float)hh * inv;
        float sn, cs;
        sincosf(ang, &sn, &cs);
        float a = qv[2*p], b = qv[2*p+1];
        qo[2*p]   = f2bf((a*cs - b*sn) * 0.125f);
        qo[2*p+1] = f2bf((a*sn + b*cs) * 0.125f);
        a = kv[2*p]; b = kv[2*p+1];
        ko[2*p]   = f2bf(a*cs - b*sn);
        ko[2*p+1] = f2bf(a*sn + b*cs);
    }
    size_t rowo = ((size_t)bh*S_ + st*64 + sr) * 64 + c4*16;
    *(uint4*)(qb + rowo)     = *(uint4*)&qo[0];
    *(uint4*)(qb + rowo + 8) = *(uint4*)&qo[8];
    *(uint4*)(kb + rowo)     = *(uint4*)&ko[0];
    *(uint4*)(kb + rowo + 8) = *(uint4*)&ko[8];
    // ---- v transpose
    #pragma unroll
    for (int p = 0; p < 4; ++p)
        *(float4*)&t[sr][c4*16 + 4*p] = *(const float4*)(base + 128 + c4*16 + 4*p);
    __syncthreads();
    int d = tid >> 2, s0 = (tid & 3) * 16;
    ushort_t vo[16];
    #pragma unroll
    for (int u = 0; u < 16; ++u) vo[u] = f2bf(t[s0+u][d]);
    size_t vout = ((size_t)bh*64 + d) * S_ + st*64 + s0;
    *(uint4*)(vtb + vout)     = *(uint4*)&vo[0];
    *(uint4*)(vtb + vout + 8) = *(uint4*)&vo[8];
}

// ------------------------------------------- bf16 MFMA flash attn (layers>=1)
// Block = 4 waves, 64 q-rows of one (b,h). 16x16x32 MFMA; fp32 softmax state.
// K_lds[key][64d], Vt_lds[d][64key], P_lds per-wave [16][64], all XOR-swizzled
// (byte ^= (row&7)<<4) so b128 reads are 2-way (free) instead of 16-way.
__global__ __launch_bounds__(256) void attn_mfma_k(const ushort_t* __restrict__ qb,
                                                   const ushort_t* __restrict__ kb,
                                                   const ushort_t* __restrict__ vtb,
                                                   ushort_t* __restrict__ o) {
    __shared__ __align__(16) char Kl[8192];
    __shared__ __align__(16) char Vl[8192];
    __shared__ __align__(16) char Pl[8192];
    int blk = blockIdx.x;
    int qt = 15 - (blk & 15);            // longest first
    int bh = blk >> 4;
    int hh = bh & 15, bb = bh >> 4;
    int tid = threadIdx.x, w = tid >> 6, lane = tid & 63;
    int lg = lane >> 4, lr = lane & 15;

    // Q fragments (A-operand): row = lr, k-chunk = lg*8 (+32)
    const ushort_t* qhb = qb + ((size_t)bh*S_ + qt*64 + w*16 + lr) * 64;
    bf16x8_t aq0 = *(const bf16x8_t*)(qhb + lg*8);
    bf16x8_t aq1 = *(const bf16x8_t*)(qhb + 32 + lg*8);

    f32x4_t oacc[4];
    #pragma unroll
    for (int n = 0; n < 4; ++n) oacc[n] = (f32x4_t){0.f,0.f,0.f,0.f};
    float m[4] = {-3.0e38f,-3.0e38f,-3.0e38f,-3.0e38f};
    float l[4] = {0.f,0.f,0.f,0.f};

    int srow = tid >> 2;                 // staging row 0..63
    int soff = (tid & 3) * 32;           // byte offset in 128B row
    const ushort_t* kg = kb  + (size_t)bh * S_ * 64;
    const ushort_t* vg = vtb + (size_t)bh * 64 * S_;

    for (int kt = 0; kt <= qt; ++kt) {
        __syncthreads();
        {   // stage K tile: K_lds[key][d], swizzled
            const ushort_t* src = kg + (size_t)(kt*64 + srow) * 64 + soff/2;
            uint4 v0 = *(const uint4*)src;
            uint4 v1 = *(const uint4*)(src + 8);
            int b0 = (srow*128 + soff) ^ ((srow & 7) << 4);
            int b1 = (srow*128 + soff + 16) ^ ((srow & 7) << 4);
            *(uint4*)(Kl + b0) = v0;
            *(uint4*)(Kl + b1) = v1;
            // stage Vt tile: Vt_lds[d][key], swizzled
            const ushort_t* vs = vg + (size_t)srow * S_ + kt*64 + soff/2;
            uint4 u0 = *(const uint4*)vs;
            uint4 u1 = *(const uint4*)(vs + 8);
            *(uint4*)(Vl + b0) = u0;
            *(uint4*)(Vl + b1) = u1;
        }
        __syncthreads();

        // ---- QK^T: 8 MFMAs -> scores s[n][j], col=key(lr+16n), row=lg*4+j
        f32x4_t sfr[4];
        #pragma unroll
        for (int n = 0; n < 4; ++n) sfr[n] = (f32x4_t){0.f,0.f,0.f,0.f};
        #pragma unroll
        for (int n = 0; n < 4; ++n) {
            int row = n*16 + lr;
            int swz = (row & 7) << 4;
            bf16x8_t b0 = *(const bf16x8_t*)(Kl + ((row*128 + lg*16) ^ swz));
            bf16x8_t b1 = *(const bf16x8_t*)(Kl + ((row*128 + 64 + lg*16) ^ swz));
            sfr[n] = __builtin_amdgcn_mfma_f32_16x16x32_bf16(aq0, b0, sfr[n], 0,0,0);
            sfr[n] = __builtin_amdgcn_mfma_f32_16x16x32_bf16(aq1, b1, sfr[n], 0,0,0);
        }

        // ---- causal mask (diagonal tile only)
        if (kt == qt) {
            #pragma unroll
            for (int n = 0; n < 4; ++n) {
                int key = n*16 + lr;
                #pragma unroll
                for (int j = 0; j < 4; ++j) {
                    int qrow = w*16 + lg*4 + j;
                    if (key > qrow) sfr[n][j] = -3.0e38f;
                }
            }
        }

        // ---- online softmax (rows in 16-lane groups -> 4 shuffle steps)
        float sc[4];
        #pragma unroll
        for (int j = 0; j < 4; ++j) {
            float v = fmaxf(fmaxf(sfr[0][j], sfr[1][j]), fmaxf(sfr[2][j], sfr[3][j]));
            v = fmaxf(v, __shfl_xor(v, 1));
            v = fmaxf(v, __shfl_xor(v, 2));
            v = fmaxf(v, __shfl_xor(v, 4));
            v = fmaxf(v, __shfl_xor(v, 8));
            float mn = fmaxf(m[j], v);
            sc[j] = __expf(m[j] - mn);
            m[j] = mn;
        }
        #pragma unroll
        for (int n = 0; n < 4; ++n)
            #pragma unroll
            for (int j = 0; j < 4; ++j)
                sfr[n][j] = __expf(sfr[n][j] - m[j]);
        #pragma unroll
        for (int j = 0; j < 4; ++j) {
            float s = sfr[0][j] + sfr[1][j] + sfr[2][j] + sfr[3][j];
            s += __shfl_xor(s, 1);
            s += __shfl_xor(s, 2);
            s += __shfl_xor(s, 4);
            s += __shfl_xor(s, 8);
            l[j] = l[j] * sc[j] + s;
            #pragma unroll
            for (int n = 0; n < 4; ++n) oacc[n][j] *= sc[j];
        }

        // ---- P -> per-wave LDS (bf16, swizzled) to reshape into A-fragments
        #pragma unroll
        for (int n = 0; n < 4; ++n) {
            #pragma unroll
            for (int j = 0; j < 4; ++j) {
                int row = lg*4 + j;
                int byt = (w*2048 + row*128 + (n*16 + lr)*2) ^ ((row & 7) << 4);
                *(ushort_t*)(Pl + byt) = f2bf(sfr[n][j]);
            }
        }
        int pswz = (lr & 7) << 4;
        bf16x8_t pa0 = *(const bf16x8_t*)(Pl + ((w*2048 + lr*128 + lg*16) ^ pswz));
        bf16x8_t pa1 = *(const bf16x8_t*)(Pl + ((w*2048 + lr*128 + 64 + lg*16) ^ pswz));

        // ---- PV: 8 MFMAs, B-frag from Vt (col=d, k=key)
        #pragma unroll
        for (int n = 0; n < 4; ++n) {
            int row = n*16 + lr;
            int swz = (row & 7) << 4;
            bf16x8_t v0 = *(const bf16x8_t*)(Vl + ((row*128 + lg*16) ^ swz));
            bf16x8_t v1 = *(const bf16x8_t*)(Vl + ((row*128 + 64 + lg*16) ^ swz));
            oacc[n] = __builtin_amdgcn_mfma_f32_16x16x32_bf16(pa0, v0, oacc[n], 0,0,0);
            oacc[n] = __builtin_amdgcn_mfma_f32_16x16x32_bf16(pa1, v1, oacc[n], 0,0,0);
        }
    }

    // ---- epilogue
    #pragma unroll
    for (int j = 0; j < 4; ++j) {
        float rl = 1.f / l[j];
        int row = qt*64 + w*16 + lg*4 + j;
        size_t base = (size_t)(bb*S_ + row) * D_ + hh*64;
        #pragma unroll
        for (int n = 0; n < 4; ++n)
            o[base + n*16 + lr] = f2bf(oacc[n][j] * rl);
    }
}

// ------------------------------------------------- weight transpose fp32->bf16
__global__ __launch_bounds__(256) void wt_k(const float* __restrict__ W,
                                            ushort_t* __restrict__ Wt,
                                            int K, int N) {
    __shared__ float t[32][33];
    int k0 = blockIdx.y << 5, n0 = blockIdx.x << 5;
    int r = threadIdx.x >> 3, c4 = (threadIdx.x & 7) << 2;
    float4 v = *(const float4*)(W + (size_t)(k0 + r) * N + n0 + c4);
    t[r][c4+0] = v.x; t[r][c4+1] = v.y; t[r][c4+2] = v.z; t[r][c4+3] = v.w;
    __syncthreads();
    ushort4 o;
    o.x = f2bf(t[c4+0][r]); o.y = f2bf(t[c4+1][r]);
    o.z = f2bf(t[c4+2][r]); o.w = f2bf(t[c4+3][r]);
    *(ushort4*)(Wt + (size_t)(n0 + r) * K + k0 + c4) = o;
}

// ---------------------------------------------------------------- GEMM fp32 (layer-0 QKV)
#define BM 64
#define BN 64
#define BK 16
__global__ __launch_bounds__(256) void gemm_k(const float* __restrict__ A,
                                              const float* __restrict__ Bm,
                                              float* __restrict__ C,
                                              int M, int N, int K) {
    __shared__ float As[BK][BM + 4];
    __shared__ float Bs[BK][BN];
    int bm = blockIdx.y * BM;
    int bn = blockIdx.x * BN;
    int tid = threadIdx.x;
    int tm = (tid >> 4) * 4;
    int tn = (tid & 15) * 4;
    int aRow = tid >> 2;
    int aCol = (tid & 3) * 4;
    int bRow = tid >> 4;
    int bCol = (tid & 15) * 4;
    const float* Aptr = A + (size_t)(bm + aRow) * K + aCol;
    const float* Bptr = Bm + (size_t)bRow * N + bn + bCol;
    float acc[4][4] = {};
    for (int k0 = 0; k0 < K; k0 += BK) {
        float4 av = *(const float4*)(Aptr + k0);
        float4 bv = *(const float4*)(Bptr + (size_t)k0 * N);
        __syncthreads();
        As[aCol + 0][aRow] = av.x;
        As[aCol + 1][aRow] = av.y;
        As[aCol + 2][aRow] = av.z;
        As[aCol + 3][aRow] = av.w;
        *(float4*)&Bs[bRow][bCol] = bv;
        __syncthreads();
        #pragma unroll
        for (int k = 0; k < BK; ++k) {
            float4 a4 = *(const float4*)&As[k][tm];
            float4 b4 = *(const float4*)&Bs[k][tn];
            acc[0][0] += a4.x * b4.x; acc[0][1] += a4.x * b4.y;
            acc[0][2] += a4.x * b4.z; acc[0][3] += a4.x * b4.w;
            acc[1][0] += a4.y * b4.x; acc[1][1] += a4.y * b4.y;
            acc[1][2] += a4.y * b4.z; acc[1][3] += a4.y * b4.w;
            acc[2][0] += a4.z * b4.x; acc[2][1] += a4.z * b4.y;
            acc[2][2] += a4.z * b4.z; acc[2][3] += a4.z * b4.w;
            acc[3][0] += a4.w * b4.x; acc[3][1] += a4.w * b4.y;
            acc[3][2] += a4.w * b4.z; acc[3][3] += a4.w * b4.w;
        }
    }
    #pragma unroll
    for (int i = 0; i < 4; ++i) {
        size_t off = (size_t)(bm + tm + i) * N + bn + tn;
        *(float4*)(C + off) = make_float4(acc[i][0], acc[i][1], acc[i][2], acc[i][3]);
    }
}

// ---------------------------------------------------------------- GEMM bf16
__device__ __forceinline__ float gelu_f(float x) {
    return 0.5f * x * (1.f + erff(x * 0.70710678118654752f));
}

__global__ __launch_bounds__(256, 2) void gemm_bf16_k(
    const ushort_t* __restrict__ A,
    const ushort_t* __restrict__ Bt,
    const float* __restrict__ Res,
    float* __restrict__ Cf,
    ushort_t* __restrict__ Cb,
    int M, int N, int K, int epi)
{
    __shared__ __align__(16) ushort_t As[128 * 64];
    __shared__ __align__(16) ushort_t Bs[128 * 64];
    int tid = threadIdx.x;
    int wid = tid >> 6, lane = tid & 63;
    int wm = wid >> 1, wn = wid & 1;
    int bm = blockIdx.y * 128, bn = blockIdx.x * 128;

    f32x4_t acc[4][4];
    #pragma unroll
    for (int m = 0; m < 4; ++m)
        #pragma unroll
        for (int n = 0; n < 4; ++n)
            acc[m][n] = (f32x4_t){0.f, 0.f, 0.f, 0.f};

    int srow = (lane >> 3);
    int scol = (lane & 7) * 8;

    for (int k0 = 0; k0 < K; k0 += 64) {
        __syncthreads();
        #pragma unroll
        for (int i = 0; i < 4; ++i) {
            int rb = i * 32 + wid * 8;
            gload_lds16(A  + (size_t)(bm + rb + srow) * K + k0 + scol, &As[rb * 64]);
            gload_lds16(Bt + (size_t)(bn + rb + srow) * K + k0 + scol, &Bs[rb * 64]);
        }
        __syncthreads();
        #pragma unroll
        for (int kk = 0; kk < 64; kk += 32) {
            bf16x8_t af[4], bfr[4];
            int kof = kk + (lane >> 4) * 8;
            #pragma unroll
            for (int m = 0; m < 4; ++m) {
                int r = wm * 64 + m * 16 + (lane & 15);
                af[m] = *(const bf16x8_t*)&As[r * 64 + kof];
            }
            #pragma unroll
            for (int n = 0; n < 4; ++n) {
                int r = wn * 64 + n * 16 + (lane & 15);
                bfr[n] = *(const bf16x8_t*)&Bs[r * 64 + kof];
            }
            #pragma unroll
            for (int m = 0; m < 4; ++m)
                #pragma unroll
                for (int n = 0; n < 4; ++n)
                    acc[m][n] = __builtin_amdgcn_mfma_f32_16x16x32_bf16(
                        af[m], bfr[n], acc[m][n], 0, 0, 0);
        }
    }

    int cr = (lane >> 4) * 4, cc = lane & 15;
    #pragma unroll
    for (int m = 0; m < 4; ++m) {
        int row = bm + wm * 64 + m * 16 + cr;
        #pragma unroll
        for (int n = 0; n < 4; ++n) {
            int col = bn + wn * 64 + n * 16 + cc;
            #pragma unroll
            for (int j = 0; j < 4; ++j) {
                size_t off = (size_t)(row + j) * N + col;
                float v = acc[m][n][j];
                if (epi == 0) {
                    Cf[off] = v;
                } else if (epi == 1) {
                    Cf[off] = Res[off] + v;
                } else {
                    Cb[off] = f2bf(gelu_f(v));
                }
            }
        }
    }
}

// ---------------------------------------------------------------- launch
extern "C" void kernel_launch(void* const* d_in, const int* in_sizes, int n_in,
                              void* d_out, int out_size, void* d_ws, size_t ws_size,
                              hipStream_t stream) {
    const int*   x    = (const int*)  d_in[0];
    const float* emb  = (const float*)d_in[1];
    const float* ln1w = (const float*)d_in[2];
    const float* ln1b = (const float*)d_in[3];
    const float* Wqkv = (const float*)d_in[4];
    const float* Wo   = (const float*)d_in[5];
    const float* ln2w = (const float*)d_in[6];
    const float* ln2b = (const float*)d_in[7];
    const float* W1   = (const float*)d_in[8];
    const float* W2   = (const float*)d_in[9];
    const float* lnfw = (const float*)d_in[10];
    const float* lnfb = (const float*)d_in[11];
    const float* Wdec = (const float*)d_in[12];
    float* out = (float*)d_out;

    // ---- workspace layout (bytes), lifetime-aliased, 80 MB total ----
    char* ws = (char*)d_ws;
    float*    h     = (float*)   (ws + 0);              // 8 MB  [2048,1024] f32
    ushort_t* xnb   = (ushort_t*)(ws + (8u<<20));       // 4 MB  [2048,1024] bf16
    ushort_t* ob    = (ushort_t*)(ws + (12u<<20));      // 4 MB  [2048,1024] bf16
    float*    qkv   = (float*)   (ws + (16u<<20));      // 24 MB [2048,3072] f32
    ushort_t* ffb   = (ushort_t*)(ws + (40u<<20));      // 16 MB [2048,4096] bf16 (W1 out)
    ushort_t* q_bf  = (ushort_t*)(ws + (40u<<20));      // 4 MB, aliases ffb (dead then)
    ushort_t* k_bf  = (ushort_t*)(ws + (44u<<20));      // 4 MB
    ushort_t* vT_bf = (ushort_t*)(ws + (48u<<20));      // 4 MB
    ushort_t* wqkvT = (ushort_t*)(ws + (56u<<20));      // 6 MB  [3072,1024] bf16
    ushort_t* woT   = (ushort_t*)(ws + (62u<<20));      // 2 MB  [1024,1024] bf16
    ushort_t* w1T   = (ushort_t*)(ws + (64u<<20));      // 8 MB  [4096,1024] bf16
    ushort_t* w2T   = (ushort_t*)(ws + (72u<<20));      // 8 MB  [1024,4096] bf16
    float*    xn    = (float*)   (ws + (64u<<20));      // 8 MB, aliases w1T (l=0, dead before wt(W1))
    ushort_t* wdecT = (ushort_t*)(ws + (16u<<20));      // 64 MB, aliases qkv..w2T (post-loop)

    embed_k<<<M_, 256, 0, stream>>>(x, emb, h);
    for (int l = 0; l < L_; ++l) {
        if (l == 0) {
            layernorm_k<<<M_, 256, 0, stream>>>(h, ln1w, ln1b, xn, xnb);
            gemm_k<<<dim3(3*D_/BN, M_/BM), 256, 0, stream>>>(
                xn, Wqkv, qkv, M_, 3*D_, D_);
            rope_k<<<(M_*H_*32)/256, 256, 0, stream>>>(qkv);
            attn_tile_k<<<B_*H_*(S_/16), 256, 0, stream>>>(qkv, ob);
        } else {
            layernorm_k<<<M_, 256, 0, stream>>>(h, ln1w + l*D_, ln1b + l*D_, nullptr, xnb);
            wt_k<<<dim3(3*D_/32, D_/32), 256, 0, stream>>>(
                Wqkv + (size_t)l*D_*3*D_, wqkvT, D_, 3*D_);
            gemm_bf16_k<<<dim3(3*D_/128, M_/128), 256, 0, stream>>>(
                xnb, wqkvT, nullptr, qkv, nullptr, M_, 3*D_, D_, 0);
            qkv_cvt_k<<<B_*H_*(S_/64), 256, 0, stream>>>(qkv, q_bf, k_bf, vT_bf);
            attn_mfma_k<<<B_*H_*(S_/64), 256, 0, stream>>>(q_bf, k_bf, vT_bf, ob);
        }
        wt_k<<<dim3(D_/32, D_/32), 256, 0, stream>>>(
            Wo + (size_t)l*D_*D_, woT, D_, D_);
        gemm_bf16_k<<<dim3(D_/128, M_/128), 256, 0, stream>>>(
            ob, woT, h, h, nullptr, M_, D_, D_, 1);
        layernorm_k<<<M_, 256, 0, stream>>>(h, ln2w + l*D_, ln2b + l*D_, nullptr, xnb);
        wt_k<<<dim3(DFF_/32, D_/32), 256, 0, stream>>>(
            W1 + (size_t)l*D_*DFF_, w1T, D_, DFF_);
        gemm_bf16_k<<<dim3(DFF_/128, M_/128), 256, 0, stream>>>(
            xnb, w1T, nullptr, nullptr, ffb, M_, DFF_, D_, 2);
        wt_k<<<dim3(D_/32, DFF_/32), 256, 0, stream>>>(
            W2 + (size_t)l*DFF_*D_, w2T, DFF_, D_);
        gemm_bf16_k<<<dim3(D_/128, M_/128), 256, 0, stream>>>(
            ffb, w2T, h, h, nullptr, M_, D_, DFF_, 1);
    }
    layernorm_k<<<M_, 256, 0, stream>>>(h, lnfw, lnfb, nullptr, xnb);
    wt_k<<<dim3(V_/32, D_/32), 256, 0, stream>>>(Wdec, wdecT, D_, V_);
    gemm_bf16_k<<<dim3(V_/128, M_/128), 256, 0, stream>>>(
        xnb, wdecT, nullptr, out, nullptr, M_, V_, D_, 0);
}

// Round 6
// 2470.273 us; speedup vs baseline: 7.7466x; 1.1659x over previous
//
#include <hip/hip_runtime.h>
#include <hip/hip_bf16.h>
#include <math.h>

#define B_ 2
#define S_ 1024
#define D_ 1024
#define H_ 16
#define HD_ 64
#define L_ 8
#define DFF_ 4096
#define V_ 32000
#define M_ (B_*S_)   /* 2048 rows */

typedef unsigned short ushort_t;
typedef __attribute__((ext_vector_type(8))) __bf16 bf16x8_t;
typedef __attribute__((ext_vector_type(4))) float f32x4_t;

__device__ __forceinline__ ushort_t f2bf(float f) {
    union { float f; unsigned u; } x; x.f = f;
    unsigned r = x.u + 0x7fffu + ((x.u >> 16) & 1u);
    return (ushort_t)(r >> 16);
}
__device__ __forceinline__ float bf2f(ushort_t u) {
    union { unsigned u; float f; } x; x.u = ((unsigned)u) << 16; return x.f;
}

__device__ __forceinline__ void gload_lds16(const void* g, void* l) {
    __builtin_amdgcn_global_load_lds(
        (const __attribute__((address_space(1))) void*)g,
        (__attribute__((address_space(3))) void*)l, 16, 0, 0);
}

// ---------------------------------------------------------------- embedding
__global__ __launch_bounds__(256) void embed_k(const int* __restrict__ x,
                                               const float* __restrict__ emb,
                                               float* __restrict__ h) {
    int row = blockIdx.x;
    int tok = x[row];
    const float4* src = (const float4*)(emb + (size_t)tok * D_);
    float4* dst = (float4*)(h + (size_t)row * D_);
    dst[threadIdx.x] = src[threadIdx.x];
}

// ---------------------------------------------------------------- layernorm
// Faithful: out = w*(x-m)/(var + 1e-12) + b   (NO sqrt).
// Writes bf16 hi; optionally also bf16 lo residual (split-precision path).
__global__ __launch_bounds__(256) void layernorm_k(const float* __restrict__ x,
                                                   const float* __restrict__ w,
                                                   const float* __restrict__ bb,
                                                   ushort_t* __restrict__ out16,
                                                   ushort_t* __restrict__ out16l) {
    int row = blockIdx.x;
    const float4* xr = (const float4*)(x + (size_t)row * D_);
    float4 v = xr[threadIdx.x];
    float s = v.x + v.y + v.z + v.w;
    #pragma unroll
    for (int off = 32; off; off >>= 1) s += __shfl_xor(s, off);
    __shared__ float red1[4];
    __shared__ float red2[4];
    int wave = threadIdx.x >> 6, lane = threadIdx.x & 63;
    if (lane == 0) red1[wave] = s;
    __syncthreads();
    float m = (red1[0] + red1[1] + red1[2] + red1[3]) * (1.f / 1024.f);
    float dx = v.x - m, dy = v.y - m, dz = v.z - m, dw = v.w - m;
    float ss = dx*dx + dy*dy + dz*dz + dw*dw;
    #pragma unroll
    for (int off = 32; off; off >>= 1) ss += __shfl_xor(ss, off);
    if (lane == 0) red2[wave] = ss;
    __syncthreads();
    float var = (red2[0] + red2[1] + red2[2] + red2[3]) * (1.f / 1024.f);
    float inv = 1.f / (var + 1e-12f);
    float4 wv = ((const float4*)w)[threadIdx.x];
    float4 bv = ((const float4*)bb)[threadIdx.x];
    float4 ov;
    ov.x = wv.x * dx * inv + bv.x;
    ov.y = wv.y * dy * inv + bv.y;
    ov.z = wv.z * dz * inv + bv.z;
    ov.w = wv.w * dw * inv + bv.w;
    ushort4 oh;
    oh.x = f2bf(ov.x); oh.y = f2bf(ov.y); oh.z = f2bf(ov.z); oh.w = f2bf(ov.w);
    ((ushort4*)(out16 + (size_t)row * D_))[threadIdx.x] = oh;
    if (out16l) {
        ushort4 ol;
        ol.x = f2bf(ov.x - bf2f(oh.x));
        ol.y = f2bf(ov.y - bf2f(oh.y));
        ol.z = f2bf(ov.z - bf2f(oh.z));
        ol.w = f2bf(ov.w - bf2f(oh.w));
        ((ushort4*)(out16l + (size_t)row * D_))[threadIdx.x] = ol;
    }
}

// ------------------------------------------- qkv fp32 -> rope'd bf16 q/k + vT
// Layers >= 1. q_bf/k_bf: [bh][s][64] (q pre-scaled by 0.125); vT_bf: [bh][d][s].
// Faithful rope quirk: angle = head_index * inv_freq(pair).
__global__ __launch_bounds__(256) void qkv_cvt_k(const float* __restrict__ qkv,
                                                 ushort_t* __restrict__ qb,
                                                 ushort_t* __restrict__ kb,
                                                 ushort_t* __restrict__ vtb) {
    __shared__ float t[64][68];
    int blk = blockIdx.x;
    int st = blk & 15, bh = blk >> 4;
    int hh = bh & 15, bb = bh >> 4;
    int tid = threadIdx.x;
    int sr = tid >> 2, c4 = tid & 3;
    const float* base = qkv + (size_t)(bb*S_ + st*64 + sr) * (3*D_) + hh*192;
    float qv[16], kv[16];
    #pragma unroll
    for (int p = 0; p < 4; ++p) {
        float4 a = *(const float4*)(base + c4*16 + 4*p);
        float4 b = *(const float4*)(base + 64 + c4*16 + 4*p);
        qv[4*p+0]=a.x; qv[4*p+1]=a.y; qv[4*p+2]=a.z; qv[4*p+3]=a.w;
        kv[4*p+0]=b.x; kv[4*p+1]=b.y; kv[4*p+2]=b.z; kv[4*p+3]=b.w;
    }
    ushort_t qo[16], ko[16];
    #pragma unroll
    for (int p = 0; p < 8; ++p) {
        int i = c4*8 + p;
        float inv = exp2f((float)i * (-13.287712379549449f / 32.f));
        float ang = (float)hh * inv;
        float sn, cs;
        sincosf(ang, &sn, &cs);
        float a = qv[2*p], b = qv[2*p+1];
        qo[2*p]   = f2bf((a*cs - b*sn) * 0.125f);
        qo[2*p+1] = f2bf((a*sn + b*cs) * 0.125f);
        a = kv[2*p]; b = kv[2*p+1];
        ko[2*p]   = f2bf(a*cs - b*sn);
        ko[2*p+1] = f2bf(a*sn + b*cs);
    }
    size_t rowo = ((size_t)bh*S_ + st*64 + sr) * 64 + c4*16;
    *(uint4*)(qb + rowo)     = *(uint4*)&qo[0];
    *(uint4*)(qb + rowo + 8) = *(uint4*)&qo[8];
    *(uint4*)(kb + rowo)     = *(uint4*)&ko[0];
    *(uint4*)(kb + rowo + 8) = *(uint4*)&ko[8];
    #pragma unroll
    for (int p = 0; p < 4; ++p)
        *(float4*)&t[sr][c4*16 + 4*p] = *(const float4*)(base + 128 + c4*16 + 4*p);
    __syncthreads();
    int d = tid >> 2, s0 = (tid & 3) * 16;
    ushort_t vo[16];
    #pragma unroll
    for (int u = 0; u < 16; ++u) vo[u] = f2bf(t[s0+u][d]);
    size_t vout = ((size_t)bh*64 + d) * S_ + st*64 + s0;
    *(uint4*)(vtb + vout)     = *(uint4*)&vo[0];
    *(uint4*)(vtb + vout + 8) = *(uint4*)&vo[8];
}

// ------------------------------------------- layer-0 variant: split hi/lo q,k
__global__ __launch_bounds__(256) void qkv_cvt0_k(const float* __restrict__ qkv,
                                                  ushort_t* __restrict__ qhb,
                                                  ushort_t* __restrict__ qlb,
                                                  ushort_t* __restrict__ khb,
                                                  ushort_t* __restrict__ klb,
                                                  ushort_t* __restrict__ vtb) {
    __shared__ float t[64][68];
    int blk = blockIdx.x;
    int st = blk & 15, bh = blk >> 4;
    int hh = bh & 15, bb = bh >> 4;
    int tid = threadIdx.x;
    int sr = tid >> 2, c4 = tid & 3;
    const float* base = qkv + (size_t)(bb*S_ + st*64 + sr) * (3*D_) + hh*192;
    float qv[16], kv[16];
    #pragma unroll
    for (int p = 0; p < 4; ++p) {
        float4 a = *(const float4*)(base + c4*16 + 4*p);
        float4 b = *(const float4*)(base + 64 + c4*16 + 4*p);
        qv[4*p+0]=a.x; qv[4*p+1]=a.y; qv[4*p+2]=a.z; qv[4*p+3]=a.w;
        kv[4*p+0]=b.x; kv[4*p+1]=b.y; kv[4*p+2]=b.z; kv[4*p+3]=b.w;
    }
    float qr[16], kr[16];
    #pragma unroll
    for (int p = 0; p < 8; ++p) {
        int i = c4*8 + p;
        float inv = exp2f((float)i * (-13.287712379549449f / 32.f));
        float ang = (float)hh * inv;
        float sn, cs;
        sincosf(ang, &sn, &cs);
        float a = qv[2*p], b = qv[2*p+1];
        qr[2*p]   = (a*cs - b*sn) * 0.125f;
        qr[2*p+1] = (a*sn + b*cs) * 0.125f;
        a = kv[2*p]; b = kv[2*p+1];
        kr[2*p]   = a*cs - b*sn;
        kr[2*p+1] = a*sn + b*cs;
    }
    ushort_t qho[16], qlo[16], kho[16], klo[16];
    #pragma unroll
    for (int e = 0; e < 16; ++e) {
        ushort_t qh = f2bf(qr[e]);
        qho[e] = qh; qlo[e] = f2bf(qr[e] - bf2f(qh));
        ushort_t kh = f2bf(kr[e]);
        kho[e] = kh; klo[e] = f2bf(kr[e] - bf2f(kh));
    }
    size_t rowo = ((size_t)bh*S_ + st*64 + sr) * 64 + c4*16;
    *(uint4*)(qhb + rowo)     = *(uint4*)&qho[0];
    *(uint4*)(qhb + rowo + 8) = *(uint4*)&qho[8];
    *(uint4*)(qlb + rowo)     = *(uint4*)&qlo[0];
    *(uint4*)(qlb + rowo + 8) = *(uint4*)&qlo[8];
    *(uint4*)(khb + rowo)     = *(uint4*)&kho[0];
    *(uint4*)(khb + rowo + 8) = *(uint4*)&kho[8];
    *(uint4*)(klb + rowo)     = *(uint4*)&klo[0];
    *(uint4*)(klb + rowo + 8) = *(uint4*)&klo[8];
    #pragma unroll
    for (int p = 0; p < 4; ++p)
        *(float4*)&t[sr][c4*16 + 4*p] = *(const float4*)(base + 128 + c4*16 + 4*p);
    __syncthreads();
    int d = tid >> 2, s0 = (tid & 3) * 16;
    ushort_t vo[16];
    #pragma unroll
    for (int u = 0; u < 16; ++u) vo[u] = f2bf(t[s0+u][d]);
    size_t vout = ((size_t)bh*64 + d) * S_ + st*64 + s0;
    *(uint4*)(vtb + vout)     = *(uint4*)&vo[0];
    *(uint4*)(vtb + vout + 8) = *(uint4*)&vo[8];
}

// ------------------------------------------- bf16 MFMA flash attn (layers>=1)
// Block = 4 waves, 64 q-rows of one (b,h). 16x16x32 MFMA; fp32 softmax state.
// K_lds[key][64d], Vt_lds[d][64key], P_lds per-wave [16][64], all XOR-swizzled
// (byte ^= (row&7)<<4) so b128 reads are 2-way (free) instead of 16-way.
__global__ __launch_bounds__(256) void attn_mfma_k(const ushort_t* __restrict__ qb,
                                                   const ushort_t* __restrict__ kb,
                                                   const ushort_t* __restrict__ vtb,
                                                   ushort_t* __restrict__ o) {
    __shared__ __align__(16) char Kl[8192];
    __shared__ __align__(16) char Vl[8192];
    __shared__ __align__(16) char Pl[8192];
    int blk = blockIdx.x;
    int qt = 15 - (blk & 15);            // longest first
    int bh = blk >> 4;
    int hh = bh & 15, bb = bh >> 4;
    int tid = threadIdx.x, w = tid >> 6, lane = tid & 63;
    int lg = lane >> 4, lr = lane & 15;

    const ushort_t* qhb = qb + ((size_t)bh*S_ + qt*64 + w*16 + lr) * 64;
    bf16x8_t aq0 = *(const bf16x8_t*)(qhb + lg*8);
    bf16x8_t aq1 = *(const bf16x8_t*)(qhb + 32 + lg*8);

    f32x4_t oacc[4];
    #pragma unroll
    for (int n = 0; n < 4; ++n) oacc[n] = (f32x4_t){0.f,0.f,0.f,0.f};
    float m[4] = {-3.0e38f,-3.0e38f,-3.0e38f,-3.0e38f};
    float l[4] = {0.f,0.f,0.f,0.f};

    int srow = tid >> 2;
    int soff = (tid & 3) * 32;
    const ushort_t* kg = kb  + (size_t)bh * S_ * 64;
    const ushort_t* vg = vtb + (size_t)bh * 64 * S_;

    for (int kt = 0; kt <= qt; ++kt) {
        __syncthreads();
        {
            const ushort_t* src = kg + (size_t)(kt*64 + srow) * 64 + soff/2;
            uint4 v0 = *(const uint4*)src;
            uint4 v1 = *(const uint4*)(src + 8);
            int b0 = (srow*128 + soff) ^ ((srow & 7) << 4);
            int b1 = (srow*128 + soff + 16) ^ ((srow & 7) << 4);
            *(uint4*)(Kl + b0) = v0;
            *(uint4*)(Kl + b1) = v1;
            const ushort_t* vs = vg + (size_t)srow * S_ + kt*64 + soff/2;
            uint4 u0 = *(const uint4*)vs;
            uint4 u1 = *(const uint4*)(vs + 8);
            *(uint4*)(Vl + b0) = u0;
            *(uint4*)(Vl + b1) = u1;
        }
        __syncthreads();

        f32x4_t sfr[4];
        #pragma unroll
        for (int n = 0; n < 4; ++n) sfr[n] = (f32x4_t){0.f,0.f,0.f,0.f};
        #pragma unroll
        for (int n = 0; n < 4; ++n) {
            int row = n*16 + lr;
            int swz = (row & 7) << 4;
            bf16x8_t b0 = *(const bf16x8_t*)(Kl + ((row*128 + lg*16) ^ swz));
            bf16x8_t b1 = *(const bf16x8_t*)(Kl + ((row*128 + 64 + lg*16) ^ swz));
            sfr[n] = __builtin_amdgcn_mfma_f32_16x16x32_bf16(aq0, b0, sfr[n], 0,0,0);
            sfr[n] = __builtin_amdgcn_mfma_f32_16x16x32_bf16(aq1, b1, sfr[n], 0,0,0);
        }

        if (kt == qt) {
            #pragma unroll
            for (int n = 0; n < 4; ++n) {
                int key = n*16 + lr;
                #pragma unroll
                for (int j = 0; j < 4; ++j) {
                    int qrow = w*16 + lg*4 + j;
                    if (key > qrow) sfr[n][j] = -3.0e38f;
                }
            }
        }

        float sc[4];
        #pragma unroll
        for (int j = 0; j < 4; ++j) {
            float v = fmaxf(fmaxf(sfr[0][j], sfr[1][j]), fmaxf(sfr[2][j], sfr[3][j]));
            v = fmaxf(v, __shfl_xor(v, 1));
            v = fmaxf(v, __shfl_xor(v, 2));
            v = fmaxf(v, __shfl_xor(v, 4));
            v = fmaxf(v, __shfl_xor(v, 8));
            float mn = fmaxf(m[j], v);
            sc[j] = __expf(m[j] - mn);
            m[j] = mn;
        }
        #pragma unroll
        for (int n = 0; n < 4; ++n)
            #pragma unroll
            for (int j = 0; j < 4; ++j)
                sfr[n][j] = __expf(sfr[n][j] - m[j]);
        #pragma unroll
        for (int j = 0; j < 4; ++j) {
            float s = sfr[0][j] + sfr[1][j] + sfr[2][j] + sfr[3][j];
            s += __shfl_xor(s, 1);
            s += __shfl_xor(s, 2);
            s += __shfl_xor(s, 4);
            s += __shfl_xor(s, 8);
            l[j] = l[j] * sc[j] + s;
            #pragma unroll
            for (int n = 0; n < 4; ++n) oacc[n][j] *= sc[j];
        }

        #pragma unroll
        for (int n = 0; n < 4; ++n) {
            #pragma unroll
            for (int j = 0; j < 4; ++j) {
                int row = lg*4 + j;
                int byt = (w*2048 + row*128 + (n*16 + lr)*2) ^ ((row & 7) << 4);
                *(ushort_t*)(Pl + byt) = f2bf(sfr[n][j]);
            }
        }
        int pswz = (lr & 7) << 4;
        bf16x8_t pa0 = *(const bf16x8_t*)(Pl + ((w*2048 + lr*128 + lg*16) ^ pswz));
        bf16x8_t pa1 = *(const bf16x8_t*)(Pl + ((w*2048 + lr*128 + 64 + lg*16) ^ pswz));

        #pragma unroll
        for (int n = 0; n < 4; ++n) {
            int row = n*16 + lr;
            int swz = (row & 7) << 4;
            bf16x8_t v0 = *(const bf16x8_t*)(Vl + ((row*128 + lg*16) ^ swz));
            bf16x8_t v1 = *(const bf16x8_t*)(Vl + ((row*128 + 64 + lg*16) ^ swz));
            oacc[n] = __builtin_amdgcn_mfma_f32_16x16x32_bf16(pa0, v0, oacc[n], 0,0,0);
            oacc[n] = __builtin_amdgcn_mfma_f32_16x16x32_bf16(pa1, v1, oacc[n], 0,0,0);
        }
    }

    #pragma unroll
    for (int j = 0; j < 4; ++j) {
        float rl = 1.f / l[j];
        int row = qt*64 + w*16 + lg*4 + j;
        size_t base = (size_t)(bb*S_ + row) * D_ + hh*64;
        #pragma unroll
        for (int n = 0; n < 4; ++n)
            o[base + n*16 + lr] = f2bf(oacc[n][j] * rl);
    }
}

// ------------------------------------------- split-precision MFMA attn, layer 0
// Identical structure; QK^T = qh*kh + qh*kl + ql*kh (3-pass split-bf16, score
// rel err ~2^-17 -- safe for the sharp layer-0 softmax). PV plain bf16.
__global__ __launch_bounds__(256) void attn_mfma0_k(const ushort_t* __restrict__ qhp,
                                                    const ushort_t* __restrict__ qlp,
                                                    const ushort_t* __restrict__ khp,
                                                    const ushort_t* __restrict__ klp,
                                                    const ushort_t* __restrict__ vtb,
                                                    ushort_t* __restrict__ o) {
    __shared__ __align__(16) char Khl[8192];
    __shared__ __align__(16) char Kll[8192];
    __shared__ __align__(16) char Vl[8192];
    __shared__ __align__(16) char Pl[8192];
    int blk = blockIdx.x;
    int qt = 15 - (blk & 15);
    int bh = blk >> 4;
    int hh = bh & 15, bb = bh >> 4;
    int tid = threadIdx.x, w = tid >> 6, lane = tid & 63;
    int lg = lane >> 4, lr = lane & 15;

    size_t qoff = ((size_t)bh*S_ + qt*64 + w*16 + lr) * 64;
    bf16x8_t aqh0 = *(const bf16x8_t*)(qhp + qoff + lg*8);
    bf16x8_t aqh1 = *(const bf16x8_t*)(qhp + qoff + 32 + lg*8);
    bf16x8_t aql0 = *(const bf16x8_t*)(qlp + qoff + lg*8);
    bf16x8_t aql1 = *(const bf16x8_t*)(qlp + qoff + 32 + lg*8);

    f32x4_t oacc[4];
    #pragma unroll
    for (int n = 0; n < 4; ++n) oacc[n] = (f32x4_t){0.f,0.f,0.f,0.f};
    float m[4] = {-3.0e38f,-3.0e38f,-3.0e38f,-3.0e38f};
    float l[4] = {0.f,0.f,0.f,0.f};

    int srow = tid >> 2;
    int soff = (tid & 3) * 32;
    const ushort_t* kgh = khp + (size_t)bh * S_ * 64;
    const ushort_t* kgl = klp + (size_t)bh * S_ * 64;
    const ushort_t* vg  = vtb + (size_t)bh * 64 * S_;

    for (int kt = 0; kt <= qt; ++kt) {
        __syncthreads();
        {
            int b0 = (srow*128 + soff) ^ ((srow & 7) << 4);
            int b1 = (srow*128 + soff + 16) ^ ((srow & 7) << 4);
            const ushort_t* src = kgh + (size_t)(kt*64 + srow) * 64 + soff/2;
            *(uint4*)(Khl + b0) = *(const uint4*)src;
            *(uint4*)(Khl + b1) = *(const uint4*)(src + 8);
            const ushort_t* srl = kgl + (size_t)(kt*64 + srow) * 64 + soff/2;
            *(uint4*)(Kll + b0) = *(const uint4*)srl;
            *(uint4*)(Kll + b1) = *(const uint4*)(srl + 8);
            const ushort_t* vs = vg + (size_t)srow * S_ + kt*64 + soff/2;
            *(uint4*)(Vl + b0) = *(const uint4*)vs;
            *(uint4*)(Vl + b1) = *(const uint4*)(vs + 8);
        }
        __syncthreads();

        f32x4_t sfr[4];
        #pragma unroll
        for (int n = 0; n < 4; ++n) sfr[n] = (f32x4_t){0.f,0.f,0.f,0.f};
        #pragma unroll
        for (int n = 0; n < 4; ++n) {
            int row = n*16 + lr;
            int swz = (row & 7) << 4;
            bf16x8_t bh0 = *(const bf16x8_t*)(Khl + ((row*128 + lg*16) ^ swz));
            bf16x8_t bh1 = *(const bf16x8_t*)(Khl + ((row*128 + 64 + lg*16) ^ swz));
            bf16x8_t bl0 = *(const bf16x8_t*)(Kll + ((row*128 + lg*16) ^ swz));
            bf16x8_t bl1 = *(const bf16x8_t*)(Kll + ((row*128 + 64 + lg*16) ^ swz));
            sfr[n] = __builtin_amdgcn_mfma_f32_16x16x32_bf16(aqh0, bh0, sfr[n], 0,0,0);
            sfr[n] = __builtin_amdgcn_mfma_f32_16x16x32_bf16(aqh1, bh1, sfr[n], 0,0,0);
            sfr[n] = __builtin_amdgcn_mfma_f32_16x16x32_bf16(aqh0, bl0, sfr[n], 0,0,0);
            sfr[n] = __builtin_amdgcn_mfma_f32_16x16x32_bf16(aqh1, bl1, sfr[n], 0,0,0);
            sfr[n] = __builtin_amdgcn_mfma_f32_16x16x32_bf16(aql0, bh0, sfr[n], 0,0,0);
            sfr[n] = __builtin_amdgcn_mfma_f32_16x16x32_bf16(aql1, bh1, sfr[n], 0,0,0);
        }

        if (kt == qt) {
            #pragma unroll
            for (int n = 0; n < 4; ++n) {
                int key = n*16 + lr;
                #pragma unroll
                for (int j = 0; j < 4; ++j) {
                    int qrow = w*16 + lg*4 + j;
                    if (key > qrow) sfr[n][j] = -3.0e38f;
                }
            }
        }

        float sc[4];
        #pragma unroll
        for (int j = 0; j < 4; ++j) {
            float v = fmaxf(fmaxf(sfr[0][j], sfr[1][j]), fmaxf(sfr[2][j], sfr[3][j]));
            v = fmaxf(v, __shfl_xor(v, 1));
            v = fmaxf(v, __shfl_xor(v, 2));
            v = fmaxf(v, __shfl_xor(v, 4));
            v = fmaxf(v, __shfl_xor(v, 8));
            float mn = fmaxf(m[j], v);
            sc[j] = __expf(m[j] - mn);
            m[j] = mn;
        }
        #pragma unroll
        for (int n = 0; n < 4; ++n)
            #pragma unroll
            for (int j = 0; j < 4; ++j)
                sfr[n][j] = __expf(sfr[n][j] - m[j]);
        #pragma unroll
        for (int j = 0; j < 4; ++j) {
            float s = sfr[0][j] + sfr[1][j] + sfr[2][j] + sfr[3][j];
            s += __shfl_xor(s, 1);
            s += __shfl_xor(s, 2);
            s += __shfl_xor(s, 4);
            s += __shfl_xor(s, 8);
            l[j] = l[j] * sc[j] + s;
            #pragma unroll
            for (int n = 0; n < 4; ++n) oacc[n][j] *= sc[j];
        }

        #pragma unroll
        for (int n = 0; n < 4; ++n) {
            #pragma unroll
            for (int j = 0; j < 4; ++j) {
                int row = lg*4 + j;
                int byt = (w*2048 + row*128 + (n*16 + lr)*2) ^ ((row & 7) << 4);
                *(ushort_t*)(Pl + byt) = f2bf(sfr[n][j]);
            }
        }
        int pswz = (lr & 7) << 4;
        bf16x8_t pa0 = *(const bf16x8_t*)(Pl + ((w*2048 + lr*128 + lg*16) ^ pswz));
        bf16x8_t pa1 = *(const bf16x8_t*)(Pl + ((w*2048 + lr*128 + 64 + lg*16) ^ pswz));

        #pragma unroll
        for (int n = 0; n < 4; ++n) {
            int row = n*16 + lr;
            int swz = (row & 7) << 4;
            bf16x8_t v0 = *(const bf16x8_t*)(Vl + ((row*128 + lg*16) ^ swz));
            bf16x8_t v1 = *(const bf16x8_t*)(Vl + ((row*128 + 64 + lg*16) ^ swz));
            oacc[n] = __builtin_amdgcn_mfma_f32_16x16x32_bf16(pa0, v0, oacc[n], 0,0,0);
            oacc[n] = __builtin_amdgcn_mfma_f32_16x16x32_bf16(pa1, v1, oacc[n], 0,0,0);
        }
    }

    #pragma unroll
    for (int j = 0; j < 4; ++j) {
        float rl = 1.f / l[j];
        int row = qt*64 + w*16 + lg*4 + j;
        size_t base = (size_t)(bb*S_ + row) * D_ + hh*64;
        #pragma unroll
        for (int n = 0; n < 4; ++n)
            o[base + n*16 + lr] = f2bf(oacc[n][j] * rl);
    }
}

// ------------------------------------------------- weight transpose fp32->bf16
__global__ __launch_bounds__(256) void wt_k(const float* __restrict__ W,
                                            ushort_t* __restrict__ Wt,
                                            int K, int N) {
    __shared__ float t[32][33];
    int k0 = blockIdx.y << 5, n0 = blockIdx.x << 5;
    int r = threadIdx.x >> 3, c4 = (threadIdx.x & 7) << 2;
    float4 v = *(const float4*)(W + (size_t)(k0 + r) * N + n0 + c4);
    t[r][c4+0] = v.x; t[r][c4+1] = v.y; t[r][c4+2] = v.z; t[r][c4+3] = v.w;
    __syncthreads();
    ushort4 o;
    o.x = f2bf(t[c4+0][r]); o.y = f2bf(t[c4+1][r]);
    o.z = f2bf(t[c4+2][r]); o.w = f2bf(t[c4+3][r]);
    *(ushort4*)(Wt + (size_t)(n0 + r) * K + k0 + c4) = o;
}

// ---------------------------------- dual-output (hi/lo) transpose, layer-0 Wqkv
__global__ __launch_bounds__(256) void wt2_k(const float* __restrict__ W,
                                             ushort_t* __restrict__ Wth,
                                             ushort_t* __restrict__ Wtl,
                                             int K, int N) {
    __shared__ float t[32][33];
    int k0 = blockIdx.y << 5, n0 = blockIdx.x << 5;
    int r = threadIdx.x >> 3, c4 = (threadIdx.x & 7) << 2;
    float4 v = *(const float4*)(W + (size_t)(k0 + r) * N + n0 + c4);
    t[r][c4+0] = v.x; t[r][c4+1] = v.y; t[r][c4+2] = v.z; t[r][c4+3] = v.w;
    __syncthreads();
    ushort4 oh, ol;
    float v0 = t[c4+0][r], v1 = t[c4+1][r], v2 = t[c4+2][r], v3 = t[c4+3][r];
    oh.x = f2bf(v0); ol.x = f2bf(v0 - bf2f(oh.x));
    oh.y = f2bf(v1); ol.y = f2bf(v1 - bf2f(oh.y));
    oh.z = f2bf(v2); ol.z = f2bf(v2 - bf2f(oh.z));
    oh.w = f2bf(v3); ol.w = f2bf(v3 - bf2f(oh.w));
    size_t off = (size_t)(n0 + r) * K + k0 + c4;
    *(ushort4*)(Wth + off) = oh;
    *(ushort4*)(Wtl + off) = ol;
}

// ---------------------------------------------------------------- GEMM bf16
// C[M,N] = A[M,K] @ Bt[N,K]^T.  TM=128: 256 thr, 4 waves (2x2), 128x128 tile.
// TM=64: 128 thr, 2 waves (1x2), 64x128 tile (full-grid for small-N GEMMs).
// epi: 0 = fp32 out, 1 = fp32 out + Res, 2 = gelu->bf16, 3 = fp32 accumulate
__device__ __forceinline__ float gelu_f(float x) {
    return 0.5f * x * (1.f + erff(x * 0.70710678118654752f));
}

template<int TM>
__global__ __launch_bounds__(2*TM, 2) void gemm_bf16_k(
    const ushort_t* __restrict__ A,
    const ushort_t* __restrict__ Bt,
    const float* __restrict__ Res,
    float* __restrict__ Cf,
    ushort_t* __restrict__ Cb,
    int M, int N, int K, int epi)
{
    __shared__ __align__(16) ushort_t As[TM * 64];
    __shared__ __align__(16) ushort_t Bs[128 * 64];
    int tid = threadIdx.x;
    int wid = tid >> 6, lane = tid & 63;
    int wm = (TM == 128) ? (wid >> 1) : 0;
    int wn = (TM == 128) ? (wid & 1) : wid;
    int bm = blockIdx.y * TM, bn = blockIdx.x * 128;

    f32x4_t acc[4][4];
    #pragma unroll
    for (int m = 0; m < 4; ++m)
        #pragma unroll
        for (int n = 0; n < 4; ++n)
            acc[m][n] = (f32x4_t){0.f, 0.f, 0.f, 0.f};

    int srow = (lane >> 3);
    int scol = (lane & 7) * 8;

    for (int k0 = 0; k0 < K; k0 += 64) {
        __syncthreads();
        #pragma unroll
        for (int i = 0; i < 4; ++i) {
            int rb = i * (TM/4) + wid * 8;
            gload_lds16(A + (size_t)(bm + rb + srow) * K + k0 + scol, &As[rb * 64]);
        }
        #pragma unroll
        for (int i = 0; i < 512/TM; ++i) {
            int rb = i * (TM/4) + wid * 8;
            gload_lds16(Bt + (size_t)(bn + rb + srow) * K + k0 + scol, &Bs[rb * 64]);
        }
        __syncthreads();
        #pragma unroll
        for (int kk = 0; kk < 64; kk += 32) {
            bf16x8_t af[4], bfr[4];
            int kof = kk + (lane >> 4) * 8;
            #pragma unroll
            for (int m = 0; m < 4; ++m) {
                int r = wm * 64 + m * 16 + (lane & 15);
                af[m] = *(const bf16x8_t*)&As[r * 64 + kof];
            }
            #pragma unroll
            for (int n = 0; n < 4; ++n) {
                int r = wn * 64 + n * 16 + (lane & 15);
                bfr[n] = *(const bf16x8_t*)&Bs[r * 64 + kof];
            }
            #pragma unroll
            for (int m = 0; m < 4; ++m)
                #pragma unroll
                for (int n = 0; n < 4; ++n)
                    acc[m][n] = __builtin_amdgcn_mfma_f32_16x16x32_bf16(
                        af[m], bfr[n], acc[m][n], 0, 0, 0);
        }
    }

    int cr = (lane >> 4) * 4, cc = lane & 15;
    #pragma unroll
    for (int m = 0; m < 4; ++m) {
        int row = bm + wm * 64 + m * 16 + cr;
        #pragma unroll
        for (int n = 0; n < 4; ++n) {
            int col = bn + wn * 64 + n * 16 + cc;
            #pragma unroll
            for (int j = 0; j < 4; ++j) {
                size_t off = (size_t)(row + j) * N + col;
                float v = acc[m][n][j];
                if (epi == 0) {
                    Cf[off] = v;
                } else if (epi == 1) {
                    Cf[off] = Res[off] + v;
                } else if (epi == 3) {
                    Cf[off] += v;
                } else {
                    Cb[off] = f2bf(gelu_f(v));
                }
            }
        }
    }
}

// ---------------------------------------------------------------- launch
extern "C" void kernel_launch(void* const* d_in, const int* in_sizes, int n_in,
                              void* d_out, int out_size, void* d_ws, size_t ws_size,
                              hipStream_t stream) {
    const int*   x    = (const int*)  d_in[0];
    const float* emb  = (const float*)d_in[1];
    const float* ln1w = (const float*)d_in[2];
    const float* ln1b = (const float*)d_in[3];
    const float* Wqkv = (const float*)d_in[4];
    const float* Wo   = (const float*)d_in[5];
    const float* ln2w = (const float*)d_in[6];
    const float* ln2b = (const float*)d_in[7];
    const float* W1   = (const float*)d_in[8];
    const float* W2   = (const float*)d_in[9];
    const float* lnfw = (const float*)d_in[10];
    const float* lnfb = (const float*)d_in[11];
    const float* Wdec = (const float*)d_in[12];
    float* out = (float*)d_out;

    // ---- workspace layout (bytes), lifetime-aliased, 80 MB total ----
    char* ws = (char*)d_ws;
    float*    h     = (float*)   (ws + 0);              // 8 MB  [2048,1024] f32
    ushort_t* xnb   = (ushort_t*)(ws + (8u<<20));       // 4 MB  bf16 (xh for l=0)
    ushort_t* ob    = (ushort_t*)(ws + (12u<<20));      // 4 MB  bf16 (xl for l=0, pre-attn)
    float*    qkv   = (float*)   (ws + (16u<<20));      // 24 MB [2048,3072] f32
    ushort_t* ffb   = (ushort_t*)(ws + (40u<<20));      // 16 MB [2048,4096] bf16 (W1 out)
    ushort_t* q_bf  = (ushort_t*)(ws + (40u<<20));      // 4 MB  (l>=1) / qh (l=0)
    ushort_t* k_bf  = (ushort_t*)(ws + (44u<<20));      // 4 MB  (l>=1) / ql (l=0)
    ushort_t* vT_bf = (ushort_t*)(ws + (48u<<20));      // 4 MB  (l>=1) / kh (l=0)
    ushort_t* vT0   = (ushort_t*)(ws + (52u<<20));      // 4 MB  vT (l=0)
    ushort_t* wqkvT = (ushort_t*)(ws + (56u<<20));      // 6 MB  [3072,1024] bf16 (hi for l=0)
    ushort_t* wqkvTl= (ushort_t*)(ws + (62u<<20));      // 6 MB  lo (l=0 only; dead pre-woT/w1T)
    ushort_t* kl0   = (ushort_t*)(ws + (62u<<20));      // 4 MB  kl (l=0; dead pre-woT)
    ushort_t* woT   = (ushort_t*)(ws + (62u<<20));      // 2 MB  [1024,1024] bf16
    ushort_t* w1T   = (ushort_t*)(ws + (64u<<20));      // 8 MB  [4096,1024] bf16
    ushort_t* w2T   = (ushort_t*)(ws + (72u<<20));      // 8 MB  [1024,4096] bf16
    ushort_t* wdecT = (ushort_t*)(ws + (16u<<20));      // 64 MB, aliases qkv..w2T (post-loop)

    embed_k<<<M_, 256, 0, stream>>>(x, emb, h);
    for (int l = 0; l < L_; ++l) {
        if (l == 0) {
            // split-precision path: scores need fp32-grade accuracy (sharp softmax)
            layernorm_k<<<M_, 256, 0, stream>>>(h, ln1w, ln1b, xnb, ob /*=xl*/);
            wt2_k<<<dim3(3*D_/32, D_/32), 256, 0, stream>>>(Wqkv, wqkvT, wqkvTl, D_, 3*D_);
            gemm_bf16_k<128><<<dim3(3*D_/128, M_/128), 256, 0, stream>>>(
                xnb, wqkvT, nullptr, qkv, nullptr, M_, 3*D_, D_, 0);
            gemm_bf16_k<128><<<dim3(3*D_/128, M_/128), 256, 0, stream>>>(
                xnb, wqkvTl, nullptr, qkv, nullptr, M_, 3*D_, D_, 3);
            gemm_bf16_k<128><<<dim3(3*D_/128, M_/128), 256, 0, stream>>>(
                ob /*=xl*/, wqkvT, nullptr, qkv, nullptr, M_, 3*D_, D_, 3);
            qkv_cvt0_k<<<B_*H_*(S_/64), 256, 0, stream>>>(
                qkv, q_bf /*qh*/, k_bf /*ql*/, vT_bf /*kh*/, kl0, vT0);
            attn_mfma0_k<<<B_*H_*(S_/64), 256, 0, stream>>>(
                q_bf, k_bf, vT_bf, kl0, vT0, ob);
        } else {
            layernorm_k<<<M_, 256, 0, stream>>>(h, ln1w + l*D_, ln1b + l*D_, xnb, nullptr);
            wt_k<<<dim3(3*D_/32, D_/32), 256, 0, stream>>>(
                Wqkv + (size_t)l*D_*3*D_, wqkvT, D_, 3*D_);
            gemm_bf16_k<128><<<dim3(3*D_/128, M_/128), 256, 0, stream>>>(
                xnb, wqkvT, nullptr, qkv, nullptr, M_, 3*D_, D_, 0);
            qkv_cvt_k<<<B_*H_*(S_/64), 256, 0, stream>>>(qkv, q_bf, k_bf, vT_bf);
            attn_mfma_k<<<B_*H_*(S_/64), 256, 0, stream>>>(q_bf, k_bf, vT_bf, ob);
        }
        wt_k<<<dim3(D_/32, D_/32), 256, 0, stream>>>(
            Wo + (size_t)l*D_*D_, woT, D_, D_);
        gemm_bf16_k<64><<<dim3(D_/128, M_/64), 128, 0, stream>>>(
            ob, woT, h, h, nullptr, M_, D_, D_, 1);
        layernorm_k<<<M_, 256, 0, stream>>>(h, ln2w + l*D_, ln2b + l*D_, xnb, nullptr);
        wt_k<<<dim3(DFF_/32, D_/32), 256, 0, stream>>>(
            W1 + (size_t)l*D_*DFF_, w1T, D_, DFF_);
        gemm_bf16_k<128><<<dim3(DFF_/128, M_/128), 256, 0, stream>>>(
            xnb, w1T, nullptr, nullptr, ffb, M_, DFF_, D_, 2);
        wt_k<<<dim3(D_/32, DFF_/32), 256, 0, stream>>>(
            W2 + (size_t)l*DFF_*D_, w2T, DFF_, D_);
        gemm_bf16_k<64><<<dim3(D_/128, M_/64), 128, 0, stream>>>(
            ffb, w2T, h, h, nullptr, M_, D_, DFF_, 1);
    }
    layernorm_k<<<M_, 256, 0, stream>>>(h, lnfw, lnfb, xnb, nullptr);
    wt_k<<<dim3(V_/32, D_/32), 256, 0, stream>>>(Wdec, wdecT, D_, V_);
    gemm_bf16_k<128><<<dim3(V_/128, M_/128), 256, 0, stream>>>(
        xnb, wdecT, nullptr, out, nullptr, M_, V_, D_, 0);
}

// Round 7
// 2266.323 us; speedup vs baseline: 8.4437x; 1.0900x over previous
//
#include <hip/hip_runtime.h>
#include <hip/hip_bf16.h>
#include <math.h>

#define B_ 2
#define S_ 1024
#define D_ 1024
#define H_ 16
#define HD_ 64
#define L_ 8
#define DFF_ 4096
#define V_ 32000
#define M_ (B_*S_)   /* 2048 rows */

typedef unsigned short ushort_t;
typedef __attribute__((ext_vector_type(8))) __bf16 bf16x8_t;
typedef __attribute__((ext_vector_type(4))) float f32x4_t;

__device__ __forceinline__ ushort_t f2bf(float f) {
    union { float f; unsigned u; } x; x.f = f;
    unsigned r = x.u + 0x7fffu + ((x.u >> 16) & 1u);
    return (ushort_t)(r >> 16);
}
__device__ __forceinline__ float bf2f(ushort_t u) {
    union { unsigned u; float f; } x; x.u = ((unsigned)u) << 16; return x.f;
}

__device__ __forceinline__ void gload_lds16(const void* g, void* l) {
    __builtin_amdgcn_global_load_lds(
        (const __attribute__((address_space(1))) void*)g,
        (__attribute__((address_space(3))) void*)l, 16, 0, 0);
}

// ---------------------------------------------------------------- embedding
__global__ __launch_bounds__(256) void embed_k(const int* __restrict__ x,
                                               const float* __restrict__ emb,
                                               float* __restrict__ h) {
    int row = blockIdx.x;
    int tok = x[row];
    const float4* src = (const float4*)(emb + (size_t)tok * D_);
    float4* dst = (float4*)(h + (size_t)row * D_);
    dst[threadIdx.x] = src[threadIdx.x];
}

// ---------------------------------------------------------------- layernorm
// Faithful: out = w*(x-m)/(var + 1e-12) + b   (NO sqrt).
// Writes bf16 hi; optionally also bf16 lo residual (split-precision path).
__global__ __launch_bounds__(256) void layernorm_k(const float* __restrict__ x,
                                                   const float* __restrict__ w,
                                                   const float* __restrict__ bb,
                                                   ushort_t* __restrict__ out16,
                                                   ushort_t* __restrict__ out16l) {
    int row = blockIdx.x;
    const float4* xr = (const float4*)(x + (size_t)row * D_);
    float4 v = xr[threadIdx.x];
    float s = v.x + v.y + v.z + v.w;
    #pragma unroll
    for (int off = 32; off; off >>= 1) s += __shfl_xor(s, off);
    __shared__ float red1[4];
    __shared__ float red2[4];
    int wave = threadIdx.x >> 6, lane = threadIdx.x & 63;
    if (lane == 0) red1[wave] = s;
    __syncthreads();
    float m = (red1[0] + red1[1] + red1[2] + red1[3]) * (1.f / 1024.f);
    float dx = v.x - m, dy = v.y - m, dz = v.z - m, dw = v.w - m;
    float ss = dx*dx + dy*dy + dz*dz + dw*dw;
    #pragma unroll
    for (int off = 32; off; off >>= 1) ss += __shfl_xor(ss, off);
    if (lane == 0) red2[wave] = ss;
    __syncthreads();
    float var = (red2[0] + red2[1] + red2[2] + red2[3]) * (1.f / 1024.f);
    float inv = 1.f / (var + 1e-12f);
    float4 wv = ((const float4*)w)[threadIdx.x];
    float4 bv = ((const float4*)bb)[threadIdx.x];
    float4 ov;
    ov.x = wv.x * dx * inv + bv.x;
    ov.y = wv.y * dy * inv + bv.y;
    ov.z = wv.z * dz * inv + bv.z;
    ov.w = wv.w * dw * inv + bv.w;
    ushort4 oh;
    oh.x = f2bf(ov.x); oh.y = f2bf(ov.y); oh.z = f2bf(ov.z); oh.w = f2bf(ov.w);
    ((ushort4*)(out16 + (size_t)row * D_))[threadIdx.x] = oh;
    if (out16l) {
        ushort4 ol;
        ol.x = f2bf(ov.x - bf2f(oh.x));
        ol.y = f2bf(ov.y - bf2f(oh.y));
        ol.z = f2bf(ov.z - bf2f(oh.z));
        ol.w = f2bf(ov.w - bf2f(oh.w));
        ((ushort4*)(out16l + (size_t)row * D_))[threadIdx.x] = ol;
    }
}

// ------------------------------------------- qkv fp32 -> rope'd bf16 q/k + vT
// Layers >= 1. q_bf/k_bf: [bh][s][64] (q pre-scaled by 0.125); vT_bf: [bh][d][s].
// Faithful rope quirk: angle = head_index * inv_freq(pair).
__global__ __launch_bounds__(256) void qkv_cvt_k(const float* __restrict__ qkv,
                                                 ushort_t* __restrict__ qb,
                                                 ushort_t* __restrict__ kb,
                                                 ushort_t* __restrict__ vtb) {
    __shared__ float t[64][68];
    int blk = blockIdx.x;
    int st = blk & 15, bh = blk >> 4;
    int hh = bh & 15, bb = bh >> 4;
    int tid = threadIdx.x;
    int sr = tid >> 2, c4 = tid & 3;
    const float* base = qkv + (size_t)(bb*S_ + st*64 + sr) * (3*D_) + hh*192;
    float qv[16], kv[16];
    #pragma unroll
    for (int p = 0; p < 4; ++p) {
        float4 a = *(const float4*)(base + c4*16 + 4*p);
        float4 b = *(const float4*)(base + 64 + c4*16 + 4*p);
        qv[4*p+0]=a.x; qv[4*p+1]=a.y; qv[4*p+2]=a.z; qv[4*p+3]=a.w;
        kv[4*p+0]=b.x; kv[4*p+1]=b.y; kv[4*p+2]=b.z; kv[4*p+3]=b.w;
    }
    ushort_t qo[16], ko[16];
    #pragma unroll
    for (int p = 0; p < 8; ++p) {
        int i = c4*8 + p;
        float inv = exp2f((float)i * (-13.287712379549449f / 32.f));
        float ang = (float)hh * inv;
        float sn, cs;
        sincosf(ang, &sn, &cs);
        float a = qv[2*p], b = qv[2*p+1];
        qo[2*p]   = f2bf((a*cs - b*sn) * 0.125f);
        qo[2*p+1] = f2bf((a*sn + b*cs) * 0.125f);
        a = kv[2*p]; b = kv[2*p+1];
        ko[2*p]   = f2bf(a*cs - b*sn);
        ko[2*p+1] = f2bf(a*sn + b*cs);
    }
    size_t rowo = ((size_t)bh*S_ + st*64 + sr) * 64 + c4*16;
    *(uint4*)(qb + rowo)     = *(uint4*)&qo[0];
    *(uint4*)(qb + rowo + 8) = *(uint4*)&qo[8];
    *(uint4*)(kb + rowo)     = *(uint4*)&ko[0];
    *(uint4*)(kb + rowo + 8) = *(uint4*)&ko[8];
    #pragma unroll
    for (int p = 0; p < 4; ++p)
        *(float4*)&t[sr][c4*16 + 4*p] = *(const float4*)(base + 128 + c4*16 + 4*p);
    __syncthreads();
    int d = tid >> 2, s0 = (tid & 3) * 16;
    ushort_t vo[16];
    #pragma unroll
    for (int u = 0; u < 16; ++u) vo[u] = f2bf(t[s0+u][d]);
    size_t vout = ((size_t)bh*64 + d) * S_ + st*64 + s0;
    *(uint4*)(vtb + vout)     = *(uint4*)&vo[0];
    *(uint4*)(vtb + vout + 8) = *(uint4*)&vo[8];
}

// ------------------------------------------- layer-0 variant: split hi/lo q,k
__global__ __launch_bounds__(256) void qkv_cvt0_k(const float* __restrict__ qkv,
                                                  ushort_t* __restrict__ qhb,
                                                  ushort_t* __restrict__ qlb,
                                                  ushort_t* __restrict__ khb,
                                                  ushort_t* __restrict__ klb,
                                                  ushort_t* __restrict__ vtb) {
    __shared__ float t[64][68];
    int blk = blockIdx.x;
    int st = blk & 15, bh = blk >> 4;
    int hh = bh & 15, bb = bh >> 4;
    int tid = threadIdx.x;
    int sr = tid >> 2, c4 = tid & 3;
    const float* base = qkv + (size_t)(bb*S_ + st*64 + sr) * (3*D_) + hh*192;
    float qv[16], kv[16];
    #pragma unroll
    for (int p = 0; p < 4; ++p) {
        float4 a = *(const float4*)(base + c4*16 + 4*p);
        float4 b = *(const float4*)(base + 64 + c4*16 + 4*p);
        qv[4*p+0]=a.x; qv[4*p+1]=a.y; qv[4*p+2]=a.z; qv[4*p+3]=a.w;
        kv[4*p+0]=b.x; kv[4*p+1]=b.y; kv[4*p+2]=b.z; kv[4*p+3]=b.w;
    }
    float qr[16], kr[16];
    #pragma unroll
    for (int p = 0; p < 8; ++p) {
        int i = c4*8 + p;
        float inv = exp2f((float)i * (-13.287712379549449f / 32.f));
        float ang = (float)hh * inv;
        float sn, cs;
        sincosf(ang, &sn, &cs);
        float a = qv[2*p], b = qv[2*p+1];
        qr[2*p]   = (a*cs - b*sn) * 0.125f;
        qr[2*p+1] = (a*sn + b*cs) * 0.125f;
        a = kv[2*p]; b = kv[2*p+1];
        kr[2*p]   = a*cs - b*sn;
        kr[2*p+1] = a*sn + b*cs;
    }
    ushort_t qho[16], qlo[16], kho[16], klo[16];
    #pragma unroll
    for (int e = 0; e < 16; ++e) {
        ushort_t qh = f2bf(qr[e]);
        qho[e] = qh; qlo[e] = f2bf(qr[e] - bf2f(qh));
        ushort_t kh = f2bf(kr[e]);
        kho[e] = kh; klo[e] = f2bf(kr[e] - bf2f(kh));
    }
    size_t rowo = ((size_t)bh*S_ + st*64 + sr) * 64 + c4*16;
    *(uint4*)(qhb + rowo)     = *(uint4*)&qho[0];
    *(uint4*)(qhb + rowo + 8) = *(uint4*)&qho[8];
    *(uint4*)(qlb + rowo)     = *(uint4*)&qlo[0];
    *(uint4*)(qlb + rowo + 8) = *(uint4*)&qlo[8];
    *(uint4*)(khb + rowo)     = *(uint4*)&kho[0];
    *(uint4*)(khb + rowo + 8) = *(uint4*)&kho[8];
    *(uint4*)(klb + rowo)     = *(uint4*)&klo[0];
    *(uint4*)(klb + rowo + 8) = *(uint4*)&klo[8];
    #pragma unroll
    for (int p = 0; p < 4; ++p)
        *(float4*)&t[sr][c4*16 + 4*p] = *(const float4*)(base + 128 + c4*16 + 4*p);
    __syncthreads();
    int d = tid >> 2, s0 = (tid & 3) * 16;
    ushort_t vo[16];
    #pragma unroll
    for (int u = 0; u < 16; ++u) vo[u] = f2bf(t[s0+u][d]);
    size_t vout = ((size_t)bh*64 + d) * S_ + st*64 + s0;
    *(uint4*)(vtb + vout)     = *(uint4*)&vo[0];
    *(uint4*)(vtb + vout + 8) = *(uint4*)&vo[8];
}

// ------------------------------------------- bf16 MFMA flash attn (layers>=1)
__global__ __launch_bounds__(256) void attn_mfma_k(const ushort_t* __restrict__ qb,
                                                   const ushort_t* __restrict__ kb,
                                                   const ushort_t* __restrict__ vtb,
                                                   ushort_t* __restrict__ o) {
    __shared__ __align__(16) char Kl[8192];
    __shared__ __align__(16) char Vl[8192];
    __shared__ __align__(16) char Pl[8192];
    int blk = blockIdx.x;
    int qt = 15 - (blk & 15);            // longest first
    int bh = blk >> 4;
    int hh = bh & 15, bb = bh >> 4;
    int tid = threadIdx.x, w = tid >> 6, lane = tid & 63;
    int lg = lane >> 4, lr = lane & 15;

    const ushort_t* qhb = qb + ((size_t)bh*S_ + qt*64 + w*16 + lr) * 64;
    bf16x8_t aq0 = *(const bf16x8_t*)(qhb + lg*8);
    bf16x8_t aq1 = *(const bf16x8_t*)(qhb + 32 + lg*8);

    f32x4_t oacc[4];
    #pragma unroll
    for (int n = 0; n < 4; ++n) oacc[n] = (f32x4_t){0.f,0.f,0.f,0.f};
    float m[4] = {-3.0e38f,-3.0e38f,-3.0e38f,-3.0e38f};
    float l[4] = {0.f,0.f,0.f,0.f};

    int srow = tid >> 2;
    int soff = (tid & 3) * 32;
    const ushort_t* kg = kb  + (size_t)bh * S_ * 64;
    const ushort_t* vg = vtb + (size_t)bh * 64 * S_;

    for (int kt = 0; kt <= qt; ++kt) {
        __syncthreads();
        {
            const ushort_t* src = kg + (size_t)(kt*64 + srow) * 64 + soff/2;
            uint4 v0 = *(const uint4*)src;
            uint4 v1 = *(const uint4*)(src + 8);
            int b0 = (srow*128 + soff) ^ ((srow & 7) << 4);
            int b1 = (srow*128 + soff + 16) ^ ((srow & 7) << 4);
            *(uint4*)(Kl + b0) = v0;
            *(uint4*)(Kl + b1) = v1;
            const ushort_t* vs = vg + (size_t)srow * S_ + kt*64 + soff/2;
            uint4 u0 = *(const uint4*)vs;
            uint4 u1 = *(const uint4*)(vs + 8);
            *(uint4*)(Vl + b0) = u0;
            *(uint4*)(Vl + b1) = u1;
        }
        __syncthreads();

        f32x4_t sfr[4];
        #pragma unroll
        for (int n = 0; n < 4; ++n) sfr[n] = (f32x4_t){0.f,0.f,0.f,0.f};
        #pragma unroll
        for (int n = 0; n < 4; ++n) {
            int row = n*16 + lr;
            int swz = (row & 7) << 4;
            bf16x8_t b0 = *(const bf16x8_t*)(Kl + ((row*128 + lg*16) ^ swz));
            bf16x8_t b1 = *(const bf16x8_t*)(Kl + ((row*128 + 64 + lg*16) ^ swz));
            sfr[n] = __builtin_amdgcn_mfma_f32_16x16x32_bf16(aq0, b0, sfr[n], 0,0,0);
            sfr[n] = __builtin_amdgcn_mfma_f32_16x16x32_bf16(aq1, b1, sfr[n], 0,0,0);
        }

        if (kt == qt) {
            #pragma unroll
            for (int n = 0; n < 4; ++n) {
                int key = n*16 + lr;
                #pragma unroll
                for (int j = 0; j < 4; ++j) {
                    int qrow = w*16 + lg*4 + j;
                    if (key > qrow) sfr[n][j] = -3.0e38f;
                }
            }
        }

        float sc[4];
        #pragma unroll
        for (int j = 0; j < 4; ++j) {
            float v = fmaxf(fmaxf(sfr[0][j], sfr[1][j]), fmaxf(sfr[2][j], sfr[3][j]));
            v = fmaxf(v, __shfl_xor(v, 1));
            v = fmaxf(v, __shfl_xor(v, 2));
            v = fmaxf(v, __shfl_xor(v, 4));
            v = fmaxf(v, __shfl_xor(v, 8));
            float mn = fmaxf(m[j], v);
            sc[j] = __expf(m[j] - mn);
            m[j] = mn;
        }
        #pragma unroll
        for (int n = 0; n < 4; ++n)
            #pragma unroll
            for (int j = 0; j < 4; ++j)
                sfr[n][j] = __expf(sfr[n][j] - m[j]);
        #pragma unroll
        for (int j = 0; j < 4; ++j) {
            float s = sfr[0][j] + sfr[1][j] + sfr[2][j] + sfr[3][j];
            s += __shfl_xor(s, 1);
            s += __shfl_xor(s, 2);
            s += __shfl_xor(s, 4);
            s += __shfl_xor(s, 8);
            l[j] = l[j] * sc[j] + s;
            #pragma unroll
            for (int n = 0; n < 4; ++n) oacc[n][j] *= sc[j];
        }

        #pragma unroll
        for (int n = 0; n < 4; ++n) {
            #pragma unroll
            for (int j = 0; j < 4; ++j) {
                int row = lg*4 + j;
                int byt = (w*2048 + row*128 + (n*16 + lr)*2) ^ ((row & 7) << 4);
                *(ushort_t*)(Pl + byt) = f2bf(sfr[n][j]);
            }
        }
        int pswz = (lr & 7) << 4;
        bf16x8_t pa0 = *(const bf16x8_t*)(Pl + ((w*2048 + lr*128 + lg*16) ^ pswz));
        bf16x8_t pa1 = *(const bf16x8_t*)(Pl + ((w*2048 + lr*128 + 64 + lg*16) ^ pswz));

        #pragma unroll
        for (int n = 0; n < 4; ++n) {
            int row = n*16 + lr;
            int swz = (row & 7) << 4;
            bf16x8_t v0 = *(const bf16x8_t*)(Vl + ((row*128 + lg*16) ^ swz));
            bf16x8_t v1 = *(const bf16x8_t*)(Vl + ((row*128 + 64 + lg*16) ^ swz));
            oacc[n] = __builtin_amdgcn_mfma_f32_16x16x32_bf16(pa0, v0, oacc[n], 0,0,0);
            oacc[n] = __builtin_amdgcn_mfma_f32_16x16x32_bf16(pa1, v1, oacc[n], 0,0,0);
        }
    }

    #pragma unroll
    for (int j = 0; j < 4; ++j) {
        float rl = 1.f / l[j];
        int row = qt*64 + w*16 + lg*4 + j;
        size_t base = (size_t)(bb*S_ + row) * D_ + hh*64;
        #pragma unroll
        for (int n = 0; n < 4; ++n)
            o[base + n*16 + lr] = f2bf(oacc[n][j] * rl);
    }
}

// ------------------------------------------- split-precision MFMA attn, layer 0
__global__ __launch_bounds__(256) void attn_mfma0_k(const ushort_t* __restrict__ qhp,
                                                    const ushort_t* __restrict__ qlp,
                                                    const ushort_t* __restrict__ khp,
                                                    const ushort_t* __restrict__ klp,
                                                    const ushort_t* __restrict__ vtb,
                                                    ushort_t* __restrict__ o) {
    __shared__ __align__(16) char Khl[8192];
    __shared__ __align__(16) char Kll[8192];
    __shared__ __align__(16) char Vl[8192];
    __shared__ __align__(16) char Pl[8192];
    int blk = blockIdx.x;
    int qt = 15 - (blk & 15);
    int bh = blk >> 4;
    int hh = bh & 15, bb = bh >> 4;
    int tid = threadIdx.x, w = tid >> 6, lane = tid & 63;
    int lg = lane >> 4, lr = lane & 15;

    size_t qoff = ((size_t)bh*S_ + qt*64 + w*16 + lr) * 64;
    bf16x8_t aqh0 = *(const bf16x8_t*)(qhp + qoff + lg*8);
    bf16x8_t aqh1 = *(const bf16x8_t*)(qhp + qoff + 32 + lg*8);
    bf16x8_t aql0 = *(const bf16x8_t*)(qlp + qoff + lg*8);
    bf16x8_t aql1 = *(const bf16x8_t*)(qlp + qoff + 32 + lg*8);

    f32x4_t oacc[4];
    #pragma unroll
    for (int n = 0; n < 4; ++n) oacc[n] = (f32x4_t){0.f,0.f,0.f,0.f};
    float m[4] = {-3.0e38f,-3.0e38f,-3.0e38f,-3.0e38f};
    float l[4] = {0.f,0.f,0.f,0.f};

    int srow = tid >> 2;
    int soff = (tid & 3) * 32;
    const ushort_t* kgh = khp + (size_t)bh * S_ * 64;
    const ushort_t* kgl = klp + (size_t)bh * S_ * 64;
    const ushort_t* vg  = vtb + (size_t)bh * 64 * S_;

    for (int kt = 0; kt <= qt; ++kt) {
        __syncthreads();
        {
            int b0 = (srow*128 + soff) ^ ((srow & 7) << 4);
            int b1 = (srow*128 + soff + 16) ^ ((srow & 7) << 4);
            const ushort_t* src = kgh + (size_t)(kt*64 + srow) * 64 + soff/2;
            *(uint4*)(Khl + b0) = *(const uint4*)src;
            *(uint4*)(Khl + b1) = *(const uint4*)(src + 8);
            const ushort_t* srl = kgl + (size_t)(kt*64 + srow) * 64 + soff/2;
            *(uint4*)(Kll + b0) = *(const uint4*)srl;
            *(uint4*)(Kll + b1) = *(const uint4*)(srl + 8);
            const ushort_t* vs = vg + (size_t)srow * S_ + kt*64 + soff/2;
            *(uint4*)(Vl + b0) = *(const uint4*)vs;
            *(uint4*)(Vl + b1) = *(const uint4*)(vs + 8);
        }
        __syncthreads();

        f32x4_t sfr[4];
        #pragma unroll
        for (int n = 0; n < 4; ++n) sfr[n] = (f32x4_t){0.f,0.f,0.f,0.f};
        #pragma unroll
        for (int n = 0; n < 4; ++n) {
            int row = n*16 + lr;
            int swz = (row & 7) << 4;
            bf16x8_t bh0 = *(const bf16x8_t*)(Khl + ((row*128 + lg*16) ^ swz));
            bf16x8_t bh1 = *(const bf16x8_t*)(Khl + ((row*128 + 64 + lg*16) ^ swz));
            bf16x8_t bl0 = *(const bf16x8_t*)(Kll + ((row*128 + lg*16) ^ swz));
            bf16x8_t bl1 = *(const bf16x8_t*)(Kll + ((row*128 + 64 + lg*16) ^ swz));
            sfr[n] = __builtin_amdgcn_mfma_f32_16x16x32_bf16(aqh0, bh0, sfr[n], 0,0,0);
            sfr[n] = __builtin_amdgcn_mfma_f32_16x16x32_bf16(aqh1, bh1, sfr[n], 0,0,0);
            sfr[n] = __builtin_amdgcn_mfma_f32_16x16x32_bf16(aqh0, bl0, sfr[n], 0,0,0);
            sfr[n] = __builtin_amdgcn_mfma_f32_16x16x32_bf16(aqh1, bl1, sfr[n], 0,0,0);
            sfr[n] = __builtin_amdgcn_mfma_f32_16x16x32_bf16(aql0, bh0, sfr[n], 0,0,0);
            sfr[n] = __builtin_amdgcn_mfma_f32_16x16x32_bf16(aql1, bh1, sfr[n], 0,0,0);
        }

        if (kt == qt) {
            #pragma unroll
            for (int n = 0; n < 4; ++n) {
                int key = n*16 + lr;
                #pragma unroll
                for (int j = 0; j < 4; ++j) {
                    int qrow = w*16 + lg*4 + j;
                    if (key > qrow) sfr[n][j] = -3.0e38f;
                }
            }
        }

        float sc[4];
        #pragma unroll
        for (int j = 0; j < 4; ++j) {
            float v = fmaxf(fmaxf(sfr[0][j], sfr[1][j]), fmaxf(sfr[2][j], sfr[3][j]));
            v = fmaxf(v, __shfl_xor(v, 1));
            v = fmaxf(v, __shfl_xor(v, 2));
            v = fmaxf(v, __shfl_xor(v, 4));
            v = fmaxf(v, __shfl_xor(v, 8));
            float mn = fmaxf(m[j], v);
            sc[j] = __expf(m[j] - mn);
            m[j] = mn;
        }
        #pragma unroll
        for (int n = 0; n < 4; ++n)
            #pragma unroll
            for (int j = 0; j < 4; ++j)
                sfr[n][j] = __expf(sfr[n][j] - m[j]);
        #pragma unroll
        for (int j = 0; j < 4; ++j) {
            float s = sfr[0][j] + sfr[1][j] + sfr[2][j] + sfr[3][j];
            s += __shfl_xor(s, 1);
            s += __shfl_xor(s, 2);
            s += __shfl_xor(s, 4);
            s += __shfl_xor(s, 8);
            l[j] = l[j] * sc[j] + s;
            #pragma unroll
            for (int n = 0; n < 4; ++n) oacc[n][j] *= sc[j];
        }

        #pragma unroll
        for (int n = 0; n < 4; ++n) {
            #pragma unroll
            for (int j = 0; j < 4; ++j) {
                int row = lg*4 + j;
                int byt = (w*2048 + row*128 + (n*16 + lr)*2) ^ ((row & 7) << 4);
                *(ushort_t*)(Pl + byt) = f2bf(sfr[n][j]);
            }
        }
        int pswz = (lr & 7) << 4;
        bf16x8_t pa0 = *(const bf16x8_t*)(Pl + ((w*2048 + lr*128 + lg*16) ^ pswz));
        bf16x8_t pa1 = *(const bf16x8_t*)(Pl + ((w*2048 + lr*128 + 64 + lg*16) ^ pswz));

        #pragma unroll
        for (int n = 0; n < 4; ++n) {
            int row = n*16 + lr;
            int swz = (row & 7) << 4;
            bf16x8_t v0 = *(const bf16x8_t*)(Vl + ((row*128 + lg*16) ^ swz));
            bf16x8_t v1 = *(const bf16x8_t*)(Vl + ((row*128 + 64 + lg*16) ^ swz));
            oacc[n] = __builtin_amdgcn_mfma_f32_16x16x32_bf16(pa0, v0, oacc[n], 0,0,0);
            oacc[n] = __builtin_amdgcn_mfma_f32_16x16x32_bf16(pa1, v1, oacc[n], 0,0,0);
        }
    }

    #pragma unroll
    for (int j = 0; j < 4; ++j) {
        float rl = 1.f / l[j];
        int row = qt*64 + w*16 + lg*4 + j;
        size_t base = (size_t)(bb*S_ + row) * D_ + hh*64;
        #pragma unroll
        for (int n = 0; n < 4; ++n)
            o[base + n*16 + lr] = f2bf(oacc[n][j] * rl);
    }
}

// ------------------------------------------------- weight transpose fp32->bf16
__global__ __launch_bounds__(256) void wt_k(const float* __restrict__ W,
                                            ushort_t* __restrict__ Wt,
                                            int K, int N) {
    __shared__ float t[32][33];
    int k0 = blockIdx.y << 5, n0 = blockIdx.x << 5;
    int r = threadIdx.x >> 3, c4 = (threadIdx.x & 7) << 2;
    float4 v = *(const float4*)(W + (size_t)(k0 + r) * N + n0 + c4);
    t[r][c4+0] = v.x; t[r][c4+1] = v.y; t[r][c4+2] = v.z; t[r][c4+3] = v.w;
    __syncthreads();
    ushort4 o;
    o.x = f2bf(t[c4+0][r]); o.y = f2bf(t[c4+1][r]);
    o.z = f2bf(t[c4+2][r]); o.w = f2bf(t[c4+3][r]);
    *(ushort4*)(Wt + (size_t)(n0 + r) * K + k0 + c4) = o;
}

// ---------------------------------- dual-output (hi/lo) transpose, layer-0 Wqkv
__global__ __launch_bounds__(256) void wt2_k(const float* __restrict__ W,
                                             ushort_t* __restrict__ Wth,
                                             ushort_t* __restrict__ Wtl,
                                             int K, int N) {
    __shared__ float t[32][33];
    int k0 = blockIdx.y << 5, n0 = blockIdx.x << 5;
    int r = threadIdx.x >> 3, c4 = (threadIdx.x & 7) << 2;
    float4 v = *(const float4*)(W + (size_t)(k0 + r) * N + n0 + c4);
    t[r][c4+0] = v.x; t[r][c4+1] = v.y; t[r][c4+2] = v.z; t[r][c4+3] = v.w;
    __syncthreads();
    ushort4 oh, ol;
    float v0 = t[c4+0][r], v1 = t[c4+1][r], v2 = t[c4+2][r], v3 = t[c4+3][r];
    oh.x = f2bf(v0); ol.x = f2bf(v0 - bf2f(oh.x));
    oh.y = f2bf(v1); ol.y = f2bf(v1 - bf2f(oh.y));
    oh.z = f2bf(v2); ol.z = f2bf(v2 - bf2f(oh.z));
    oh.w = f2bf(v3); ol.w = f2bf(v3 - bf2f(oh.w));
    size_t off = (size_t)(n0 + r) * K + k0 + c4;
    *(ushort4*)(Wth + off) = oh;
    *(ushort4*)(Wtl + off) = ol;
}

// ---------------------------------------------------------------- GEMM bf16
// C[M,N] = A[M,K] @ Bt[N,K]^T.  Grid: blockIdx.x = M-tiles (fastest) so
// consecutive blocks share the same weight panel (L2-resident, read once).
// epi: 0 = fp32 out, 1 = fp32 out + Res, 2 = gelu->bf16
__device__ __forceinline__ float gelu_f(float x) {
    return 0.5f * x * (1.f + erff(x * 0.70710678118654752f));
}

template<int TM>
__global__ __launch_bounds__(2*TM, 2) void gemm_bf16_k(
    const ushort_t* __restrict__ A,
    const ushort_t* __restrict__ Bt,
    const float* __restrict__ Res,
    float* __restrict__ Cf,
    ushort_t* __restrict__ Cb,
    int M, int N, int K, int epi)
{
    __shared__ __align__(16) ushort_t As[TM * 64];
    __shared__ __align__(16) ushort_t Bs[128 * 64];
    int tid = threadIdx.x;
    int wid = tid >> 6, lane = tid & 63;
    int wm = (TM == 128) ? (wid >> 1) : 0;
    int wn = (TM == 128) ? (wid & 1) : wid;
    int bm = blockIdx.x * TM, bn = blockIdx.y * 128;

    f32x4_t acc[4][4];
    #pragma unroll
    for (int m = 0; m < 4; ++m)
        #pragma unroll
        for (int n = 0; n < 4; ++n)
            acc[m][n] = (f32x4_t){0.f, 0.f, 0.f, 0.f};

    int srow = (lane >> 3);
    int scol = (lane & 7) * 8;

    for (int k0 = 0; k0 < K; k0 += 64) {
        __syncthreads();
        #pragma unroll
        for (int i = 0; i < 4; ++i) {
            int rb = i * (TM/4) + wid * 8;
            gload_lds16(A + (size_t)(bm + rb + srow) * K + k0 + scol, &As[rb * 64]);
        }
        #pragma unroll
        for (int i = 0; i < 512/TM; ++i) {
            int rb = i * (TM/4) + wid * 8;
            gload_lds16(Bt + (size_t)(bn + rb + srow) * K + k0 + scol, &Bs[rb * 64]);
        }
        __syncthreads();
        #pragma unroll
        for (int kk = 0; kk < 64; kk += 32) {
            bf16x8_t af[4], bfr[4];
            int kof = kk + (lane >> 4) * 8;
            #pragma unroll
            for (int m = 0; m < 4; ++m) {
                int r = wm * 64 + m * 16 + (lane & 15);
                af[m] = *(const bf16x8_t*)&As[r * 64 + kof];
            }
            #pragma unroll
            for (int n = 0; n < 4; ++n) {
                int r = wn * 64 + n * 16 + (lane & 15);
                bfr[n] = *(const bf16x8_t*)&Bs[r * 64 + kof];
            }
            #pragma unroll
            for (int m = 0; m < 4; ++m)
                #pragma unroll
                for (int n = 0; n < 4; ++n)
                    acc[m][n] = __builtin_amdgcn_mfma_f32_16x16x32_bf16(
                        af[m], bfr[n], acc[m][n], 0, 0, 0);
        }
    }

    int cr = (lane >> 4) * 4, cc = lane & 15;
    #pragma unroll
    for (int m = 0; m < 4; ++m) {
        int row = bm + wm * 64 + m * 16 + cr;
        #pragma unroll
        for (int n = 0; n < 4; ++n) {
            int col = bn + wn * 64 + n * 16 + cc;
            #pragma unroll
            for (int j = 0; j < 4; ++j) {
                size_t off = (size_t)(row + j) * N + col;
                float v = acc[m][n][j];
                if (epi == 0) {
                    Cf[off] = v;
                } else if (epi == 1) {
                    Cf[off] = Res[off] + v;
                } else {
                    Cb[off] = f2bf(gelu_f(v));
                }
            }
        }
    }
}

// ---------------------------------------- split-precision GEMM (layer-0 QKV)
// C = (Ah+Al)(Bh+Bl)^T approx= Ah Bh + Ah Bl + Al Bh, fp32 accumulate, one pass.
__global__ __launch_bounds__(256, 2) void gemm_split_k(
    const ushort_t* __restrict__ Ah, const ushort_t* __restrict__ Al,
    const ushort_t* __restrict__ Bh, const ushort_t* __restrict__ Bl,
    float* __restrict__ Cf, int M, int N, int K)
{
    __shared__ __align__(16) ushort_t Ash[128 * 64];
    __shared__ __align__(16) ushort_t Asl[128 * 64];
    __shared__ __align__(16) ushort_t Bsh[128 * 64];
    __shared__ __align__(16) ushort_t Bsl[128 * 64];
    int tid = threadIdx.x;
    int wid = tid >> 6, lane = tid & 63;
    int wm = wid >> 1, wn = wid & 1;
    int bm = blockIdx.x * 128, bn = blockIdx.y * 128;

    f32x4_t acc[4][4];
    #pragma unroll
    for (int m = 0; m < 4; ++m)
        #pragma unroll
        for (int n = 0; n < 4; ++n)
            acc[m][n] = (f32x4_t){0.f, 0.f, 0.f, 0.f};

    int srow = (lane >> 3);
    int scol = (lane & 7) * 8;

    for (int k0 = 0; k0 < K; k0 += 64) {
        __syncthreads();
        #pragma unroll
        for (int i = 0; i < 4; ++i) {
            int rb = i * 32 + wid * 8;
            size_t ga = (size_t)(bm + rb + srow) * K + k0 + scol;
            size_t gb = (size_t)(bn + rb + srow) * K + k0 + scol;
            gload_lds16(Ah + ga, &Ash[rb * 64]);
            gload_lds16(Al + ga, &Asl[rb * 64]);
            gload_lds16(Bh + gb, &Bsh[rb * 64]);
            gload_lds16(Bl + gb, &Bsl[rb * 64]);
        }
        __syncthreads();
        #pragma unroll
        for (int kk = 0; kk < 64; kk += 32) {
            bf16x8_t ah[4], al[4], bhf[4], blf[4];
            int kof = kk + (lane >> 4) * 8;
            #pragma unroll
            for (int m = 0; m < 4; ++m) {
                int r = wm * 64 + m * 16 + (lane & 15);
                ah[m] = *(const bf16x8_t*)&Ash[r * 64 + kof];
                al[m] = *(const bf16x8_t*)&Asl[r * 64 + kof];
            }
            #pragma unroll
            for (int n = 0; n < 4; ++n) {
                int r = wn * 64 + n * 16 + (lane & 15);
                bhf[n] = *(const bf16x8_t*)&Bsh[r * 64 + kof];
                blf[n] = *(const bf16x8_t*)&Bsl[r * 64 + kof];
            }
            #pragma unroll
            for (int m = 0; m < 4; ++m)
                #pragma unroll
                for (int n = 0; n < 4; ++n) {
                    acc[m][n] = __builtin_amdgcn_mfma_f32_16x16x32_bf16(
                        ah[m], bhf[n], acc[m][n], 0, 0, 0);
                    acc[m][n] = __builtin_amdgcn_mfma_f32_16x16x32_bf16(
                        ah[m], blf[n], acc[m][n], 0, 0, 0);
                    acc[m][n] = __builtin_amdgcn_mfma_f32_16x16x32_bf16(
                        al[m], bhf[n], acc[m][n], 0, 0, 0);
                }
        }
    }

    int cr = (lane >> 4) * 4, cc = lane & 15;
    #pragma unroll
    for (int m = 0; m < 4; ++m) {
        int row = bm + wm * 64 + m * 16 + cr;
        #pragma unroll
        for (int n = 0; n < 4; ++n) {
            int col = bn + wn * 64 + n * 16 + cc;
            #pragma unroll
            for (int j = 0; j < 4; ++j)
                Cf[(size_t)(row + j) * N + col] = acc[m][n][j];
        }
    }
}

// ---------------------------------------------------------------- launch
extern "C" void kernel_launch(void* const* d_in, const int* in_sizes, int n_in,
                              void* d_out, int out_size, void* d_ws, size_t ws_size,
                              hipStream_t stream) {
    const int*   x    = (const int*)  d_in[0];
    const float* emb  = (const float*)d_in[1];
    const float* ln1w = (const float*)d_in[2];
    const float* ln1b = (const float*)d_in[3];
    const float* Wqkv = (const float*)d_in[4];
    const float* Wo   = (const float*)d_in[5];
    const float* ln2w = (const float*)d_in[6];
    const float* ln2b = (const float*)d_in[7];
    const float* W1   = (const float*)d_in[8];
    const float* W2   = (const float*)d_in[9];
    const float* lnfw = (const float*)d_in[10];
    const float* lnfb = (const float*)d_in[11];
    const float* Wdec = (const float*)d_in[12];
    float* out = (float*)d_out;

    // ---- workspace layout (bytes), lifetime-aliased, 80 MB total ----
    char* ws = (char*)d_ws;
    float*    h     = (float*)   (ws + 0);              // 8 MB  [2048,1024] f32
    ushort_t* xnb   = (ushort_t*)(ws + (8u<<20));       // 4 MB  bf16 (xh for l=0)
    ushort_t* ob    = (ushort_t*)(ws + (12u<<20));      // 4 MB  bf16 (xl for l=0, pre-attn)
    float*    qkv   = (float*)   (ws + (16u<<20));      // 24 MB [2048,3072] f32
    ushort_t* ffb   = (ushort_t*)(ws + (40u<<20));      // 16 MB [2048,4096] bf16 (W1 out)
    ushort_t* q_bf  = (ushort_t*)(ws + (40u<<20));      // 4 MB  (l>=1) / qh (l=0)
    ushort_t* k_bf  = (ushort_t*)(ws + (44u<<20));      // 4 MB  (l>=1) / ql (l=0)
    ushort_t* vT_bf = (ushort_t*)(ws + (48u<<20));      // 4 MB  (l>=1) / kh (l=0)
    ushort_t* vT0   = (ushort_t*)(ws + (52u<<20));      // 4 MB  vT (l=0)
    ushort_t* wqkvT = (ushort_t*)(ws + (56u<<20));      // 6 MB  [3072,1024] bf16 (hi for l=0)
    ushort_t* wqkvTl= (ushort_t*)(ws + (62u<<20));      // 6 MB  lo (l=0 only; dead pre-woT/w1T)
    ushort_t* kl0   = (ushort_t*)(ws + (62u<<20));      // 4 MB  kl (l=0; dead pre-woT)
    ushort_t* woT   = (ushort_t*)(ws + (62u<<20));      // 2 MB  [1024,1024] bf16
    ushort_t* w1T   = (ushort_t*)(ws + (64u<<20));      // 8 MB  [4096,1024] bf16
    ushort_t* w2T   = (ushort_t*)(ws + (72u<<20));      // 8 MB  [1024,4096] bf16
    ushort_t* wdecT = (ushort_t*)(ws + (16u<<20));      // 64 MB, aliases qkv..w2T (post-loop)

    embed_k<<<M_, 256, 0, stream>>>(x, emb, h);
    for (int l = 0; l < L_; ++l) {
        if (l == 0) {
            // split-precision path: scores need fp32-grade accuracy (sharp softmax)
            layernorm_k<<<M_, 256, 0, stream>>>(h, ln1w, ln1b, xnb, ob /*=xl*/);
            wt2_k<<<dim3(3*D_/32, D_/32), 256, 0, stream>>>(Wqkv, wqkvT, wqkvTl, D_, 3*D_);
            gemm_split_k<<<dim3(M_/128, 3*D_/128), 256, 0, stream>>>(
                xnb, ob /*=xl*/, wqkvT, wqkvTl, qkv, M_, 3*D_, D_);
            qkv_cvt0_k<<<B_*H_*(S_/64), 256, 0, stream>>>(
                qkv, q_bf /*qh*/, k_bf /*ql*/, vT_bf /*kh*/, kl0, vT0);
            attn_mfma0_k<<<B_*H_*(S_/64), 256, 0, stream>>>(
                q_bf, k_bf, vT_bf, kl0, vT0, ob);
        } else {
            layernorm_k<<<M_, 256, 0, stream>>>(h, ln1w + l*D_, ln1b + l*D_, xnb, nullptr);
            wt_k<<<dim3(3*D_/32, D_/32), 256, 0, stream>>>(
                Wqkv + (size_t)l*D_*3*D_, wqkvT, D_, 3*D_);
            gemm_bf16_k<128><<<dim3(M_/128, 3*D_/128), 256, 0, stream>>>(
                xnb, wqkvT, nullptr, qkv, nullptr, M_, 3*D_, D_, 0);
            qkv_cvt_k<<<B_*H_*(S_/64), 256, 0, stream>>>(qkv, q_bf, k_bf, vT_bf);
            attn_mfma_k<<<B_*H_*(S_/64), 256, 0, stream>>>(q_bf, k_bf, vT_bf, ob);
        }
        wt_k<<<dim3(D_/32, D_/32), 256, 0, stream>>>(
            Wo + (size_t)l*D_*D_, woT, D_, D_);
        gemm_bf16_k<64><<<dim3(M_/64, D_/128), 128, 0, stream>>>(
            ob, woT, h, h, nullptr, M_, D_, D_, 1);
        layernorm_k<<<M_, 256, 0, stream>>>(h, ln2w + l*D_, ln2b + l*D_, xnb, nullptr);
        wt_k<<<dim3(DFF_/32, D_/32), 256, 0, stream>>>(
            W1 + (size_t)l*D_*DFF_, w1T, D_, DFF_);
        gemm_bf16_k<128><<<dim3(M_/128, DFF_/128), 256, 0, stream>>>(
            xnb, w1T, nullptr, nullptr, ffb, M_, DFF_, D_, 2);
        wt_k<<<dim3(D_/32, DFF_/32), 256, 0, stream>>>(
            W2 + (size_t)l*DFF_*D_, w2T, DFF_, D_);
        gemm_bf16_k<64><<<dim3(M_/64, D_/128), 128, 0, stream>>>(
            ffb, w2T, h, h, nullptr, M_, D_, DFF_, 1);
    }
    layernorm_k<<<M_, 256, 0, stream>>>(h, lnfw, lnfb, xnb, nullptr);
    wt_k<<<dim3(V_/32, D_/32), 256, 0, stream>>>(Wdec, wdecT, D_, V_);
    gemm_bf16_k<128><<<dim3(M_/128, V_/128), 256, 0, stream>>>(
        xnb, wdecT, nullptr, out, nullptr, M_, V_, D_, 0);
}

// Round 8
// 2199.426 us; speedup vs baseline: 8.7005x; 1.0304x over previous
//
#include <hip/hip_runtime.h>
#include <hip/hip_bf16.h>
#include <math.h>

#define B_ 2
#define S_ 1024
#define D_ 1024
#define H_ 16
#define HD_ 64
#define L_ 8
#define DFF_ 4096
#define V_ 32000
#define M_ (B_*S_)   /* 2048 rows */

typedef unsigned short ushort_t;
typedef __attribute__((ext_vector_type(8))) __bf16 bf16x8_t;
typedef __attribute__((ext_vector_type(4))) float f32x4_t;

__device__ __forceinline__ ushort_t f2bf(float f) {
    union { float f; unsigned u; } x; x.f = f;
    unsigned r = x.u + 0x7fffu + ((x.u >> 16) & 1u);
    return (ushort_t)(r >> 16);
}
__device__ __forceinline__ float bf2f(ushort_t u) {
    union { unsigned u; float f; } x; x.u = ((unsigned)u) << 16; return x.f;
}

__device__ __forceinline__ void gload_lds16(const void* g, void* l) {
    __builtin_amdgcn_global_load_lds(
        (const __attribute__((address_space(1))) void*)g,
        (__attribute__((address_space(3))) void*)l, 16, 0, 0);
}

// ---------------------------------------------------------------- embedding
__global__ __launch_bounds__(256) void embed_k(const int* __restrict__ x,
                                               const float* __restrict__ emb,
                                               float* __restrict__ h) {
    int row = blockIdx.x;
    int tok = x[row];
    const float4* src = (const float4*)(emb + (size_t)tok * D_);
    float4* dst = (float4*)(h + (size_t)row * D_);
    dst[threadIdx.x] = src[threadIdx.x];
}

// ---------------------------------------------------------------- layernorm
// Faithful: out = w*(x-m)/(var + 1e-12) + b   (NO sqrt).
__global__ __launch_bounds__(256) void layernorm_k(const float* __restrict__ x,
                                                   const float* __restrict__ w,
                                                   const float* __restrict__ bb,
                                                   ushort_t* __restrict__ out16,
                                                   ushort_t* __restrict__ out16l) {
    int row = blockIdx.x;
    const float4* xr = (const float4*)(x + (size_t)row * D_);
    float4 v = xr[threadIdx.x];
    float s = v.x + v.y + v.z + v.w;
    #pragma unroll
    for (int off = 32; off; off >>= 1) s += __shfl_xor(s, off);
    __shared__ float red1[4];
    __shared__ float red2[4];
    int wave = threadIdx.x >> 6, lane = threadIdx.x & 63;
    if (lane == 0) red1[wave] = s;
    __syncthreads();
    float m = (red1[0] + red1[1] + red1[2] + red1[3]) * (1.f / 1024.f);
    float dx = v.x - m, dy = v.y - m, dz = v.z - m, dw = v.w - m;
    float ss = dx*dx + dy*dy + dz*dz + dw*dw;
    #pragma unroll
    for (int off = 32; off; off >>= 1) ss += __shfl_xor(ss, off);
    if (lane == 0) red2[wave] = ss;
    __syncthreads();
    float var = (red2[0] + red2[1] + red2[2] + red2[3]) * (1.f / 1024.f);
    float inv = 1.f / (var + 1e-12f);
    float4 wv = ((const float4*)w)[threadIdx.x];
    float4 bv = ((const float4*)bb)[threadIdx.x];
    float4 ov;
    ov.x = wv.x * dx * inv + bv.x;
    ov.y = wv.y * dy * inv + bv.y;
    ov.z = wv.z * dz * inv + bv.z;
    ov.w = wv.w * dw * inv + bv.w;
    ushort4 oh;
    oh.x = f2bf(ov.x); oh.y = f2bf(ov.y); oh.z = f2bf(ov.z); oh.w = f2bf(ov.w);
    ((ushort4*)(out16 + (size_t)row * D_))[threadIdx.x] = oh;
    if (out16l) {
        ushort4 ol;
        ol.x = f2bf(ov.x - bf2f(oh.x));
        ol.y = f2bf(ov.y - bf2f(oh.y));
        ol.z = f2bf(ov.z - bf2f(oh.z));
        ol.w = f2bf(ov.w - bf2f(oh.w));
        ((ushort4*)(out16l + (size_t)row * D_))[threadIdx.x] = ol;
    }
}

// ----------------------------------------------- v [bh][s][64] -> vT [bh][d][s]
__global__ __launch_bounds__(256) void vt_k(const ushort_t* __restrict__ vb,
                                            ushort_t* __restrict__ vtb) {
    __shared__ ushort_t t[64][72];
    int blk = blockIdx.x;            // bh*16 + st
    int st = blk & 15, bh = blk >> 4;
    int tid = threadIdx.x;
    int sr = tid >> 2, c0 = (tid & 3) * 16;
    const ushort_t* src = vb + ((size_t)bh*S_ + st*64 + sr) * 64 + c0;
    *(uint4*)&t[sr][c0]     = *(const uint4*)src;
    *(uint4*)&t[sr][c0 + 8] = *(const uint4*)(src + 8);
    __syncthreads();
    int d = tid >> 2, s0 = (tid & 3) * 16;
    ushort_t vo[16];
    #pragma unroll
    for (int u = 0; u < 16; ++u) vo[u] = t[s0+u][d];
    size_t vout = ((size_t)bh*64 + d) * S_ + st*64 + s0;
    *(uint4*)(vtb + vout)     = *(uint4*)&vo[0];
    *(uint4*)(vtb + vout + 8) = *(uint4*)&vo[8];
}

// ------------------------------------------- bf16 MFMA flash attn (layers>=1)
__global__ __launch_bounds__(256) void attn_mfma_k(const ushort_t* __restrict__ qb,
                                                   const ushort_t* __restrict__ kb,
                                                   const ushort_t* __restrict__ vtb,
                                                   ushort_t* __restrict__ o) {
    __shared__ __align__(16) char Kl[8192];
    __shared__ __align__(16) char Vl[8192];
    __shared__ __align__(16) char Pl[8192];
    int blk = blockIdx.x;
    int qt = 15 - (blk & 15);            // longest first
    int bh = blk >> 4;
    int hh = bh & 15, bb = bh >> 4;
    int tid = threadIdx.x, w = tid >> 6, lane = tid & 63;
    int lg = lane >> 4, lr = lane & 15;

    const ushort_t* qhb = qb + ((size_t)bh*S_ + qt*64 + w*16 + lr) * 64;
    bf16x8_t aq0 = *(const bf16x8_t*)(qhb + lg*8);
    bf16x8_t aq1 = *(const bf16x8_t*)(qhb + 32 + lg*8);

    f32x4_t oacc[4];
    #pragma unroll
    for (int n = 0; n < 4; ++n) oacc[n] = (f32x4_t){0.f,0.f,0.f,0.f};
    float m[4] = {-3.0e38f,-3.0e38f,-3.0e38f,-3.0e38f};
    float l[4] = {0.f,0.f,0.f,0.f};

    int srow = tid >> 2;
    int soff = (tid & 3) * 32;
    const ushort_t* kg = kb  + (size_t)bh * S_ * 64;
    const ushort_t* vg = vtb + (size_t)bh * 64 * S_;

    for (int kt = 0; kt <= qt; ++kt) {
        __syncthreads();
        {
            const ushort_t* src = kg + (size_t)(kt*64 + srow) * 64 + soff/2;
            uint4 v0 = *(const uint4*)src;
            uint4 v1 = *(const uint4*)(src + 8);
            int b0 = (srow*128 + soff) ^ ((srow & 7) << 4);
            int b1 = (srow*128 + soff + 16) ^ ((srow & 7) << 4);
            *(uint4*)(Kl + b0) = v0;
            *(uint4*)(Kl + b1) = v1;
            const ushort_t* vs = vg + (size_t)srow * S_ + kt*64 + soff/2;
            uint4 u0 = *(const uint4*)vs;
            uint4 u1 = *(const uint4*)(vs + 8);
            *(uint4*)(Vl + b0) = u0;
            *(uint4*)(Vl + b1) = u1;
        }
        __syncthreads();

        f32x4_t sfr[4];
        #pragma unroll
        for (int n = 0; n < 4; ++n) sfr[n] = (f32x4_t){0.f,0.f,0.f,0.f};
        #pragma unroll
        for (int n = 0; n < 4; ++n) {
            int row = n*16 + lr;
            int swz = (row & 7) << 4;
            bf16x8_t b0 = *(const bf16x8_t*)(Kl + ((row*128 + lg*16) ^ swz));
            bf16x8_t b1 = *(const bf16x8_t*)(Kl + ((row*128 + 64 + lg*16) ^ swz));
            sfr[n] = __builtin_amdgcn_mfma_f32_16x16x32_bf16(aq0, b0, sfr[n], 0,0,0);
            sfr[n] = __builtin_amdgcn_mfma_f32_16x16x32_bf16(aq1, b1, sfr[n], 0,0,0);
        }

        if (kt == qt) {
            #pragma unroll
            for (int n = 0; n < 4; ++n) {
                int key = n*16 + lr;
                #pragma unroll
                for (int j = 0; j < 4; ++j) {
                    int qrow = w*16 + lg*4 + j;
                    if (key > qrow) sfr[n][j] = -3.0e38f;
                }
            }
        }

        float sc[4];
        #pragma unroll
        for (int j = 0; j < 4; ++j) {
            float v = fmaxf(fmaxf(sfr[0][j], sfr[1][j]), fmaxf(sfr[2][j], sfr[3][j]));
            v = fmaxf(v, __shfl_xor(v, 1));
            v = fmaxf(v, __shfl_xor(v, 2));
            v = fmaxf(v, __shfl_xor(v, 4));
            v = fmaxf(v, __shfl_xor(v, 8));
            float mn = fmaxf(m[j], v);
            sc[j] = __expf(m[j] - mn);
            m[j] = mn;
        }
        #pragma unroll
        for (int n = 0; n < 4; ++n)
            #pragma unroll
            for (int j = 0; j < 4; ++j)
                sfr[n][j] = __expf(sfr[n][j] - m[j]);
        #pragma unroll
        for (int j = 0; j < 4; ++j) {
            float s = sfr[0][j] + sfr[1][j] + sfr[2][j] + sfr[3][j];
            s += __shfl_xor(s, 1);
            s += __shfl_xor(s, 2);
            s += __shfl_xor(s, 4);
            s += __shfl_xor(s, 8);
            l[j] = l[j] * sc[j] + s;
            #pragma unroll
            for (int n = 0; n < 4; ++n) oacc[n][j] *= sc[j];
        }

        #pragma unroll
        for (int n = 0; n < 4; ++n) {
            #pragma unroll
            for (int j = 0; j < 4; ++j) {
                int row = lg*4 + j;
                int byt = (w*2048 + row*128 + (n*16 + lr)*2) ^ ((row & 7) << 4);
                *(ushort_t*)(Pl + byt) = f2bf(sfr[n][j]);
            }
        }
        int pswz = (lr & 7) << 4;
        bf16x8_t pa0 = *(const bf16x8_t*)(Pl + ((w*2048 + lr*128 + lg*16) ^ pswz));
        bf16x8_t pa1 = *(const bf16x8_t*)(Pl + ((w*2048 + lr*128 + 64 + lg*16) ^ pswz));

        #pragma unroll
        for (int n = 0; n < 4; ++n) {
            int row = n*16 + lr;
            int swz = (row & 7) << 4;
            bf16x8_t v0 = *(const bf16x8_t*)(Vl + ((row*128 + lg*16) ^ swz));
            bf16x8_t v1 = *(const bf16x8_t*)(Vl + ((row*128 + 64 + lg*16) ^ swz));
            oacc[n] = __builtin_amdgcn_mfma_f32_16x16x32_bf16(pa0, v0, oacc[n], 0,0,0);
            oacc[n] = __builtin_amdgcn_mfma_f32_16x16x32_bf16(pa1, v1, oacc[n], 0,0,0);
        }
    }

    #pragma unroll
    for (int j = 0; j < 4; ++j) {
        float rl = 1.f / l[j];
        int row = qt*64 + w*16 + lg*4 + j;
        size_t base = (size_t)(bb*S_ + row) * D_ + hh*64;
        #pragma unroll
        for (int n = 0; n < 4; ++n)
            o[base + n*16 + lr] = f2bf(oacc[n][j] * rl);
    }
}

// ------------------------------------------- split-precision MFMA attn, layer 0
__global__ __launch_bounds__(256) void attn_mfma0_k(const ushort_t* __restrict__ qhp,
                                                    const ushort_t* __restrict__ qlp,
                                                    const ushort_t* __restrict__ khp,
                                                    const ushort_t* __restrict__ klp,
                                                    const ushort_t* __restrict__ vtb,
                                                    ushort_t* __restrict__ o) {
    __shared__ __align__(16) char Khl[8192];
    __shared__ __align__(16) char Kll[8192];
    __shared__ __align__(16) char Vl[8192];
    __shared__ __align__(16) char Pl[8192];
    int blk = blockIdx.x;
    int qt = 15 - (blk & 15);
    int bh = blk >> 4;
    int hh = bh & 15, bb = bh >> 4;
    int tid = threadIdx.x, w = tid >> 6, lane = tid & 63;
    int lg = lane >> 4, lr = lane & 15;

    size_t qoff = ((size_t)bh*S_ + qt*64 + w*16 + lr) * 64;
    bf16x8_t aqh0 = *(const bf16x8_t*)(qhp + qoff + lg*8);
    bf16x8_t aqh1 = *(const bf16x8_t*)(qhp + qoff + 32 + lg*8);
    bf16x8_t aql0 = *(const bf16x8_t*)(qlp + qoff + lg*8);
    bf16x8_t aql1 = *(const bf16x8_t*)(qlp + qoff + 32 + lg*8);

    f32x4_t oacc[4];
    #pragma unroll
    for (int n = 0; n < 4; ++n) oacc[n] = (f32x4_t){0.f,0.f,0.f,0.f};
    float m[4] = {-3.0e38f,-3.0e38f,-3.0e38f,-3.0e38f};
    float l[4] = {0.f,0.f,0.f,0.f};

    int srow = tid >> 2;
    int soff = (tid & 3) * 32;
    const ushort_t* kgh = khp + (size_t)bh * S_ * 64;
    const ushort_t* kgl = klp + (size_t)bh * S_ * 64;
    const ushort_t* vg  = vtb + (size_t)bh * 64 * S_;

    for (int kt = 0; kt <= qt; ++kt) {
        __syncthreads();
        {
            int b0 = (srow*128 + soff) ^ ((srow & 7) << 4);
            int b1 = (srow*128 + soff + 16) ^ ((srow & 7) << 4);
            const ushort_t* src = kgh + (size_t)(kt*64 + srow) * 64 + soff/2;
            *(uint4*)(Khl + b0) = *(const uint4*)src;
            *(uint4*)(Khl + b1) = *(const uint4*)(src + 8);
            const ushort_t* srl = kgl + (size_t)(kt*64 + srow) * 64 + soff/2;
            *(uint4*)(Kll + b0) = *(const uint4*)srl;
            *(uint4*)(Kll + b1) = *(const uint4*)(srl + 8);
            const ushort_t* vs = vg + (size_t)srow * S_ + kt*64 + soff/2;
            *(uint4*)(Vl + b0) = *(const uint4*)vs;
            *(uint4*)(Vl + b1) = *(const uint4*)(vs + 8);
        }
        __syncthreads();

        f32x4_t sfr[4];
        #pragma unroll
        for (int n = 0; n < 4; ++n) sfr[n] = (f32x4_t){0.f,0.f,0.f,0.f};
        #pragma unroll
        for (int n = 0; n < 4; ++n) {
            int row = n*16 + lr;
            int swz = (row & 7) << 4;
            bf16x8_t bh0 = *(const bf16x8_t*)(Khl + ((row*128 + lg*16) ^ swz));
            bf16x8_t bh1 = *(const bf16x8_t*)(Khl + ((row*128 + 64 + lg*16) ^ swz));
            bf16x8_t bl0 = *(const bf16x8_t*)(Kll + ((row*128 + lg*16) ^ swz));
            bf16x8_t bl1 = *(const bf16x8_t*)(Kll + ((row*128 + 64 + lg*16) ^ swz));
            sfr[n] = __builtin_amdgcn_mfma_f32_16x16x32_bf16(aqh0, bh0, sfr[n], 0,0,0);
            sfr[n] = __builtin_amdgcn_mfma_f32_16x16x32_bf16(aqh1, bh1, sfr[n], 0,0,0);
            sfr[n] = __builtin_amdgcn_mfma_f32_16x16x32_bf16(aqh0, bl0, sfr[n], 0,0,0);
            sfr[n] = __builtin_amdgcn_mfma_f32_16x16x32_bf16(aqh1, bl1, sfr[n], 0,0,0);
            sfr[n] = __builtin_amdgcn_mfma_f32_16x16x32_bf16(aql0, bh0, sfr[n], 0,0,0);
            sfr[n] = __builtin_amdgcn_mfma_f32_16x16x32_bf16(aql1, bh1, sfr[n], 0,0,0);
        }

        if (kt == qt) {
            #pragma unroll
            for (int n = 0; n < 4; ++n) {
                int key = n*16 + lr;
                #pragma unroll
                for (int j = 0; j < 4; ++j) {
                    int qrow = w*16 + lg*4 + j;
                    if (key > qrow) sfr[n][j] = -3.0e38f;
                }
            }
        }

        float sc[4];
        #pragma unroll
        for (int j = 0; j < 4; ++j) {
            float v = fmaxf(fmaxf(sfr[0][j], sfr[1][j]), fmaxf(sfr[2][j], sfr[3][j]));
            v = fmaxf(v, __shfl_xor(v, 1));
            v = fmaxf(v, __shfl_xor(v, 2));
            v = fmaxf(v, __shfl_xor(v, 4));
            v = fmaxf(v, __shfl_xor(v, 8));
            float mn = fmaxf(m[j], v);
            sc[j] = __expf(m[j] - mn);
            m[j] = mn;
        }
        #pragma unroll
        for (int n = 0; n < 4; ++n)
            #pragma unroll
            for (int j = 0; j < 4; ++j)
                sfr[n][j] = __expf(sfr[n][j] - m[j]);
        #pragma unroll
        for (int j = 0; j < 4; ++j) {
            float s = sfr[0][j] + sfr[1][j] + sfr[2][j] + sfr[3][j];
            s += __shfl_xor(s, 1);
            s += __shfl_xor(s, 2);
            s += __shfl_xor(s, 4);
            s += __shfl_xor(s, 8);
            l[j] = l[j] * sc[j] + s;
            #pragma unroll
            for (int n = 0; n < 4; ++n) oacc[n][j] *= sc[j];
        }

        #pragma unroll
        for (int n = 0; n < 4; ++n) {
            #pragma unroll
            for (int j = 0; j < 4; ++j) {
                int row = lg*4 + j;
                int byt = (w*2048 + row*128 + (n*16 + lr)*2) ^ ((row & 7) << 4);
                *(ushort_t*)(Pl + byt) = f2bf(sfr[n][j]);
            }
        }
        int pswz = (lr & 7) << 4;
        bf16x8_t pa0 = *(const bf16x8_t*)(Pl + ((w*2048 + lr*128 + lg*16) ^ pswz));
        bf16x8_t pa1 = *(const bf16x8_t*)(Pl + ((w*2048 + lr*128 + 64 + lg*16) ^ pswz));

        #pragma unroll
        for (int n = 0; n < 4; ++n) {
            int row = n*16 + lr;
            int swz = (row & 7) << 4;
            bf16x8_t v0 = *(const bf16x8_t*)(Vl + ((row*128 + lg*16) ^ swz));
            bf16x8_t v1 = *(const bf16x8_t*)(Vl + ((row*128 + 64 + lg*16) ^ swz));
            oacc[n] = __builtin_amdgcn_mfma_f32_16x16x32_bf16(pa0, v0, oacc[n], 0,0,0);
            oacc[n] = __builtin_amdgcn_mfma_f32_16x16x32_bf16(pa1, v1, oacc[n], 0,0,0);
        }
    }

    #pragma unroll
    for (int j = 0; j < 4; ++j) {
        float rl = 1.f / l[j];
        int row = qt*64 + w*16 + lg*4 + j;
        size_t base = (size_t)(bb*S_ + row) * D_ + hh*64;
        #pragma unroll
        for (int n = 0; n < 4; ++n)
            o[base + n*16 + lr] = f2bf(oacc[n][j] * rl);
    }
}

// ------------------------------------------------- weight transpose fp32->bf16
__global__ __launch_bounds__(256) void wt_k(const float* __restrict__ W,
                                            ushort_t* __restrict__ Wt,
                                            int K, int N) {
    __shared__ float t[32][33];
    int k0 = blockIdx.y << 5, n0 = blockIdx.x << 5;
    int r = threadIdx.x >> 3, c4 = (threadIdx.x & 7) << 2;
    float4 v = *(const float4*)(W + (size_t)(k0 + r) * N + n0 + c4);
    t[r][c4+0] = v.x; t[r][c4+1] = v.y; t[r][c4+2] = v.z; t[r][c4+3] = v.w;
    __syncthreads();
    ushort4 o;
    o.x = f2bf(t[c4+0][r]); o.y = f2bf(t[c4+1][r]);
    o.z = f2bf(t[c4+2][r]); o.w = f2bf(t[c4+3][r]);
    *(ushort4*)(Wt + (size_t)(n0 + r) * K + k0 + c4) = o;
}

// ---------------------------------- dual-output (hi/lo) transpose, layer-0 Wqkv
__global__ __launch_bounds__(256) void wt2_k(const float* __restrict__ W,
                                             ushort_t* __restrict__ Wth,
                                             ushort_t* __restrict__ Wtl,
                                             int K, int N) {
    __shared__ float t[32][33];
    int k0 = blockIdx.y << 5, n0 = blockIdx.x << 5;
    int r = threadIdx.x >> 3, c4 = (threadIdx.x & 7) << 2;
    float4 v = *(const float4*)(W + (size_t)(k0 + r) * N + n0 + c4);
    t[r][c4+0] = v.x; t[r][c4+1] = v.y; t[r][c4+2] = v.z; t[r][c4+3] = v.w;
    __syncthreads();
    ushort4 oh, ol;
    float v0 = t[c4+0][r], v1 = t[c4+1][r], v2 = t[c4+2][r], v3 = t[c4+3][r];
    oh.x = f2bf(v0); ol.x = f2bf(v0 - bf2f(oh.x));
    oh.y = f2bf(v1); ol.y = f2bf(v1 - bf2f(oh.y));
    oh.z = f2bf(v2); ol.z = f2bf(v2 - bf2f(oh.z));
    oh.w = f2bf(v3); ol.w = f2bf(v3 - bf2f(oh.w));
    size_t off = (size_t)(n0 + r) * K + k0 + c4;
    *(ushort4*)(Wth + off) = oh;
    *(ushort4*)(Wtl + off) = ol;
}

// ---------------------------------------------------------------- GEMM bf16
// C[M,N] = A[M,K] @ Bt[N,K]^T.  blockIdx.x = M-tiles (fastest) for weight-panel
// L2 reuse.  epi: 0 = fp32 out (non-temporal), 1 = fp32 out + Res, 2 = gelu->bf16
__device__ __forceinline__ float gelu_f(float x) {
    return 0.5f * x * (1.f + erff(x * 0.70710678118654752f));
}

template<int TM>
__global__ __launch_bounds__(2*TM, 2) void gemm_bf16_k(
    const ushort_t* __restrict__ A,
    const ushort_t* __restrict__ Bt,
    const float* __restrict__ Res,
    float* __restrict__ Cf,
    ushort_t* __restrict__ Cb,
    int M, int N, int K, int epi)
{
    __shared__ __align__(16) ushort_t As[TM * 64];
    __shared__ __align__(16) ushort_t Bs[128 * 64];
    int tid = threadIdx.x;
    int wid = tid >> 6, lane = tid & 63;
    int wm = (TM == 128) ? (wid >> 1) : 0;
    int wn = (TM == 128) ? (wid & 1) : wid;
    int bm = blockIdx.x * TM, bn = blockIdx.y * 128;

    f32x4_t acc[4][4];
    #pragma unroll
    for (int m = 0; m < 4; ++m)
        #pragma unroll
        for (int n = 0; n < 4; ++n)
            acc[m][n] = (f32x4_t){0.f, 0.f, 0.f, 0.f};

    int srow = (lane >> 3);
    int scol = (lane & 7) * 8;

    for (int k0 = 0; k0 < K; k0 += 64) {
        __syncthreads();
        #pragma unroll
        for (int i = 0; i < 4; ++i) {
            int rb = i * (TM/4) + wid * 8;
            gload_lds16(A + (size_t)(bm + rb + srow) * K + k0 + scol, &As[rb * 64]);
        }
        #pragma unroll
        for (int i = 0; i < 512/TM; ++i) {
            int rb = i * (TM/4) + wid * 8;
            gload_lds16(Bt + (size_t)(bn + rb + srow) * K + k0 + scol, &Bs[rb * 64]);
        }
        __syncthreads();
        #pragma unroll
        for (int kk = 0; kk < 64; kk += 32) {
            bf16x8_t af[4], bfr[4];
            int kof = kk + (lane >> 4) * 8;
            #pragma unroll
            for (int m = 0; m < 4; ++m) {
                int r = wm * 64 + m * 16 + (lane & 15);
                af[m] = *(const bf16x8_t*)&As[r * 64 + kof];
            }
            #pragma unroll
            for (int n = 0; n < 4; ++n) {
                int r = wn * 64 + n * 16 + (lane & 15);
                bfr[n] = *(const bf16x8_t*)&Bs[r * 64 + kof];
            }
            #pragma unroll
            for (int m = 0; m < 4; ++m)
                #pragma unroll
                for (int n = 0; n < 4; ++n)
                    acc[m][n] = __builtin_amdgcn_mfma_f32_16x16x32_bf16(
                        af[m], bfr[n], acc[m][n], 0, 0, 0);
        }
    }

    int cr = (lane >> 4) * 4, cc = lane & 15;
    #pragma unroll
    for (int m = 0; m < 4; ++m) {
        int row = bm + wm * 64 + m * 16 + cr;
        #pragma unroll
        for (int n = 0; n < 4; ++n) {
            int col = bn + wn * 64 + n * 16 + cc;
            #pragma unroll
            for (int j = 0; j < 4; ++j) {
                size_t off = (size_t)(row + j) * N + col;
                float v = acc[m][n][j];
                if (epi == 0) {
                    __builtin_nontemporal_store(v, &Cf[off]);
                } else if (epi == 1) {
                    Cf[off] = Res[off] + v;
                } else {
                    Cb[off] = f2bf(gelu_f(v));
                }
            }
        }
    }
}

// ----------------------- QKV GEMM with fused RoPE + bf16 epilogue (layers>=1)
// A = LN output [M][1024], Bt = wqkvT [3072][1024].  Writes q (rope'd, *0.125),
// k (rope'd), both [bh][s][64] bf16, and v [bh][s][64] bf16 (pass-through).
// Rope pair (2i,2i+1) lives in adjacent lanes -> one shfl_xor(.,1).
__global__ __launch_bounds__(256, 2) void gemm_qkv_k(
    const ushort_t* __restrict__ A,
    const ushort_t* __restrict__ Bt,
    ushort_t* __restrict__ qb, ushort_t* __restrict__ kb,
    ushort_t* __restrict__ vb)
{
    __shared__ __align__(16) ushort_t As[128 * 64];
    __shared__ __align__(16) ushort_t Bs[128 * 64];
    const int N = 3*D_, K = D_;
    int tid = threadIdx.x;
    int wid = tid >> 6, lane = tid & 63;
    int wm = wid >> 1, wn = wid & 1;
    int bm = blockIdx.x * 128, bn = blockIdx.y * 128;

    f32x4_t acc[4][4];
    #pragma unroll
    for (int m = 0; m < 4; ++m)
        #pragma unroll
        for (int n = 0; n < 4; ++n)
            acc[m][n] = (f32x4_t){0.f, 0.f, 0.f, 0.f};

    int srow = (lane >> 3);
    int scol = (lane & 7) * 8;

    for (int k0 = 0; k0 < K; k0 += 64) {
        __syncthreads();
        #pragma unroll
        for (int i = 0; i < 4; ++i) {
            int rb = i * 32 + wid * 8;
            gload_lds16(A  + (size_t)(bm + rb + srow) * K + k0 + scol, &As[rb * 64]);
            gload_lds16(Bt + (size_t)(bn + rb + srow) * K + k0 + scol, &Bs[rb * 64]);
        }
        __syncthreads();
        #pragma unroll
        for (int kk = 0; kk < 64; kk += 32) {
            bf16x8_t af[4], bfr[4];
            int kof = kk + (lane >> 4) * 8;
            #pragma unroll
            for (int m = 0; m < 4; ++m) {
                int r = wm * 64 + m * 16 + (lane & 15);
                af[m] = *(const bf16x8_t*)&As[r * 64 + kof];
            }
            #pragma unroll
            for (int n = 0; n < 4; ++n) {
                int r = wn * 64 + n * 16 + (lane & 15);
                bfr[n] = *(const bf16x8_t*)&Bs[r * 64 + kof];
            }
            #pragma unroll
            for (int m = 0; m < 4; ++m)
                #pragma unroll
                for (int n = 0; n < 4; ++n)
                    acc[m][n] = __builtin_amdgcn_mfma_f32_16x16x32_bf16(
                        af[m], bfr[n], acc[m][n], 0, 0, 0);
        }
    }

    int cr = (lane >> 4) * 4, cc = lane & 15;
    // per-n fragment: head/part uniform (16-col blocks never straddle 64-col parts)
    float csn[4], snn[4];
    int partn[4], headn[4], dn[4];
    #pragma unroll
    for (int n = 0; n < 4; ++n) {
        int col = bn + wn*64 + n*16 + cc;
        int head = col / 192;
        int rem = col - head*192;
        partn[n] = rem >> 6;
        dn[n] = rem & 63;
        headn[n] = head;
        float inv = exp2f((float)(dn[n] >> 1) * (-13.287712379549449f / 32.f));
        sincosf((float)head * inv, &snn[n], &csn[n]);
    }
    bool odd = (lane & 1);
    #pragma unroll
    for (int m = 0; m < 4; ++m) {
        int row = bm + wm * 64 + m * 16 + cr;
        #pragma unroll
        for (int n = 0; n < 4; ++n) {
            ushort_t* dst = (partn[n] == 0) ? qb : (partn[n] == 1) ? kb : vb;
            #pragma unroll
            for (int j = 0; j < 4; ++j) {
                float a = acc[m][n][j];
                float p = __shfl_xor(a, 1);
                float outv;
                if (partn[n] == 2) outv = a;
                else {
                    outv = odd ? (p*snn[n] + a*csn[n]) : (a*csn[n] - p*snn[n]);
                    if (partn[n] == 0) outv *= 0.125f;
                }
                int r = row + j;
                size_t off = ((size_t)((r >> 10)*16 + headn[n]) * S_ + (r & 1023)) * 64 + dn[n];
                dst[off] = f2bf(outv);
            }
        }
    }
}

// -------------- layer-0: split-precision QKV GEMM + fused rope/split epilogue
// C = Ah Bh + Ah Bl + Al Bh (fp32 acc); q,k written as hi/lo bf16 pairs.
__global__ __launch_bounds__(256, 2) void gemm_split_qkv_k(
    const ushort_t* __restrict__ Ah, const ushort_t* __restrict__ Al,
    const ushort_t* __restrict__ Bh, const ushort_t* __restrict__ Bl,
    ushort_t* __restrict__ qhb, ushort_t* __restrict__ qlb,
    ushort_t* __restrict__ khb, ushort_t* __restrict__ klb,
    ushort_t* __restrict__ vb)
{
    __shared__ __align__(16) ushort_t Ash[128 * 64];
    __shared__ __align__(16) ushort_t Asl[128 * 64];
    __shared__ __align__(16) ushort_t Bsh[128 * 64];
    __shared__ __align__(16) ushort_t Bsl[128 * 64];
    const int K = D_;
    int tid = threadIdx.x;
    int wid = tid >> 6, lane = tid & 63;
    int wm = wid >> 1, wn = wid & 1;
    int bm = blockIdx.x * 128, bn = blockIdx.y * 128;

    f32x4_t acc[4][4];
    #pragma unroll
    for (int m = 0; m < 4; ++m)
        #pragma unroll
        for (int n = 0; n < 4; ++n)
            acc[m][n] = (f32x4_t){0.f, 0.f, 0.f, 0.f};

    int srow = (lane >> 3);
    int scol = (lane & 7) * 8;

    for (int k0 = 0; k0 < K; k0 += 64) {
        __syncthreads();
        #pragma unroll
        for (int i = 0; i < 4; ++i) {
            int rb = i * 32 + wid * 8;
            size_t ga = (size_t)(bm + rb + srow) * K + k0 + scol;
            size_t gb = (size_t)(bn + rb + srow) * K + k0 + scol;
            gload_lds16(Ah + ga, &Ash[rb * 64]);
            gload_lds16(Al + ga, &Asl[rb * 64]);
            gload_lds16(Bh + gb, &Bsh[rb * 64]);
            gload_lds16(Bl + gb, &Bsl[rb * 64]);
        }
        __syncthreads();
        #pragma unroll
        for (int kk = 0; kk < 64; kk += 32) {
            bf16x8_t ah[4], al[4], bhf[4], blf[4];
            int kof = kk + (lane >> 4) * 8;
            #pragma unroll
            for (int m = 0; m < 4; ++m) {
                int r = wm * 64 + m * 16 + (lane & 15);
                ah[m] = *(const bf16x8_t*)&Ash[r * 64 + kof];
                al[m] = *(const bf16x8_t*)&Asl[r * 64 + kof];
            }
            #pragma unroll
            for (int n = 0; n < 4; ++n) {
                int r = wn * 64 + n * 16 + (lane & 15);
                bhf[n] = *(const bf16x8_t*)&Bsh[r * 64 + kof];
                blf[n] = *(const bf16x8_t*)&Bsl[r * 64 + kof];
            }
            #pragma unroll
            for (int m = 0; m < 4; ++m)
                #pragma unroll
                for (int n = 0; n < 4; ++n) {
                    acc[m][n] = __builtin_amdgcn_mfma_f32_16x16x32_bf16(
                        ah[m], bhf[n], acc[m][n], 0, 0, 0);
                    acc[m][n] = __builtin_amdgcn_mfma_f32_16x16x32_bf16(
                        ah[m], blf[n], acc[m][n], 0, 0, 0);
                    acc[m][n] = __builtin_amdgcn_mfma_f32_16x16x32_bf16(
                        al[m], bhf[n], acc[m][n], 0, 0, 0);
                }
        }
    }

    int cr = (lane >> 4) * 4, cc = lane & 15;
    float csn[4], snn[4];
    int partn[4], headn[4], dn[4];
    #pragma unroll
    for (int n = 0; n < 4; ++n) {
        int col = bn + wn*64 + n*16 + cc;
        int head = col / 192;
        int rem = col - head*192;
        partn[n] = rem >> 6;
        dn[n] = rem & 63;
        headn[n] = head;
        float inv = exp2f((float)(dn[n] >> 1) * (-13.287712379549449f / 32.f));
        sincosf((float)head * inv, &snn[n], &csn[n]);
    }
    bool odd = (lane & 1);
    #pragma unroll
    for (int m = 0; m < 4; ++m) {
        int row = bm + wm * 64 + m * 16 + cr;
        #pragma unroll
        for (int n = 0; n < 4; ++n) {
            #pragma unroll
            for (int j = 0; j < 4; ++j) {
                float a = acc[m][n][j];
                float p = __shfl_xor(a, 1);
                int r = row + j;
                size_t off = ((size_t)((r >> 10)*16 + headn[n]) * S_ + (r & 1023)) * 64 + dn[n];
                if (partn[n] == 2) {
                    vb[off] = f2bf(a);
                } else {
                    float outv = odd ? (p*snn[n] + a*csn[n]) : (a*csn[n] - p*snn[n]);
                    if (partn[n] == 0) outv *= 0.125f;
                    ushort_t hi = f2bf(outv);
                    ushort_t lo = f2bf(outv - bf2f(hi));
                    if (partn[n] == 0) { qhb[off] = hi; qlb[off] = lo; }
                    else               { khb[off] = hi; klb[off] = lo; }
                }
            }
        }
    }
}

// ---------------------------------------------------------------- launch
extern "C" void kernel_launch(void* const* d_in, const int* in_sizes, int n_in,
                              void* d_out, int out_size, void* d_ws, size_t ws_size,
                              hipStream_t stream) {
    const int*   x    = (const int*)  d_in[0];
    const float* emb  = (const float*)d_in[1];
    const float* ln1w = (const float*)d_in[2];
    const float* ln1b = (const float*)d_in[3];
    const float* Wqkv = (const float*)d_in[4];
    const float* Wo   = (const float*)d_in[5];
    const float* ln2w = (const float*)d_in[6];
    const float* ln2b = (const float*)d_in[7];
    const float* W1   = (const float*)d_in[8];
    const float* W2   = (const float*)d_in[9];
    const float* lnfw = (const float*)d_in[10];
    const float* lnfb = (const float*)d_in[11];
    const float* Wdec = (const float*)d_in[12];
    float* out = (float*)d_out;

    // ---- workspace layout (bytes), lifetime-aliased, 80 MB total ----
    char* ws = (char*)d_ws;
    float*    h     = (float*)   (ws + 0);              // 8 MB  [2048,1024] f32
    ushort_t* xnb   = (ushort_t*)(ws + (8u<<20));       // 4 MB  LN out hi
    ushort_t* ob    = (ushort_t*)(ws + (12u<<20));      // 4 MB  attn out / xl (l=0)
    ushort_t* q_bf  = (ushort_t*)(ws + (16u<<20));      // 4 MB  q (qh for l=0)
    ushort_t* k_bf  = (ushort_t*)(ws + (20u<<20));      // 4 MB  k (kh for l=0)
    ushort_t* vT_bf = (ushort_t*)(ws + (24u<<20));      // 4 MB  vT
    ushort_t* v_bf  = (ushort_t*)(ws + (28u<<20));      // 4 MB  v row-major
    ushort_t* ql0   = (ushort_t*)(ws + (32u<<20));      // 4 MB  ql (l=0)
    ushort_t* kl0   = (ushort_t*)(ws + (36u<<20));      // 4 MB  kl (l=0)
    ushort_t* ffb   = (ushort_t*)(ws + (40u<<20));      // 16 MB [2048,4096] bf16
    ushort_t* wqkvT = (ushort_t*)(ws + (56u<<20));      // 6 MB  [3072,1024] bf16
    ushort_t* woT   = (ushort_t*)(ws + (62u<<20));      // 2 MB  [1024,1024] bf16
    ushort_t* w1T   = (ushort_t*)(ws + (64u<<20));      // 8 MB  [4096,1024] bf16
    ushort_t* w2T   = (ushort_t*)(ws + (72u<<20));      // 8 MB  [1024,4096] bf16
    ushort_t* wqkvTl= (ushort_t*)(ws + (64u<<20));      // 6 MB  (l=0 only, dead before wt(W1))
    ushort_t* wdecT = (ushort_t*)(ws + (16u<<20));      // 64 MB, aliases q_bf..w2T (post-loop)

    embed_k<<<M_, 256, 0, stream>>>(x, emb, h);
    for (int l = 0; l < L_; ++l) {
        if (l == 0) {
            // split-precision path: scores need fp32-grade accuracy (sharp softmax)
            layernorm_k<<<M_, 256, 0, stream>>>(h, ln1w, ln1b, xnb, ob /*=xl*/);
            wt2_k<<<dim3(3*D_/32, D_/32), 256, 0, stream>>>(Wqkv, wqkvT, wqkvTl, D_, 3*D_);
            gemm_split_qkv_k<<<dim3(M_/128, 3*D_/128), 256, 0, stream>>>(
                xnb, ob /*=xl*/, wqkvT, wqkvTl, q_bf, ql0, k_bf, kl0, v_bf);
            vt_k<<<B_*H_*(S_/64), 256, 0, stream>>>(v_bf, vT_bf);
            attn_mfma0_k<<<B_*H_*(S_/64), 256, 0, stream>>>(
                q_bf, ql0, k_bf, kl0, vT_bf, ob);
        } else {
            layernorm_k<<<M_, 256, 0, stream>>>(h, ln1w + l*D_, ln1b + l*D_, xnb, nullptr);
            wt_k<<<dim3(3*D_/32, D_/32), 256, 0, stream>>>(
                Wqkv + (size_t)l*D_*3*D_, wqkvT, D_, 3*D_);
            gemm_qkv_k<<<dim3(M_/128, 3*D_/128), 256, 0, stream>>>(
                xnb, wqkvT, q_bf, k_bf, v_bf);
            vt_k<<<B_*H_*(S_/64), 256, 0, stream>>>(v_bf, vT_bf);
            attn_mfma_k<<<B_*H_*(S_/64), 256, 0, stream>>>(q_bf, k_bf, vT_bf, ob);
        }
        wt_k<<<dim3(D_/32, D_/32), 256, 0, stream>>>(
            Wo + (size_t)l*D_*D_, woT, D_, D_);
        gemm_bf16_k<64><<<dim3(M_/64, D_/128), 128, 0, stream>>>(
            ob, woT, h, h, nullptr, M_, D_, D_, 1);
        layernorm_k<<<M_, 256, 0, stream>>>(h, ln2w + l*D_, ln2b + l*D_, xnb, nullptr);
        wt_k<<<dim3(DFF_/32, D_/32), 256, 0, stream>>>(
            W1 + (size_t)l*D_*DFF_, w1T, D_, DFF_);
        gemm_bf16_k<128><<<dim3(M_/128, DFF_/128), 256, 0, stream>>>(
            xnb, w1T, nullptr, nullptr, ffb, M_, DFF_, D_, 2);
        wt_k<<<dim3(D_/32, DFF_/32), 256, 0, stream>>>(
            W2 + (size_t)l*DFF_*D_, w2T, DFF_, D_);
        gemm_bf16_k<64><<<dim3(M_/64, D_/128), 128, 0, stream>>>(
            ffb, w2T, h, h, nullptr, M_, D_, DFF_, 1);
    }
    layernorm_k<<<M_, 256, 0, stream>>>(h, lnfw, lnfb, xnb, nullptr);
    wt_k<<<dim3(V_/32, D_/32), 256, 0, stream>>>(Wdec, wdecT, D_, V_);
    gemm_bf16_k<128><<<dim3(M_/128, V_/128), 256, 0, stream>>>(
        xnb, wdecT, nullptr, out, nullptr, M_, V_, D_, 0);
}